// Round 1
// baseline (2069.015 us; speedup 1.0000x reference)
//
#include <hip/hip_runtime.h>
#include <math.h>

// ---------------- constants ----------------
#define NSAMP 32768
#define NFRM  128

// ---- ws layout (float offsets) ----
static constexpr int S_OFF  = 0;                   // 32772 (prefix sums, 32769 used)
static constexpr int HP     = 32772;               // 16384
static constexpr int NSQ    = HP + 16384;          // 16
static constexpr int HA     = NSQ + 16;            // 16384
static constexpr int HB     = HA + 16384;          // 16384
static constexpr int WC     = HB + 16384;          // 245760 combined dilated weights
static constexpr int WBC    = WC + 245760;         // 640 combined dilated bias
static constexpr int EWS    = WBC + 640;           // 2048 encoded
static constexpr int TIMEO  = EWS + 2048;          // 2048
static constexpr int TRANSO = TIMEO + 2048;        // 2048
static constexpr int PE     = TRANSO + 2048;       // 2048 softmax impulse weights
static constexpr int RSEL   = PE + 2048;           // 1024 (ints)
static constexpr int ENVO   = RSEL + 1024;         // 4096 env (16,256)
static constexpr int BUFA   = ENVO + 4096;         // 524288
static constexpr int BUFB   = BUFA + 524288;       // 524288
static constexpr int WT     = BUFB + 524288;       // transposed weights, 1064960 total
static constexpr int WT_POS = WT;                  // 327680  [l][(c*4+k)*128+o]
static constexpr int WT_ENV = WT + 327680;         // 294912  [l][(c*3+k)*128+o]
static constexpr int WT_TFU = WT + 622592;         // 147456
static constexpr int WT_TT  = WT + 770048;         // 16384   [c][o]
static constexpr int WT_TR  = WT + 786432;         // 16384
static constexpr int LT_POS = WT + 802816;         // 65536   [k][r], R=512
static constexpr int LT_ENV = WT + 868352;         // 65536
static constexpr int LT_TFU = WT + 933888;         // 131072  [k][r], R=1024
static constexpr int SINES  = WT + 1064960;        // 2097152 (64 x 32768)
static constexpr int ENVS   = SINES + 2097152;     // 524288
static constexpr int CBUF   = ENVS + 524288;       // 524288
static constexpr int KBUF   = CBUF + 524288;       // 524288
static constexpr int PART   = KBUF + 524288;       // 1048576 (32 x 32768)

// ---- output offsets ----
static constexpr int O_IDX  = 32768;
static constexpr int O_ENC  = 32784;
static constexpr int O_ENV  = 34832;
static constexpr int O_TIME = 38928;
static constexpr int O_TR   = 40976;

// ================= front-end =================

__global__ void k_prefix(const float* __restrict__ x, float* __restrict__ ws){
  float* S = ws + S_OFF;
  int tid = threadIdx.x;
  __shared__ float ps[1024];
  float v[32];
  const float4* x4 = (const float4*)(x + tid*32);
  float s = 0.f;
#pragma unroll
  for (int i=0;i<8;++i){
    float4 q = x4[i];
    v[4*i]=q.x; v[4*i+1]=q.y; v[4*i+2]=q.z; v[4*i+3]=q.w;
    s += q.x+q.y+q.z+q.w;
  }
  ps[tid] = s; __syncthreads();
  for (int ofs=1; ofs<1024; ofs<<=1){
    float add = (tid>=ofs)? ps[tid-ofs] : 0.f;
    __syncthreads();
    ps[tid] += add;
    __syncthreads();
  }
  float run = ps[tid] - s;   // exclusive prefix of chunks
#pragma unroll
  for (int i=0;i<32;++i){ S[tid*32+i] = run; run += v[i]; }
  if (tid==1023) S[32768] = ps[1023];
}

__global__ void k_fbpool(const float* __restrict__ fbw, float* __restrict__ ws){
  const float* S = ws + S_OFF;
  int c = blockIdx.x >> 5, j0 = (blockIdx.x & 31) << 2;
  int jj = threadIdx.x >> 7, kk = threadIdx.x & 127;
  int j = j0 + jj;
  int i0 = max(0, 256*j - 256), i1 = min(32767, 256*j + 255);
  float acc = 0.f;
#pragma unroll
  for (int m=0;m<4;++m){
    int k = kk + (m<<7);
    int hi = min(max(i1 + k - 255, 0), 32768);
    int lo = min(max(i0 + k - 256, 0), 32768);
    acc += fbw[c*512 + k] * (S[hi] - S[lo]);
  }
  for (int o=32;o;o>>=1) acc += __shfl_down(acc, o);
  __shared__ float red[8];
  if ((threadIdx.x & 63) == 0) red[threadIdx.x>>6] = acc;
  __syncthreads();
  if (threadIdx.x < 4)
    ws[HP + c*128 + j0 + threadIdx.x] = (red[2*threadIdx.x] + red[2*threadIdx.x+1]) * (1.0f/512.0f);
}

__global__ void k_sumsq(const float* __restrict__ a, float* __restrict__ dst){
  int tid = threadIdx.x;
  float s = 0.f;
  for (int i=tid;i<16384;i+=1024){ float v = a[i]; s += v*v; }
  for (int o=32;o;o>>=1) s += __shfl_down(s, o);
  __shared__ float red[16];
  if ((tid & 63) == 0) red[tid>>6] = s;
  __syncthreads();
  if (tid==0){ float t=0.f; for (int i=0;i<16;++i) t += red[i]; dst[0] = t; }
}

// one-shot transpose of all reused weight matrices
__global__ void k_wtrans(const float* __restrict__ posw, const float* __restrict__ envw,
                         const float* __restrict__ tfuw, const float* __restrict__ ttw,
                         const float* __restrict__ trw,  const float* __restrict__ lpw,
                         const float* __restrict__ lew,  const float* __restrict__ ltw,
                         float* __restrict__ ws){
  int i = blockIdx.x*1024 + threadIdx.x;
  float v;
  if (i < 327680){                       // pos_up (5,128,128,4) -> [l][(c*4+k)*128+o]
    int l = i>>16, r = i & 65535, o = r & 127, ck = r>>7, c = ck>>2, k = ck&3;
    v = posw[(l<<16) + (((o<<7)+c)<<2) + k];
  } else if (i < 622592){                // env_up (6,128,128,3)
    int i2 = i - 327680; int l = i2/49152, r = i2 - l*49152, o = r&127, ck = r>>7;
    int c = ck/3, k = ck - 3*c;
    v = envw[l*49152 + ((o<<7)+c)*3 + k];
  } else if (i < 770048){                // tfu_up (3,128,128,3)
    int i2 = i - 622592; int l = i2/49152, r = i2 - l*49152, o = r&127, ck = r>>7;
    int c = ck/3, k = ck - 3*c;
    v = tfuw[l*49152 + ((o<<7)+c)*3 + k];
  } else if (i < 786432){                // tt_w (128,128) -> [c][o]
    int i2 = i - 770048; int o = i2 & 127, c = i2 >> 7;
    v = ttw[(o<<7) + c];
  } else if (i < 802816){                // tr_w
    int i2 = i - 786432; int o = i2 & 127, c = i2 >> 7;
    v = trw[(o<<7) + c];
  } else if (i < 868352){                // pos_lin (512,128) -> [k][r]
    int i2 = i - 802816; int r = i2 & 511, k = i2 >> 9;
    v = lpw[(r<<7) + k];
  } else if (i < 933888){                // env_lin
    int i2 = i - 868352; int r = i2 & 511, k = i2 >> 9;
    v = lew[(r<<7) + k];
  } else {                               // tfu_lin (1024,128) -> [k][r]
    int i2 = i - 933888; int r = i2 & 1023, k = i2 >> 10;
    v = ltw[(r<<7) + k];
  }
  ws[WT + i] = v;
}

__global__ void k_reduce(const float* __restrict__ rw, const float* __restrict__ rb,
                         float* __restrict__ ws){
  int o = blockIdx.x, t = threadIdx.x;
  float g = sqrtf(ws[NSQ]) + 1e-8f;
  float acc = rb[o];
  const float* hp = ws + HP;
  for (int c=0;c<128;++c) acc += rw[o*161 + c] * __fdiv_rn(hp[c*128 + t], g);
  // positional encoding (exact replication of the f32 op sequence)
  float delta = __fdiv_rn(2.0f, 127.0f);
  float p = __fadd_rn(-1.0f, __fmul_rn((float)t, delta));
  acc += rw[o*161 + 128] * p;
  float sc = 1.0f;
  const float PIF = (float)M_PI;
#pragma unroll
  for (int i=0;i<16;++i){
    float f = __fmul_rn(__fmul_rn(p, sc), PIF);
    acc += rw[o*161 + 129 + 2*i] * sinf(f);
    acc += rw[o*161 + 130 + 2*i] * cosf(f);
    sc = sc * 2.0f;
  }
  ws[HA + o*128 + t] = acc;
}

__global__ void k_combW(const float* __restrict__ dw, const float* __restrict__ db,
                        const float* __restrict__ pw, const float* __restrict__ pb,
                        float* __restrict__ ws){
  int l = blockIdx.x >> 7, o = blockIdx.x & 127, c = threadIdx.x;
  float a0=0.f, a1=0.f, a2=0.f;
  for (int m=0;m<128;++m){
    float p = pw[(l*128 + o)*128 + m];
    const float* dp = dw + ((l*128 + m)*128 + c)*3;
    a0 += p*dp[0]; a1 += p*dp[1]; a2 += p*dp[2];
  }
  float* W = ws + WC + ((l*128 + o)*128 + c)*3;
  W[0]=a0; W[1]=a1; W[2]=a2;
  if (c==0){
    float b = pb[l*128 + o];
    for (int m=0;m<128;++m) b += pw[(l*128 + o)*128 + m] * db[l*128 + m];
    ws[WBC + l*128 + o] = b;
  }
}

__global__ void k_dil(float* __restrict__ ws, int l, int d, int inoff, int outoff){
  int o = blockIdx.x, t = threadIdx.x;
  const float* in = ws + inoff;
  const float* Wo = ws + WC + (l*128 + o)*384;
  float acc = in[o*128 + t] + ws[WBC + l*128 + o];
  for (int c=0;c<128;++c){
    float v0 = (t-d >= 0)  ? in[c*128 + t - d] : 0.f;
    float v1 = in[c*128 + t];
    float v2 = (t+d < 128) ? in[c*128 + t + d] : 0.f;
    acc += Wo[c*3]*v0 + Wo[c*3+1]*v1 + Wo[c*3+2]*v2;
  }
  ws[outoff + o*128 + t] = acc >= 0.f ? acc : 0.2f*acc;
}

__global__ void k_topk(float* __restrict__ ws, float* __restrict__ out){
  const float* h = ws + HB;
  int t = threadIdx.x;
  __shared__ float nt[128], nt0[128];
  __shared__ int idxs[16];
  __shared__ float r2[2];
  __shared__ float wv[2]; __shared__ int wi[2];
  float colsq = 0.f;
  for (int c=0;c<128;++c){ float v = h[c*128 + t]; colsq += v*v; }
  float s = colsq;
  for (int o=32;o;o>>=1) s += __shfl_down(s, o);
  if ((t & 63) == 0) r2[t>>6] = s;
  __syncthreads();
  float g2 = sqrtf(r2[0] + r2[1]) + 1e-8f;
  float sq2 = 0.f;
  for (int c=0;c<128;++c){ float v = __fdiv_rn(h[c*128 + t], g2); sq2 += v*v; }
  float ntv = sqrtf(sq2);
  nt[t] = ntv; nt0[t] = ntv;
  __syncthreads();
  for (int j=0;j<16;++j){
    float v = nt[t]; int bi = t;
    for (int o=32;o;o>>=1){
      float ov = __shfl_down(v, o); int oi = __shfl_down(bi, o);
      if (ov > v || (ov == v && oi < bi)){ v = ov; bi = oi; }
    }
    if ((t & 63) == 0){ wv[t>>6] = v; wi[t>>6] = bi; }
    __syncthreads();
    if (t == 0){
      int win = (wv[1] > wv[0] || (wv[1] == wv[0] && wi[1] < wi[0])) ? wi[1] : wi[0];
      idxs[j] = win; nt[win] = -3.0e38f;
    }
    __syncthreads();
  }
  if (t < 16) out[O_IDX + t] = (float)idxs[t];
  for (int j=0;j<16;++j){
    int ij = idxs[j];
    float hv = __fdiv_rn(h[t*128 + ij], g2);
    float enc = __fdiv_rn(hv, nt0[ij] + 1e-8f);
    out[O_ENC + j*128 + t] = enc;
    ws[EWS + j*128 + t] = enc;
  }
}

__global__ void k_timetrans(float* __restrict__ ws, const float* __restrict__ ttb,
                            const float* __restrict__ trb, float* __restrict__ out){
  int kind = blockIdx.x >> 4, j = blockIdx.x & 15, o = threadIdx.x;
  __shared__ float er[128];
  er[o] = ws[EWS + j*128 + o];
  __syncthreads();
  const float* Wt = ws + (kind ? WT_TR : WT_TT);
  float acc = kind ? trb[o] : ttb[o];
  for (int c=0;c<128;++c) acc += er[c] * Wt[c*128 + o];
  out[(kind ? O_TR : O_TIME) + j*128 + o] = acc;
  ws[(kind ? TRANSO : TIMEO) + j*128 + o] = acc;
}

// ================= decoder stacks =================

__global__ void k_lin(float* __restrict__ ws, const float* __restrict__ lb,
                      int zoff, int ltoff, int R, int start, int dstoff){
  int e = blockIdx.x, tid = threadIdx.x;
  __shared__ float z[128];
  if (tid < 128) z[tid] = ws[zoff + e*128 + tid];
  __syncthreads();
  int s = tid >> 7, c = tid & 127;
  int r = c*start + s;
  float acc = lb[r];
  const float* lt = ws + ltoff;
  for (int k=0;k<128;++k) acc += z[k] * lt[k*R + r];
  ws[dstoff + e*(start<<7) + tid] = acc;   // (e, s, c) layout
}

template<int JT>
__global__ void k_convT(float* __restrict__ ws, const float* __restrict__ bias,
                        int srcoff, int dstoff, int wtoff, int Lin, int nJT){
  int e = blockIdx.x / nJT, jt = blockIdx.x - e*nJT;
  int j0 = jt*JT, o = threadIdx.x;
  const int SC = JT/2 + 2;
  __shared__ float xs[18*128];
  int s_lo = (j0 >> 1) - 1;
  const float* in = ws + srcoff + e*Lin*128;
  for (int idx=o; idx<SC*128; idx+=128){
    int si = idx >> 7, c = idx & 127, s = s_lo + si;
    xs[idx] = (s >= 0 && s < Lin) ? in[s*128 + c] : 0.f;
  }
  __syncthreads();
  float acc[JT];
#pragma unroll
  for (int jj=0;jj<JT;++jj) acc[jj] = bias[o];
  const float* wt = ws + wtoff;
  for (int c=0;c<128;++c){
    float w0 = wt[((c<<2)+0)*128 + o];
    float w1 = wt[((c<<2)+1)*128 + o];
    float w2 = wt[((c<<2)+2)*128 + o];
    float w3 = wt[((c<<2)+3)*128 + o];
#pragma unroll
    for (int jj=0;jj<JT;++jj){
      if ((jj & 1) == 0){
        acc[jj] += xs[((jj>>1)<<7) + c]*w3 + xs[(((jj>>1)+1)<<7) + c]*w1;
      } else {
        acc[jj] += xs[(((jj+1)>>1)<<7) + c]*w2 + xs[((((jj+1)>>1)+1)<<7) + c]*w0;
      }
    }
  }
  float* outp = ws + dstoff + e*(Lin*2)*128;
#pragma unroll
  for (int jj=0;jj<JT;++jj){
    float v = acc[jj];
    outp[(j0+jj)*128 + o] = v >= 0.f ? v : 0.2f*v;
  }
}

template<int JT>
__global__ void k_conv3up(float* __restrict__ ws, const float* __restrict__ bias,
                          int srcoff, int dstoff, int wtoff, int Lin, int nJT){
  int e = blockIdx.x / nJT, jt = blockIdx.x - e*nJT;
  int j0 = jt*JT, o = threadIdx.x;
  const int SC = JT/2 + 2;
  __shared__ float xs[18*128];
  int fs = (j0 >> 1) - 1;
  const float* in = ws + srcoff + e*Lin*128;
  for (int idx=o; idx<SC*128; idx+=128){
    int si = idx >> 7, c = idx & 127, s = fs + si;
    xs[idx] = (s >= 0 && s < Lin) ? in[s*128 + c] : 0.f;
  }
  __syncthreads();
  float acc[JT];
#pragma unroll
  for (int jj=0;jj<JT;++jj) acc[jj] = bias[o];
  const float* wt = ws + wtoff;
  for (int c=0;c<128;++c){
    float w0 = wt[(c*3+0)*128 + o];
    float w1 = wt[(c*3+1)*128 + o];
    float w2 = wt[(c*3+2)*128 + o];
#pragma unroll
    for (int jj=0;jj<JT;++jj){
      acc[jj] += xs[((((jj-1)>>1)+1)<<7) + c]*w0
               + xs[((((jj  )>>1)+1)<<7) + c]*w1
               + xs[((((jj+1)>>1)+1)<<7) + c]*w2;
    }
  }
  float* outp = ws + dstoff + e*(Lin*2)*128;
#pragma unroll
  for (int jj=0;jj<JT;++jj){
    float v = acc[jj];
    outp[(j0+jj)*128 + o] = v >= 0.f ? v : 0.2f*v;
  }
}

__global__ void k_out_pos(float* __restrict__ ws, const float* __restrict__ pw,
                          const float* __restrict__ pb){
  int e = blockIdx.x, tid = threadIdx.x;
  __shared__ float xs[16384];
  const float* in = ws + BUFB + e*16384;
  for (int idx=tid; idx<16384; idx+=128){
    int q = idx >> 7, c = idx & 127;
    xs[(q<<7) + ((c+q)&127)] = in[idx];   // swizzled store
  }
  __syncthreads();
  int j = tid;
  float acc = pb[0];
  for (int c=0;c<128;++c){
#pragma unroll
    for (int k=0;k<3;++k){
      int q = j + k - 1;
      if (q >= 0 && q < 128) acc += xs[(q<<7) + ((c+q)&127)] * pw[c*3 + k];
    }
  }
  // softmax over 128 lanes; reuse xs as scratch after barrier
  float m = acc;
  for (int o=32;o;o>>=1) m = fmaxf(m, __shfl_down(m, o));
  __syncthreads();
  if ((tid & 63) == 0) xs[tid>>6] = m;
  __syncthreads();
  m = fmaxf(xs[0], xs[1]);
  float ex = expf(__fsub_rn(acc, m));
  float s = ex;
  for (int o=32;o;o>>=1) s += __shfl_down(s, o);
  __syncthreads();
  if ((tid & 63) == 0) xs[2 + (tid>>6)] = s;
  __syncthreads();
  s = xs[2] + xs[3];
  ws[PE + e*128 + j] = __fdiv_rn(ex, s);
}

__global__ void k_out_env(float* __restrict__ ws, const float* __restrict__ ew,
                          const float* __restrict__ eb, float* __restrict__ out){
  int e = blockIdx.x >> 2, b0 = (blockIdx.x & 3) << 6, tid = threadIdx.x;
  __shared__ float xs[66*128];
  const float* in = ws + BUFA + e*32768;
  for (int idx=tid; idx<66*128; idx+=64){
    int qs = idx >> 7, c = idx & 127, q = b0 - 1 + qs;
    xs[(qs<<7) + ((c+qs)&127)] = (q >= 0 && q < 256) ? in[q*128 + c] : 0.f;
  }
  __syncthreads();
  int b = b0 + tid;
  float acc = eb[0];
  for (int c=0;c<128;++c){
#pragma unroll
    for (int k=0;k<3;++k){
      int qs = tid + k;
      acc += xs[(qs<<7) + ((c+qs)&127)] * ew[c*3 + k];
    }
  }
  acc = fmaxf(acc, 0.f);
  out[O_ENV + e*256 + b] = acc;
  ws[ENVO + e*256 + b] = acc;
}

__global__ void k_out_tfu(float* __restrict__ ws, const float* __restrict__ tw,
                          const float* __restrict__ tb_){
  int e = blockIdx.x, tid = threadIdx.x;
  __shared__ float xs[66*128];
  __shared__ float tf[2048];
  const float* in = ws + BUFB + e*8192;
  for (int idx=tid; idx<66*128; idx+=1024){
    int qs = idx >> 7, c = idx & 127, q = -1 + qs;
    xs[(qs<<7) + ((c+qs)&127)] = (q >= 0 && q < 64) ? in[q*128 + c] : 0.f;
  }
  __syncthreads();
  int r0 = tid >> 6, b = tid & 63;
  for (int rr=r0; rr<32; rr+=16){
    float acc = tb_[rr];
    for (int c=0;c<128;++c){
#pragma unroll
      for (int k=0;k<3;++k){
        int qs = b + k;
        acc += xs[(qs<<7) + ((c+qs)&127)] * tw[(rr*128 + c)*3 + k];
      }
    }
    tf[rr*64 + b] = acc;
  }
  __syncthreads();
  if (tid < 64){
    float best = tf[tid]; int bi = 0;
    for (int r=1;r<32;++r){ float v = tf[r*64 + tid]; if (v > best){ best = v; bi = r; } }
    ((int*)(ws + RSEL))[e*64 + tid] = bi;
  }
}

// ================= synthesis =================

__global__ void k_sines(float* __restrict__ ws){
  int b = blockIdx.x >> 5;
  int t = ((blockIdx.x & 31) << 10) + threadIdx.x;
  float l0 = __fdiv_rn((float)log(20.0),   (float)log(10.0));
  float l1 = __fdiv_rn((float)log(9922.5), (float)log(10.0));
  float dl = __fdiv_rn(__fsub_rn(l1, l0), 63.0f);
  float lb = __fadd_rn(l0, __fmul_rn((float)b, dl));
  float freq = (float)pow(10.0, (double)lb);
  float w = __fmul_rn((float)(2.0*M_PI), freq);
  float tn = __fdiv_rn((float)t, 22050.0f);
  ws[SINES + b*NSAMP + t] = sinf(__fmul_rn(w, tn));
}

__global__ void k_envs(float* __restrict__ ws, const float* __restrict__ noise){
  int e = blockIdx.x >> 5;
  int tau = ((blockIdx.x & 31) << 10) + threadIdx.x;
  float cf = __fsub_rn(__fdiv_rn(__fmul_rn(__fadd_rn((float)tau, 0.5f), 256.0f), 32768.0f), 0.5f);
  float c = fminf(fmaxf(cf, 0.0f), 255.0f);
  int i0 = (int)floorf(c);
  int i1 = min(i0 + 1, 255);
  float w = __fsub_rn(c, (float)i0);
  float e0 = ws[ENVO + e*256 + i0], e1 = ws[ENVO + e*256 + i1];
  float val = __fadd_rn(__fmul_rn(e0, __fsub_rn(1.0f, w)), __fmul_rn(e1, w));
  ws[ENVS + e*NSAMP + tau] = val * noise[tau];
}

__global__ void k_c(float* __restrict__ ws){
  int e = blockIdx.x >> 5, seg = blockIdx.x & 31;
  int t = (seg << 10) + threadIdx.x;
  __shared__ float pl[128];
  if (threadIdx.x < 128) pl[threadIdx.x] = ws[PE + e*128 + threadIdx.x];
  __syncthreads();
  const float* ev = ws + ENVS + e*NSAMP;
  int kub = min(127, (seg << 2) + 3);
  float acc = 0.f;
  for (int k=0;k<=kub;++k){
    int u = t - (k << 8);
    if (u >= 0) acc += pl[k] * ev[u];
  }
  ws[CBUF + e*NSAMP + t] = acc;
}

__global__ void k_K(float* __restrict__ ws){
  int e = blockIdx.x >> 7, F = blockIdx.x & 127;
  int t = (F << 8) + threadIdx.x;
  __shared__ float ampl[64];
  if (threadIdx.x < 64){
    int r = ((const int*)(ws + RSEL))[e*64 + threadIdx.x];
    float d = __fadd_rn(0.5f, __fmul_rn((float)r, __fdiv_rn(__fsub_rn(0.9999f, 0.5f), 31.0f)));
    ampl[threadIdx.x] = (float)pow((double)d, (double)F);
  }
  __syncthreads();
  float acc = 0.f;
  for (int b=0;b<64;++b) acc += ws[SINES + b*NSAMP + t] * ampl[b];
  ws[KBUF + e*NSAMP + t] = acc * (1.0f/(64.0f*65536.0f));
}

__device__ __forceinline__ void mac8(float* acc, const float4& q0, const float4& q1,
                                     const float4& q2, float c0, float c1, float c2, float c3){
  acc[0] += c0*q1.x + c1*q0.w + c2*q0.z + c3*q0.y;
  acc[1] += c0*q1.y + c1*q1.x + c2*q0.w + c3*q0.z;
  acc[2] += c0*q1.z + c1*q1.y + c2*q1.x + c3*q0.w;
  acc[3] += c0*q1.w + c1*q1.z + c2*q1.y + c3*q1.x;
  acc[4] += c0*q2.x + c1*q1.w + c2*q1.z + c3*q1.y;
  acc[5] += c0*q2.y + c1*q2.x + c2*q1.w + c3*q1.z;
  acc[6] += c0*q2.z + c1*q2.y + c2*q2.x + c3*q1.w;
  acc[7] += c0*q2.w + c1*q2.z + c2*q2.y + c3*q2.x;
}

__device__ __forceinline__ void mac8g(float* acc, const float4& q0, const float4& q1,
                                      const float4& q2, float c0, float c1, float c2, float c3,
                                      int relm){
  acc[0] += (relm>= 0?c0:0.f)*q1.x + (relm>= 1?c1:0.f)*q0.w + (relm>= 2?c2:0.f)*q0.z + (relm>= 3?c3:0.f)*q0.y;
  acc[1] += (relm>=-1?c0:0.f)*q1.y + (relm>= 0?c1:0.f)*q1.x + (relm>= 1?c2:0.f)*q0.w + (relm>= 2?c3:0.f)*q0.z;
  acc[2] += (relm>=-2?c0:0.f)*q1.z + (relm>=-1?c1:0.f)*q1.y + (relm>= 0?c2:0.f)*q1.x + (relm>= 1?c3:0.f)*q0.w;
  acc[3] += (relm>=-3?c0:0.f)*q1.w + (relm>=-2?c1:0.f)*q1.z + (relm>=-1?c2:0.f)*q1.y + (relm>= 0?c3:0.f)*q1.x;
  acc[4] += (relm>=-4?c0:0.f)*q2.x + (relm>=-3?c1:0.f)*q1.w + (relm>=-2?c2:0.f)*q1.z + (relm>=-1?c3:0.f)*q1.y;
  acc[5] += (relm>=-5?c0:0.f)*q2.y + (relm>=-4?c1:0.f)*q2.x + (relm>=-3?c2:0.f)*q1.w + (relm>=-2?c3:0.f)*q1.z;
  acc[6] += (relm>=-6?c0:0.f)*q2.z + (relm>=-5?c1:0.f)*q2.y + (relm>=-4?c2:0.f)*q2.x + (relm>=-3?c3:0.f)*q1.w;
  acc[7] += (relm>=-7?c0:0.f)*q2.w + (relm>=-6?c1:0.f)*q2.z + (relm>=-5?c2:0.f)*q2.y + (relm>=-4?c3:0.f)*q2.x;
}

__global__ __launch_bounds__(256, 2)
void k_bigconv(float* __restrict__ ws){
  int bid = blockIdx.x;
  int e = bid >> 5;
  int tile = 15 - ((bid >> 1) & 15);   // heavy tiles dispatch first
  int h = bid & 1;
  int t0 = tile << 11;
  int tid = threadIdx.x;
  int tb = t0 + 8*tid;
  const float* ce = ws + CBUF + e*NSAMP;
  const float* Ke = ws + KBUF + e*NSAMP;
  __shared__ __align__(16) float kl[2312];
  float acc[8] = {0,0,0,0,0,0,0,0};
  int nch  = (t0 >> 8) + 8;
  int nch2 = nch >> 1;
  int m0 = h ? nch2 : 0;
  int m1 = h ? nch  : nch2;
  int mdiag = t0 >> 8;
  for (int m=m0; m<m1; ++m){
    int tau0 = m << 8;
    int base = t0 - tau0 - 256;
    __syncthreads();
    for (int i=tid; i<2312; i+=256){
      int g = base + i;
      kl[i] = (g >= 0 && g < NSAMP) ? Ke[g] : 0.f;
    }
    __syncthreads();
    float4 q2 = *(const float4*)&kl[8*tid + 260];
    float4 q1 = *(const float4*)&kl[8*tid + 256];
    if (m < mdiag){
#pragma unroll 4
      for (int dt=0; dt<256; dt+=4){
        float4 q0 = *(const float4*)&kl[8*tid + 252 - dt];
        float c0 = ce[tau0+dt], c1 = ce[tau0+dt+1], c2 = ce[tau0+dt+2], c3 = ce[tau0+dt+3];
        mac8(acc, q0, q1, q2, c0, c1, c2, c3);
        q2 = q1; q1 = q0;
      }
    } else {
      int rel = tb - tau0;
#pragma unroll 4
      for (int dt=0; dt<256; dt+=4){
        float4 q0 = *(const float4*)&kl[8*tid + 252 - dt];
        float c0 = ce[tau0+dt], c1 = ce[tau0+dt+1], c2 = ce[tau0+dt+2], c3 = ce[tau0+dt+3];
        mac8g(acc, q0, q1, q2, c0, c1, c2, c3, rel - dt);
        q2 = q1; q1 = q0;
      }
    }
  }
  float* pp = ws + PART + (e*2 + h)*NSAMP + tb;
#pragma unroll
  for (int j=0;j<8;++j) pp[j] = acc[j];
}

__global__ void k_final(const float* __restrict__ ws, float* __restrict__ out){
  int t = blockIdx.x*1024 + threadIdx.x;
  float s = 0.f;
  for (int i=0;i<32;++i) s += ws[PART + i*NSAMP + t];
  out[t] = s;
}

// ================= launcher =================

extern "C" void kernel_launch(void* const* d_in, const int* in_sizes, int n_in,
                              void* d_out, int out_size, void* d_ws, size_t ws_size,
                              hipStream_t stream){
  const float* x         = (const float*)d_in[0];
  const float* noise     = (const float*)d_in[1];
  const float* fb_w      = (const float*)d_in[2];
  const float* reduce_w  = (const float*)d_in[3];
  const float* reduce_b  = (const float*)d_in[4];
  const float* dl_dw     = (const float*)d_in[5];
  const float* dl_db     = (const float*)d_in[6];
  const float* dl_pw     = (const float*)d_in[7];
  const float* dl_pb     = (const float*)d_in[8];
  const float* tt_b      = (const float*)d_in[10];
  const float* tr_b      = (const float*)d_in[12];
  const float* pos_lin_w = (const float*)d_in[13];
  const float* pos_lin_b = (const float*)d_in[14];
  const float* pos_up_w  = (const float*)d_in[15];
  const float* pos_up_b  = (const float*)d_in[16];
  const float* pos_out_w = (const float*)d_in[17];
  const float* pos_out_b = (const float*)d_in[18];
  const float* env_lin_w = (const float*)d_in[19];
  const float* env_lin_b = (const float*)d_in[20];
  const float* env_up_w  = (const float*)d_in[21];
  const float* env_up_b  = (const float*)d_in[22];
  const float* env_out_w = (const float*)d_in[23];
  const float* env_out_b = (const float*)d_in[24];
  const float* tfu_lin_w = (const float*)d_in[25];
  const float* tfu_lin_b = (const float*)d_in[26];
  const float* tfu_up_w  = (const float*)d_in[27];
  const float* tfu_up_b  = (const float*)d_in[28];
  const float* tfu_out_w = (const float*)d_in[29];
  const float* tfu_out_b = (const float*)d_in[30];
  const float* tt_w      = (const float*)d_in[9];
  const float* tr_w      = (const float*)d_in[11];
  float* out = (float*)d_out;
  float* ws  = (float*)d_ws;

  k_prefix<<<1, 1024, 0, stream>>>(x, ws);
  k_fbpool<<<4096, 512, 0, stream>>>(fb_w, ws);
  k_sumsq<<<1, 1024, 0, stream>>>(ws + HP, ws + NSQ);
  k_wtrans<<<1040, 1024, 0, stream>>>(pos_up_w, env_up_w, tfu_up_w, tt_w, tr_w,
                                      pos_lin_w, env_lin_w, tfu_lin_w, ws);
  k_reduce<<<128, 128, 0, stream>>>(reduce_w, reduce_b, ws);
  k_combW<<<640, 128, 0, stream>>>(dl_dw, dl_db, dl_pw, dl_pb, ws);
  const int DIL[5] = {1, 3, 9, 27, 1};
  int src = HA, dst = HB;
  for (int l=0;l<5;++l){
    k_dil<<<128, 128, 0, stream>>>(ws, l, DIL[l], src, dst);
    int tmp = src; src = dst; dst = tmp;
  }
  k_topk<<<1, 128, 0, stream>>>(ws, out);
  k_timetrans<<<32, 128, 0, stream>>>(ws, tt_b, tr_b, out);

  // pos stack (impulse placement)
  k_lin<<<16, 512, 0, stream>>>(ws, pos_lin_b, TIMEO, LT_POS, 512, 4, BUFA);
  k_convT<8> <<<16, 128, 0, stream>>>(ws, pos_up_b + 0,   BUFA, BUFB, WT_POS + 0,       4,  1);
  k_convT<16><<<16, 128, 0, stream>>>(ws, pos_up_b + 128, BUFB, BUFA, WT_POS + 65536,   8,  1);
  k_convT<32><<<16, 128, 0, stream>>>(ws, pos_up_b + 256, BUFA, BUFB, WT_POS + 131072, 16,  1);
  k_convT<32><<<32, 128, 0, stream>>>(ws, pos_up_b + 384, BUFB, BUFA, WT_POS + 196608, 32,  2);
  k_convT<32><<<64, 128, 0, stream>>>(ws, pos_up_b + 512, BUFA, BUFB, WT_POS + 262144, 64,  4);
  k_out_pos<<<16, 128, 0, stream>>>(ws, pos_out_w, pos_out_b);

  // env stack
  k_lin<<<16, 512, 0, stream>>>(ws, env_lin_b, TRANSO, LT_ENV, 512, 4, BUFA);
  k_conv3up<8> <<<16, 128, 0, stream>>>(ws, env_up_b + 0,   BUFA, BUFB, WT_ENV + 0,       4,  1);
  k_conv3up<16><<<16, 128, 0, stream>>>(ws, env_up_b + 128, BUFB, BUFA, WT_ENV + 49152,   8,  1);
  k_conv3up<32><<<16, 128, 0, stream>>>(ws, env_up_b + 256, BUFA, BUFB, WT_ENV + 98304,  16,  1);
  k_conv3up<32><<<32, 128, 0, stream>>>(ws, env_up_b + 384, BUFB, BUFA, WT_ENV + 147456, 32,  2);
  k_conv3up<32><<<64, 128, 0, stream>>>(ws, env_up_b + 512, BUFA, BUFB, WT_ENV + 196608, 64,  4);
  k_conv3up<32><<<128,128, 0, stream>>>(ws, env_up_b + 640, BUFB, BUFA, WT_ENV + 245760, 128, 8);
  k_out_env<<<64, 64, 0, stream>>>(ws, env_out_w, env_out_b, out);

  // tfu stack
  k_lin<<<16, 1024, 0, stream>>>(ws, tfu_lin_b, TRANSO, LT_TFU, 1024, 8, BUFA);
  k_conv3up<16><<<16, 128, 0, stream>>>(ws, tfu_up_b + 0,   BUFA, BUFB, WT_TFU + 0,      8,  1);
  k_conv3up<32><<<16, 128, 0, stream>>>(ws, tfu_up_b + 128, BUFB, BUFA, WT_TFU + 49152, 16,  1);
  k_conv3up<32><<<32, 128, 0, stream>>>(ws, tfu_up_b + 256, BUFA, BUFB, WT_TFU + 98304, 32,  2);
  k_out_tfu<<<16, 1024, 0, stream>>>(ws, tfu_out_w, tfu_out_b);

  // synthesis
  k_sines<<<2048, 1024, 0, stream>>>(ws);
  k_envs<<<512, 1024, 0, stream>>>(ws, noise);
  k_c<<<512, 1024, 0, stream>>>(ws);
  k_K<<<2048, 256, 0, stream>>>(ws);
  k_bigconv<<<512, 256, 0, stream>>>(ws);
  k_final<<<32, 1024, 0, stream>>>(ws, out);
}

// Round 2
// 1641.728 us; speedup vs baseline: 1.2603x; 1.2603x over previous
//
#include <hip/hip_runtime.h>
#include <math.h>

// ---------------- constants ----------------
#define NSAMP 32768
#define NFRM  128

// ---- ws layout (float offsets) ----
static constexpr int S_OFF  = 0;                   // 32772 (prefix sums, 32769 used)
static constexpr int HP     = 32772;               // 16384
static constexpr int NSQ    = HP + 16384;          // 16
static constexpr int HA     = NSQ + 16;            // 16384
static constexpr int HB     = HA + 16384;          // 16384
static constexpr int WC     = HB + 16384;          // 245760 combined dilated weights
static constexpr int WBC    = WC + 245760;         // 640 combined dilated bias
static constexpr int EWS    = WBC + 640;           // 2048 encoded
static constexpr int TIMEO  = EWS + 2048;          // 2048
static constexpr int TRANSO = TIMEO + 2048;        // 2048
static constexpr int PE     = TRANSO + 2048;       // 2048 softmax impulse weights
static constexpr int RSEL   = PE + 2048;           // 1024 (ints)
static constexpr int ENVO   = RSEL + 1024;         // 4096 env (16,256)
static constexpr int BUFA   = ENVO + 4096;         // 524288
static constexpr int BUFB   = BUFA + 524288;       // 524288
static constexpr int WT     = BUFB + 524288;       // transposed weights, 1064960 total
static constexpr int WT_POS = WT;                  // 327680  [l][(c*4+k)*128+o]
static constexpr int WT_ENV = WT + 327680;         // 294912  [l][(c*3+k)*128+o]
static constexpr int WT_TFU = WT + 622592;         // 147456
static constexpr int WT_TT  = WT + 770048;         // 16384   [c][o]
static constexpr int WT_TR  = WT + 786432;         // 16384
static constexpr int LT_POS = WT + 802816;         // 65536   [k][r], R=512
static constexpr int LT_ENV = WT + 868352;         // 65536
static constexpr int LT_TFU = WT + 933888;         // 131072  [k][r], R=1024
static constexpr int SINES  = WT + 1064960;        // 2097152 (64 x 32768)
static constexpr int ENVS   = SINES + 2097152;     // 524288 (16 x 32768 f32)
// bf16 conv operands (ushort-indexed off these f32 offsets)
static constexpr int CRB0   = ENVS + 524288;       // 16 x 32832 ushort = 262656 f32 ; CRB0[x]=c[32768-x]
static constexpr int CRB1   = CRB0 + 262656;       // 16 x 32832 ushort ; CRB1[y]=c[32767-y]
static constexpr int KB     = CRB1 + 262656;       // 16 x 34816 ushort = 278528 f32 ; KB[2048+u]=K[u]
static constexpr int PART16 = KB + 278528;         // 16 x 32768 f32 partial outputs

// ---- output offsets ----
static constexpr int O_IDX  = 32768;
static constexpr int O_ENC  = 32784;
static constexpr int O_ENV  = 34832;
static constexpr int O_TIME = 38928;
static constexpr int O_TR   = 40976;

typedef short bf16x8 __attribute__((ext_vector_type(8)));
typedef float f32x4  __attribute__((ext_vector_type(4)));
typedef float f32x16 __attribute__((ext_vector_type(16)));

static __device__ __forceinline__ unsigned short f2bf(float f){
  unsigned int u = __float_as_uint(f);
  unsigned int r = (u + 0x7FFFu + ((u >> 16) & 1u)) >> 16;
  return (unsigned short)r;
}

// ================= front-end =================

__global__ void k_prefix(const float* __restrict__ x, float* __restrict__ ws){
  float* S = ws + S_OFF;
  int tid = threadIdx.x;
  __shared__ float ps[1024];
  float v[32];
  const float4* x4 = (const float4*)(x + tid*32);
  float s = 0.f;
#pragma unroll
  for (int i=0;i<8;++i){
    float4 q = x4[i];
    v[4*i]=q.x; v[4*i+1]=q.y; v[4*i+2]=q.z; v[4*i+3]=q.w;
    s += q.x+q.y+q.z+q.w;
  }
  ps[tid] = s; __syncthreads();
  for (int ofs=1; ofs<1024; ofs<<=1){
    float add = (tid>=ofs)? ps[tid-ofs] : 0.f;
    __syncthreads();
    ps[tid] += add;
    __syncthreads();
  }
  float run = ps[tid] - s;   // exclusive prefix of chunks
#pragma unroll
  for (int i=0;i<32;++i){ S[tid*32+i] = run; run += v[i]; }
  if (tid==1023) S[32768] = ps[1023];
}

__global__ void k_fbpool(const float* __restrict__ fbw, float* __restrict__ ws){
  const float* S = ws + S_OFF;
  int c = blockIdx.x >> 5, j0 = (blockIdx.x & 31) << 2;
  int jj = threadIdx.x >> 7, kk = threadIdx.x & 127;
  int j = j0 + jj;
  int i0 = max(0, 256*j - 256), i1 = min(32767, 256*j + 255);
  float acc = 0.f;
#pragma unroll
  for (int m=0;m<4;++m){
    int k = kk + (m<<7);
    int hi = min(max(i1 + k - 255, 0), 32768);
    int lo = min(max(i0 + k - 256, 0), 32768);
    acc += fbw[c*512 + k] * (S[hi] - S[lo]);
  }
  for (int o=32;o;o>>=1) acc += __shfl_down(acc, o);
  __shared__ float red[8];
  if ((threadIdx.x & 63) == 0) red[threadIdx.x>>6] = acc;
  __syncthreads();
  if (threadIdx.x < 4)
    ws[HP + c*128 + j0 + threadIdx.x] = (red[2*threadIdx.x] + red[2*threadIdx.x+1]) * (1.0f/512.0f);
}

__global__ void k_sumsq(const float* __restrict__ a, float* __restrict__ dst){
  int tid = threadIdx.x;
  float s = 0.f;
  for (int i=tid;i<16384;i+=1024){ float v = a[i]; s += v*v; }
  for (int o=32;o;o>>=1) s += __shfl_down(s, o);
  __shared__ float red[16];
  if ((tid & 63) == 0) red[tid>>6] = s;
  __syncthreads();
  if (tid==0){ float t=0.f; for (int i=0;i<16;++i) t += red[i]; dst[0] = t; }
}

// one-shot transpose of all reused weight matrices
__global__ void k_wtrans(const float* __restrict__ posw, const float* __restrict__ envw,
                         const float* __restrict__ tfuw, const float* __restrict__ ttw,
                         const float* __restrict__ trw,  const float* __restrict__ lpw,
                         const float* __restrict__ lew,  const float* __restrict__ ltw,
                         float* __restrict__ ws){
  int i = blockIdx.x*1024 + threadIdx.x;
  float v;
  if (i < 327680){                       // pos_up (5,128,128,4) -> [l][(c*4+k)*128+o]
    int l = i>>16, r = i & 65535, o = r & 127, ck = r>>7, c = ck>>2, k = ck&3;
    v = posw[(l<<16) + (((o<<7)+c)<<2) + k];
  } else if (i < 622592){                // env_up (6,128,128,3)
    int i2 = i - 327680; int l = i2/49152, r = i2 - l*49152, o = r&127, ck = r>>7;
    int c = ck/3, k = ck - 3*c;
    v = envw[l*49152 + ((o<<7)+c)*3 + k];
  } else if (i < 770048){                // tfu_up (3,128,128,3)
    int i2 = i - 622592; int l = i2/49152, r = i2 - l*49152, o = r&127, ck = r>>7;
    int c = ck/3, k = ck - 3*c;
    v = tfuw[l*49152 + ((o<<7)+c)*3 + k];
  } else if (i < 786432){                // tt_w (128,128) -> [c][o]
    int i2 = i - 770048; int o = i2 & 127, c = i2 >> 7;
    v = ttw[(o<<7) + c];
  } else if (i < 802816){                // tr_w
    int i2 = i - 786432; int o = i2 & 127, c = i2 >> 7;
    v = trw[(o<<7) + c];
  } else if (i < 868352){                // pos_lin (512,128) -> [k][r]
    int i2 = i - 802816; int r = i2 & 511, k = i2 >> 9;
    v = lpw[(r<<7) + k];
  } else if (i < 933888){                // env_lin
    int i2 = i - 868352; int r = i2 & 511, k = i2 >> 9;
    v = lew[(r<<7) + k];
  } else {                               // tfu_lin (1024,128) -> [k][r]
    int i2 = i - 933888; int r = i2 & 1023, k = i2 >> 10;
    v = ltw[(r<<7) + k];
  }
  ws[WT + i] = v;
}

__global__ void k_reduce(const float* __restrict__ rw, const float* __restrict__ rb,
                         float* __restrict__ ws){
  int o = blockIdx.x, t = threadIdx.x;
  float g = sqrtf(ws[NSQ]) + 1e-8f;
  float acc = rb[o];
  const float* hp = ws + HP;
  for (int c=0;c<128;++c) acc += rw[o*161 + c] * __fdiv_rn(hp[c*128 + t], g);
  // positional encoding (exact replication of the f32 op sequence)
  float delta = __fdiv_rn(2.0f, 127.0f);
  float p = __fadd_rn(-1.0f, __fmul_rn((float)t, delta));
  acc += rw[o*161 + 128] * p;
  float sc = 1.0f;
  const float PIF = (float)M_PI;
#pragma unroll
  for (int i=0;i<16;++i){
    float f = __fmul_rn(__fmul_rn(p, sc), PIF);
    acc += rw[o*161 + 129 + 2*i] * sinf(f);
    acc += rw[o*161 + 130 + 2*i] * cosf(f);
    sc = sc * 2.0f;
  }
  ws[HA + o*128 + t] = acc;
}

__global__ void k_combW(const float* __restrict__ dw, const float* __restrict__ db,
                        const float* __restrict__ pw, const float* __restrict__ pb,
                        float* __restrict__ ws){
  int l = blockIdx.x >> 7, o = blockIdx.x & 127, c = threadIdx.x;
  float a0=0.f, a1=0.f, a2=0.f;
  for (int m=0;m<128;++m){
    float p = pw[(l*128 + o)*128 + m];
    const float* dp = dw + ((l*128 + m)*128 + c)*3;
    a0 += p*dp[0]; a1 += p*dp[1]; a2 += p*dp[2];
  }
  float* W = ws + WC + ((l*128 + o)*128 + c)*3;
  W[0]=a0; W[1]=a1; W[2]=a2;
  if (c==0){
    float b = pb[l*128 + o];
    for (int m=0;m<128;++m) b += pw[(l*128 + o)*128 + m] * db[l*128 + m];
    ws[WBC + l*128 + o] = b;
  }
}

__global__ void k_dil(float* __restrict__ ws, int l, int d, int inoff, int outoff){
  int o = blockIdx.x, t = threadIdx.x;
  const float* in = ws + inoff;
  const float* Wo = ws + WC + (l*128 + o)*384;
  float acc = in[o*128 + t] + ws[WBC + l*128 + o];
  for (int c=0;c<128;++c){
    float v0 = (t-d >= 0)  ? in[c*128 + t - d] : 0.f;
    float v1 = in[c*128 + t];
    float v2 = (t+d < 128) ? in[c*128 + t + d] : 0.f;
    acc += Wo[c*3]*v0 + Wo[c*3+1]*v1 + Wo[c*3+2]*v2;
  }
  ws[outoff + o*128 + t] = acc >= 0.f ? acc : 0.2f*acc;
}

__global__ void k_topk(float* __restrict__ ws, float* __restrict__ out){
  const float* h = ws + HB;
  int t = threadIdx.x;
  __shared__ float nt[128], nt0[128];
  __shared__ int idxs[16];
  __shared__ float r2[2];
  __shared__ float wv[2]; __shared__ int wi[2];
  float colsq = 0.f;
  for (int c=0;c<128;++c){ float v = h[c*128 + t]; colsq += v*v; }
  float s = colsq;
  for (int o=32;o;o>>=1) s += __shfl_down(s, o);
  if ((t & 63) == 0) r2[t>>6] = s;
  __syncthreads();
  float g2 = sqrtf(r2[0] + r2[1]) + 1e-8f;
  float sq2 = 0.f;
  for (int c=0;c<128;++c){ float v = __fdiv_rn(h[c*128 + t], g2); sq2 += v*v; }
  float ntv = sqrtf(sq2);
  nt[t] = ntv; nt0[t] = ntv;
  __syncthreads();
  for (int j=0;j<16;++j){
    float v = nt[t]; int bi = t;
    for (int o=32;o;o>>=1){
      float ov = __shfl_down(v, o); int oi = __shfl_down(bi, o);
      if (ov > v || (ov == v && oi < bi)){ v = ov; bi = oi; }
    }
    if ((t & 63) == 0){ wv[t>>6] = v; wi[t>>6] = bi; }
    __syncthreads();
    if (t == 0){
      int win = (wv[1] > wv[0] || (wv[1] == wv[0] && wi[1] < wi[0])) ? wi[1] : wi[0];
      idxs[j] = win; nt[win] = -3.0e38f;
    }
    __syncthreads();
  }
  if (t < 16) out[O_IDX + t] = (float)idxs[t];
  for (int j=0;j<16;++j){
    int ij = idxs[j];
    float hv = __fdiv_rn(h[t*128 + ij], g2);
    float enc = __fdiv_rn(hv, nt0[ij] + 1e-8f);
    out[O_ENC + j*128 + t] = enc;
    ws[EWS + j*128 + t] = enc;
  }
}

__global__ void k_timetrans(float* __restrict__ ws, const float* __restrict__ ttb,
                            const float* __restrict__ trb, float* __restrict__ out){
  int kind = blockIdx.x >> 4, j = blockIdx.x & 15, o = threadIdx.x;
  __shared__ float er[128];
  er[o] = ws[EWS + j*128 + o];
  __syncthreads();
  const float* Wt = ws + (kind ? WT_TR : WT_TT);
  float acc = kind ? trb[o] : ttb[o];
  for (int c=0;c<128;++c) acc += er[c] * Wt[c*128 + o];
  out[(kind ? O_TR : O_TIME) + j*128 + o] = acc;
  ws[(kind ? TRANSO : TIMEO) + j*128 + o] = acc;
}

// ================= decoder stacks =================

__global__ void k_lin(float* __restrict__ ws, const float* __restrict__ lb,
                      int zoff, int ltoff, int R, int start, int dstoff){
  int e = blockIdx.x, tid = threadIdx.x;
  __shared__ float z[128];
  if (tid < 128) z[tid] = ws[zoff + e*128 + tid];
  __syncthreads();
  int s = tid >> 7, c = tid & 127;
  int r = c*start + s;
  float acc = lb[r];
  const float* lt = ws + ltoff;
  for (int k=0;k<128;++k) acc += z[k] * lt[k*R + r];
  ws[dstoff + e*(start<<7) + tid] = acc;   // (e, s, c) layout
}

template<int JT>
__global__ void k_convT(float* __restrict__ ws, const float* __restrict__ bias,
                        int srcoff, int dstoff, int wtoff, int Lin, int nJT){
  int e = blockIdx.x / nJT, jt = blockIdx.x - e*nJT;
  int j0 = jt*JT, o = threadIdx.x;
  const int SC = JT/2 + 2;
  __shared__ float xs[18*128];
  int s_lo = (j0 >> 1) - 1;
  const float* in = ws + srcoff + e*Lin*128;
  for (int idx=o; idx<SC*128; idx+=128){
    int si = idx >> 7, c = idx & 127, s = s_lo + si;
    xs[idx] = (s >= 0 && s < Lin) ? in[s*128 + c] : 0.f;
  }
  __syncthreads();
  float acc[JT];
#pragma unroll
  for (int jj=0;jj<JT;++jj) acc[jj] = bias[o];
  const float* wt = ws + wtoff;
  for (int c=0;c<128;++c){
    float w0 = wt[((c<<2)+0)*128 + o];
    float w1 = wt[((c<<2)+1)*128 + o];
    float w2 = wt[((c<<2)+2)*128 + o];
    float w3 = wt[((c<<2)+3)*128 + o];
#pragma unroll
    for (int jj=0;jj<JT;++jj){
      if ((jj & 1) == 0){
        acc[jj] += xs[((jj>>1)<<7) + c]*w3 + xs[(((jj>>1)+1)<<7) + c]*w1;
      } else {
        acc[jj] += xs[(((jj+1)>>1)<<7) + c]*w2 + xs[((((jj+1)>>1)+1)<<7) + c]*w0;
      }
    }
  }
  float* outp = ws + dstoff + e*(Lin*2)*128;
#pragma unroll
  for (int jj=0;jj<JT;++jj){
    float v = acc[jj];
    outp[(j0+jj)*128 + o] = v >= 0.f ? v : 0.2f*v;
  }
}

template<int JT>
__global__ void k_conv3up(float* __restrict__ ws, const float* __restrict__ bias,
                          int srcoff, int dstoff, int wtoff, int Lin, int nJT){
  int e = blockIdx.x / nJT, jt = blockIdx.x - e*nJT;
  int j0 = jt*JT, o = threadIdx.x;
  const int SC = JT/2 + 2;
  __shared__ float xs[18*128];
  int fs = (j0 >> 1) - 1;
  const float* in = ws + srcoff + e*Lin*128;
  for (int idx=o; idx<SC*128; idx+=128){
    int si = idx >> 7, c = idx & 127, s = fs + si;
    xs[idx] = (s >= 0 && s < Lin) ? in[s*128 + c] : 0.f;
  }
  __syncthreads();
  float acc[JT];
#pragma unroll
  for (int jj=0;jj<JT;++jj) acc[jj] = bias[o];
  const float* wt = ws + wtoff;
  for (int c=0;c<128;++c){
    float w0 = wt[(c*3+0)*128 + o];
    float w1 = wt[(c*3+1)*128 + o];
    float w2 = wt[(c*3+2)*128 + o];
#pragma unroll
    for (int jj=0;jj<JT;++jj){
      acc[jj] += xs[((((jj-1)>>1)+1)<<7) + c]*w0
               + xs[((((jj  )>>1)+1)<<7) + c]*w1
               + xs[((((jj+1)>>1)+1)<<7) + c]*w2;
    }
  }
  float* outp = ws + dstoff + e*(Lin*2)*128;
#pragma unroll
  for (int jj=0;jj<JT;++jj){
    float v = acc[jj];
    outp[(j0+jj)*128 + o] = v >= 0.f ? v : 0.2f*v;
  }
}

__global__ void k_out_pos(float* __restrict__ ws, const float* __restrict__ pw,
                          const float* __restrict__ pb){
  int e = blockIdx.x, tid = threadIdx.x;
  __shared__ float xs[16384];
  const float* in = ws + BUFB + e*16384;
  for (int idx=tid; idx<16384; idx+=128){
    int q = idx >> 7, c = idx & 127;
    xs[(q<<7) + ((c+q)&127)] = in[idx];   // swizzled store
  }
  __syncthreads();
  int j = tid;
  float acc = pb[0];
  for (int c=0;c<128;++c){
#pragma unroll
    for (int k=0;k<3;++k){
      int q = j + k - 1;
      if (q >= 0 && q < 128) acc += xs[(q<<7) + ((c+q)&127)] * pw[c*3 + k];
    }
  }
  // softmax over 128 lanes; reuse xs as scratch after barrier
  float m = acc;
  for (int o=32;o;o>>=1) m = fmaxf(m, __shfl_down(m, o));
  __syncthreads();
  if ((tid & 63) == 0) xs[tid>>6] = m;
  __syncthreads();
  m = fmaxf(xs[0], xs[1]);
  float ex = expf(__fsub_rn(acc, m));
  float s = ex;
  for (int o=32;o;o>>=1) s += __shfl_down(s, o);
  __syncthreads();
  if ((tid & 63) == 0) xs[2 + (tid>>6)] = s;
  __syncthreads();
  s = xs[2] + xs[3];
  ws[PE + e*128 + j] = __fdiv_rn(ex, s);
}

__global__ void k_out_env(float* __restrict__ ws, const float* __restrict__ ew,
                          const float* __restrict__ eb, float* __restrict__ out){
  int e = blockIdx.x >> 2, b0 = (blockIdx.x & 3) << 6, tid = threadIdx.x;
  __shared__ float xs[66*128];
  const float* in = ws + BUFA + e*32768;
  for (int idx=tid; idx<66*128; idx+=64){
    int qs = idx >> 7, c = idx & 127, q = b0 - 1 + qs;
    xs[(qs<<7) + ((c+qs)&127)] = (q >= 0 && q < 256) ? in[q*128 + c] : 0.f;
  }
  __syncthreads();
  int b = b0 + tid;
  float acc = eb[0];
  for (int c=0;c<128;++c){
#pragma unroll
    for (int k=0;k<3;++k){
      int qs = tid + k;
      acc += xs[(qs<<7) + ((c+qs)&127)] * ew[c*3 + k];
    }
  }
  acc = fmaxf(acc, 0.f);
  out[O_ENV + e*256 + b] = acc;
  ws[ENVO + e*256 + b] = acc;
}

__global__ void k_out_tfu(float* __restrict__ ws, const float* __restrict__ tw,
                          const float* __restrict__ tb_){
  int e = blockIdx.x, tid = threadIdx.x;
  __shared__ float xs[66*128];
  __shared__ float tf[2048];
  const float* in = ws + BUFB + e*8192;
  for (int idx=tid; idx<66*128; idx+=1024){
    int qs = idx >> 7, c = idx & 127, q = -1 + qs;
    xs[(qs<<7) + ((c+qs)&127)] = (q >= 0 && q < 64) ? in[q*128 + c] : 0.f;
  }
  __syncthreads();
  int r0 = tid >> 6, b = tid & 63;
  for (int rr=r0; rr<32; rr+=16){
    float acc = tb_[rr];
    for (int c=0;c<128;++c){
#pragma unroll
      for (int k=0;k<3;++k){
        int qs = b + k;
        acc += xs[(qs<<7) + ((c+qs)&127)] * tw[(rr*128 + c)*3 + k];
      }
    }
    tf[rr*64 + b] = acc;
  }
  __syncthreads();
  if (tid < 64){
    float best = tf[tid]; int bi = 0;
    for (int r=1;r<32;++r){ float v = tf[r*64 + tid]; if (v > best){ best = v; bi = r; } }
    ((int*)(ws + RSEL))[e*64 + tid] = bi;
  }
}

// ================= synthesis =================

__global__ void k_zero(float* __restrict__ ws){
  int i = blockIdx.x*1024 + threadIdx.x;          // 512 blocks x 1024
  ws[PART16 + i] = 0.f;
  if (i < 16*2048){
    int e = i >> 11, r = i & 2047;
    ((unsigned short*)(ws + KB))[e*34816 + r] = 0;
  }
  if (i < 16*128){
    int e = i >> 7, r = i & 127;
    if (r < 64) ((unsigned short*)(ws + CRB0))[e*32832 + (r==0 ? 0 : 32768 + r)] = 0;
    else        ((unsigned short*)(ws + CRB1))[e*32832 + 32768 + (r-64)] = 0;
  }
}

__global__ void k_sines(float* __restrict__ ws){
  int b = blockIdx.x >> 5;
  int t = ((blockIdx.x & 31) << 10) + threadIdx.x;
  float l0 = __fdiv_rn((float)log(20.0),   (float)log(10.0));
  float l1 = __fdiv_rn((float)log(9922.5), (float)log(10.0));
  float dl = __fdiv_rn(__fsub_rn(l1, l0), 63.0f);
  float lb = __fadd_rn(l0, __fmul_rn((float)b, dl));
  float freq = (float)pow(10.0, (double)lb);
  float w = __fmul_rn((float)(2.0*M_PI), freq);
  float tn = __fdiv_rn((float)t, 22050.0f);
  ws[SINES + b*NSAMP + t] = sinf(__fmul_rn(w, tn));
}

__global__ void k_envs(float* __restrict__ ws, const float* __restrict__ noise){
  int e = blockIdx.x >> 5;
  int tau = ((blockIdx.x & 31) << 10) + threadIdx.x;
  float cf = __fsub_rn(__fdiv_rn(__fmul_rn(__fadd_rn((float)tau, 0.5f), 256.0f), 32768.0f), 0.5f);
  float c = fminf(fmaxf(cf, 0.0f), 255.0f);
  int i0 = (int)floorf(c);
  int i1 = min(i0 + 1, 255);
  float w = __fsub_rn(c, (float)i0);
  float e0 = ws[ENVO + e*256 + i0], e1 = ws[ENVO + e*256 + i1];
  float val = __fadd_rn(__fmul_rn(e0, __fsub_rn(1.0f, w)), __fmul_rn(e1, w));
  ws[ENVS + e*NSAMP + tau] = val * noise[tau];
}

// impulse-comb conv; writes reversed bf16 copies (CRB0/CRB1) for the MFMA stage
__global__ void k_c(float* __restrict__ ws){
  int e = blockIdx.x >> 5, seg = blockIdx.x & 31;
  int t = (seg << 10) + threadIdx.x;
  __shared__ float pl[128];
  if (threadIdx.x < 128) pl[threadIdx.x] = ws[PE + e*128 + threadIdx.x];
  __syncthreads();
  const float* ev = ws + ENVS + e*NSAMP;
  int kub = min(127, (seg << 2) + 3);
  float acc = 0.f;
  for (int k=0;k<=kub;++k){
    int u = t - (k << 8);
    if (u >= 0) acc += pl[k] * ev[u];
  }
  unsigned short hv = f2bf(acc);
  ((unsigned short*)(ws + CRB0))[e*32832 + 32768 - t] = hv;
  ((unsigned short*)(ws + CRB1))[e*32832 + 32767 - t] = hv;
}

// resonance kernel K; writes bf16 (scaled) for the MFMA stage
__global__ void k_K(float* __restrict__ ws){
  int e = blockIdx.x >> 7, F = blockIdx.x & 127;
  int t = (F << 8) + threadIdx.x;
  __shared__ float ampl[64];
  if (threadIdx.x < 64){
    int r = ((const int*)(ws + RSEL))[e*64 + threadIdx.x];
    float d = __fadd_rn(0.5f, __fmul_rn((float)r, __fdiv_rn(__fsub_rn(0.9999f, 0.5f), 31.0f)));
    ampl[threadIdx.x] = (float)pow((double)d, (double)F);
  }
  __syncthreads();
  float acc = 0.f;
  for (int b=0;b<64;++b) acc += ws[SINES + b*NSAMP + t] * ampl[b];
  ((unsigned short*)(ws + KB))[e*34816 + 2048 + t] = f2bf(acc * (1.0f/(64.0f*65536.0f)));
}

// Toeplitz conv via MFMA 32x32x16 bf16.
// out[t0 + 2*i + p + 64*n] += sum_k A_p[i][k] * B[k][n]
//   A_p[i][k] = c[t0 - u0 + 2i + p - k]  (from reversed copies CRB0/CRB1, 4B-aligned)
//   B[k][n]   = K[u0 + 64n + k]
// 4352 equal wave-tasks (16 events x 272 segments of 64 steps).
__global__ void k_bigmfma(float* __restrict__ ws){
  int wave = (blockIdx.x << 2) + (threadIdx.x >> 6);
  int lane = threadIdx.x & 63;
  int e = wave / 272;
  int rem = wave - e*272;
  int T2 = 0;
  while (rem >= (T2+1)*(T2+2)) T2++;     // cumulative segs before tile T2 is T2*(T2+1)
  int seg = rem - T2*(T2+1);
  int t0 = T2 << 11;
  int il = lane & 31, h = lane >> 5;
  int u0 = -1984 + (seg << 10);          // 16 * (seg*64)
  const unsigned short* Kp  = (const unsigned short*)(ws + KB)   + e*34816 + 2048;
  const unsigned short* C0p = (const unsigned short*)(ws + CRB0) + e*32832;
  const unsigned short* C1p = (const unsigned short*)(ws + CRB1) + e*32832;
  int bB  = u0 + (il << 6) + (h << 3);
  int bA0 = 32768 - t0 + u0 - (il << 1) + (h << 3);
  int bA1 = bA0 - 2;
  f32x16 acc0 = {}; f32x16 acc1 = {};
#pragma unroll 2
  for (int q = 0; q < 64; ++q){
    union { f32x4 v; bf16x8 s; } a0u, a1u, bu;
    a0u.v = *(const f32x4*)(C0p + bA0);
    a1u.v = *(const f32x4*)(C1p + bA1);
    bu.v  = *(const f32x4*)(Kp  + bB);
    acc0 = __builtin_amdgcn_mfma_f32_32x32x16_bf16(a0u.s, bu.s, acc0, 0, 0, 0);
    acc1 = __builtin_amdgcn_mfma_f32_32x32x16_bf16(a1u.s, bu.s, acc1, 0, 0, 0);
    bA0 += 16; bA1 += 16; bB += 16;
  }
  float* P = ws + PART16 + e*32768 + t0 + (il << 6);
#pragma unroll
  for (int r = 0; r < 16; ++r){
    int row = (r & 3) + ((r >> 2) << 3) + (h << 2);
    atomicAdd(P + (row << 1),     acc0[r]);
    atomicAdd(P + (row << 1) + 1, acc1[r]);
  }
}

__global__ void k_final(const float* __restrict__ ws, float* __restrict__ out){
  int t = blockIdx.x*1024 + threadIdx.x;
  float s = 0.f;
  for (int i=0;i<16;++i) s += ws[PART16 + i*NSAMP + t];
  out[t] = s;
}

// ================= launcher =================

extern "C" void kernel_launch(void* const* d_in, const int* in_sizes, int n_in,
                              void* d_out, int out_size, void* d_ws, size_t ws_size,
                              hipStream_t stream){
  const float* x         = (const float*)d_in[0];
  const float* noise     = (const float*)d_in[1];
  const float* fb_w      = (const float*)d_in[2];
  const float* reduce_w  = (const float*)d_in[3];
  const float* reduce_b  = (const float*)d_in[4];
  const float* dl_dw     = (const float*)d_in[5];
  const float* dl_db     = (const float*)d_in[6];
  const float* dl_pw     = (const float*)d_in[7];
  const float* dl_pb     = (const float*)d_in[8];
  const float* tt_b      = (const float*)d_in[10];
  const float* tr_b      = (const float*)d_in[12];
  const float* pos_lin_w = (const float*)d_in[13];
  const float* pos_lin_b = (const float*)d_in[14];
  const float* pos_up_w  = (const float*)d_in[15];
  const float* pos_up_b  = (const float*)d_in[16];
  const float* pos_out_w = (const float*)d_in[17];
  const float* pos_out_b = (const float*)d_in[18];
  const float* env_lin_w = (const float*)d_in[19];
  const float* env_lin_b = (const float*)d_in[20];
  const float* env_up_w  = (const float*)d_in[21];
  const float* env_up_b  = (const float*)d_in[22];
  const float* env_out_w = (const float*)d_in[23];
  const float* env_out_b = (const float*)d_in[24];
  const float* tfu_lin_w = (const float*)d_in[25];
  const float* tfu_lin_b = (const float*)d_in[26];
  const float* tfu_up_w  = (const float*)d_in[27];
  const float* tfu_up_b  = (const float*)d_in[28];
  const float* tfu_out_w = (const float*)d_in[29];
  const float* tfu_out_b = (const float*)d_in[30];
  const float* tt_w      = (const float*)d_in[9];
  const float* tr_w      = (const float*)d_in[11];
  float* out = (float*)d_out;
  float* ws  = (float*)d_ws;

  k_zero<<<512, 1024, 0, stream>>>(ws);
  k_prefix<<<1, 1024, 0, stream>>>(x, ws);
  k_fbpool<<<4096, 512, 0, stream>>>(fb_w, ws);
  k_sumsq<<<1, 1024, 0, stream>>>(ws + HP, ws + NSQ);
  k_wtrans<<<1040, 1024, 0, stream>>>(pos_up_w, env_up_w, tfu_up_w, tt_w, tr_w,
                                      pos_lin_w, env_lin_w, tfu_lin_w, ws);
  k_reduce<<<128, 128, 0, stream>>>(reduce_w, reduce_b, ws);
  k_combW<<<640, 128, 0, stream>>>(dl_dw, dl_db, dl_pw, dl_pb, ws);
  const int DIL[5] = {1, 3, 9, 27, 1};
  int src = HA, dst = HB;
  for (int l=0;l<5;++l){
    k_dil<<<128, 128, 0, stream>>>(ws, l, DIL[l], src, dst);
    int tmp = src; src = dst; dst = tmp;
  }
  k_topk<<<1, 128, 0, stream>>>(ws, out);
  k_timetrans<<<32, 128, 0, stream>>>(ws, tt_b, tr_b, out);

  // pos stack (impulse placement)
  k_lin<<<16, 512, 0, stream>>>(ws, pos_lin_b, TIMEO, LT_POS, 512, 4, BUFA);
  k_convT<8> <<<16, 128, 0, stream>>>(ws, pos_up_b + 0,   BUFA, BUFB, WT_POS + 0,       4,  1);
  k_convT<16><<<16, 128, 0, stream>>>(ws, pos_up_b + 128, BUFB, BUFA, WT_POS + 65536,   8,  1);
  k_convT<32><<<16, 128, 0, stream>>>(ws, pos_up_b + 256, BUFA, BUFB, WT_POS + 131072, 16,  1);
  k_convT<32><<<32, 128, 0, stream>>>(ws, pos_up_b + 384, BUFB, BUFA, WT_POS + 196608, 32,  2);
  k_convT<32><<<64, 128, 0, stream>>>(ws, pos_up_b + 512, BUFA, BUFB, WT_POS + 262144, 64,  4);
  k_out_pos<<<16, 128, 0, stream>>>(ws, pos_out_w, pos_out_b);

  // env stack
  k_lin<<<16, 512, 0, stream>>>(ws, env_lin_b, TRANSO, LT_ENV, 512, 4, BUFA);
  k_conv3up<8> <<<16, 128, 0, stream>>>(ws, env_up_b + 0,   BUFA, BUFB, WT_ENV + 0,       4,  1);
  k_conv3up<16><<<16, 128, 0, stream>>>(ws, env_up_b + 128, BUFB, BUFA, WT_ENV + 49152,   8,  1);
  k_conv3up<32><<<16, 128, 0, stream>>>(ws, env_up_b + 256, BUFA, BUFB, WT_ENV + 98304,  16,  1);
  k_conv3up<32><<<32, 128, 0, stream>>>(ws, env_up_b + 384, BUFB, BUFA, WT_ENV + 147456, 32,  2);
  k_conv3up<32><<<64, 128, 0, stream>>>(ws, env_up_b + 512, BUFA, BUFB, WT_ENV + 196608, 64,  4);
  k_conv3up<32><<<128,128, 0, stream>>>(ws, env_up_b + 640, BUFB, BUFA, WT_ENV + 245760, 128, 8);
  k_out_env<<<64, 64, 0, stream>>>(ws, env_out_w, env_out_b, out);

  // tfu stack
  k_lin<<<16, 1024, 0, stream>>>(ws, tfu_lin_b, TRANSO, LT_TFU, 1024, 8, BUFA);
  k_conv3up<16><<<16, 128, 0, stream>>>(ws, tfu_up_b + 0,   BUFA, BUFB, WT_TFU + 0,      8,  1);
  k_conv3up<32><<<16, 128, 0, stream>>>(ws, tfu_up_b + 128, BUFB, BUFA, WT_TFU + 49152, 16,  1);
  k_conv3up<32><<<32, 128, 0, stream>>>(ws, tfu_up_b + 256, BUFA, BUFB, WT_TFU + 98304, 32,  2);
  k_out_tfu<<<16, 1024, 0, stream>>>(ws, tfu_out_w, tfu_out_b);

  // synthesis
  k_sines<<<2048, 1024, 0, stream>>>(ws);
  k_envs<<<512, 1024, 0, stream>>>(ws, noise);
  k_c<<<512, 1024, 0, stream>>>(ws);
  k_K<<<2048, 256, 0, stream>>>(ws);
  k_bigmfma<<<1088, 256, 0, stream>>>(ws);
  k_final<<<32, 1024, 0, stream>>>(ws, out);
}

// Round 3
// 1362.017 us; speedup vs baseline: 1.5191x; 1.2054x over previous
//
#include <hip/hip_runtime.h>
#include <math.h>

// ---------------- constants ----------------
#define NSAMP 32768
#define NFRM  128

// ---- ws layout (float offsets) ----
static constexpr int S_OFF  = 0;                   // 32772 (prefix sums, 32769 used)
static constexpr int HP     = 32772;               // 16384
static constexpr int NSQ    = HP + 16384;          // 16
static constexpr int HA     = NSQ + 16;            // 16384
static constexpr int HB     = HA + 16384;          // 16384
static constexpr int WC     = HB + 16384;          // 245760 combined dilated weights
static constexpr int WBC    = WC + 245760;         // 640 combined dilated bias
static constexpr int EWS    = WBC + 640;           // 2048 encoded
static constexpr int TIMEO  = EWS + 2048;          // 2048
static constexpr int TRANSO = TIMEO + 2048;        // 2048
static constexpr int PE     = TRANSO + 2048;       // 2048 softmax impulse weights
static constexpr int RSEL   = PE + 2048;           // 1024 (ints)
static constexpr int ENVO   = RSEL + 1024;         // 4096 env (16,256)
static constexpr int BUFA   = ENVO + 4096;         // 524288
static constexpr int BUFB   = BUFA + 524288;       // 524288
static constexpr int WT     = BUFB + 524288;       // transposed weights, 1064960 total
static constexpr int WT_POS = WT;                  // 327680  [l][(c*4+k)*128+o]
static constexpr int WT_ENV = WT + 327680;         // 294912  [l][(c*3+k)*128+o]
static constexpr int WT_TFU = WT + 622592;         // 147456
static constexpr int WT_TT  = WT + 770048;         // 16384   [c][o]
static constexpr int WT_TR  = WT + 786432;         // 16384
static constexpr int LT_POS = WT + 802816;         // 65536   [k][r], R=512
static constexpr int LT_ENV = WT + 868352;         // 65536
static constexpr int LT_TFU = WT + 933888;         // 131072  [k][r], R=1024
static constexpr int SINES  = WT + 1064960;        // 2097152 (64 x 32768)
static constexpr int ENVS   = SINES + 2097152;     // 524288 (16 x 32768 f32)
// SLAB overlays SINES+ENVS (both dead by the time k_bigmfma runs):
// 1152 slabs x 2048 f32 = 2359296 <= 2621440 available.
static constexpr int SLAB   = SINES;
// bf16 conv operands (ushort-indexed off these f32 offsets)
static constexpr int CRB0   = ENVS + 524288;       // 16 x 32832 ushort = 262656 f32 ; CRB0[x]=c[32768-x]
static constexpr int CRB1   = CRB0 + 262656;       // 16 x 32832 ushort ; CRB1[y]=c[32767-y]
static constexpr int KB     = CRB1 + 262656;       // 16 x 34816 ushort = 278528 f32 ; KB[2048+u]=K[u]

// ---- output offsets ----
static constexpr int O_IDX  = 32768;
static constexpr int O_ENC  = 32784;
static constexpr int O_ENV  = 34832;
static constexpr int O_TIME = 38928;
static constexpr int O_TR   = 40976;

typedef short bf16x8 __attribute__((ext_vector_type(8)));
typedef float f32x4  __attribute__((ext_vector_type(4)));
typedef float f32x16 __attribute__((ext_vector_type(16)));

static __device__ __forceinline__ unsigned short f2bf(float f){
  unsigned int u = __float_as_uint(f);
  unsigned int r = (u + 0x7FFFu + ((u >> 16) & 1u)) >> 16;
  return (unsigned short)r;
}

// ================= front-end =================

__global__ void k_prefix(const float* __restrict__ x, float* __restrict__ ws){
  float* S = ws + S_OFF;
  int tid = threadIdx.x;
  __shared__ float ps[1024];
  float v[32];
  const float4* x4 = (const float4*)(x + tid*32);
  float s = 0.f;
#pragma unroll
  for (int i=0;i<8;++i){
    float4 q = x4[i];
    v[4*i]=q.x; v[4*i+1]=q.y; v[4*i+2]=q.z; v[4*i+3]=q.w;
    s += q.x+q.y+q.z+q.w;
  }
  ps[tid] = s; __syncthreads();
  for (int ofs=1; ofs<1024; ofs<<=1){
    float add = (tid>=ofs)? ps[tid-ofs] : 0.f;
    __syncthreads();
    ps[tid] += add;
    __syncthreads();
  }
  float run = ps[tid] - s;   // exclusive prefix of chunks
#pragma unroll
  for (int i=0;i<32;++i){ S[tid*32+i] = run; run += v[i]; }
  if (tid==1023) S[32768] = ps[1023];
}

__global__ void k_fbpool(const float* __restrict__ fbw, float* __restrict__ ws){
  const float* S = ws + S_OFF;
  int c = blockIdx.x >> 5, j0 = (blockIdx.x & 31) << 2;
  int jj = threadIdx.x >> 7, kk = threadIdx.x & 127;
  int j = j0 + jj;
  int i0 = max(0, 256*j - 256), i1 = min(32767, 256*j + 255);
  float acc = 0.f;
#pragma unroll
  for (int m=0;m<4;++m){
    int k = kk + (m<<7);
    int hi = min(max(i1 + k - 255, 0), 32768);
    int lo = min(max(i0 + k - 256, 0), 32768);
    acc += fbw[c*512 + k] * (S[hi] - S[lo]);
  }
  for (int o=32;o;o>>=1) acc += __shfl_down(acc, o);
  __shared__ float red[8];
  if ((threadIdx.x & 63) == 0) red[threadIdx.x>>6] = acc;
  __syncthreads();
  if (threadIdx.x < 4)
    ws[HP + c*128 + j0 + threadIdx.x] = (red[2*threadIdx.x] + red[2*threadIdx.x+1]) * (1.0f/512.0f);
}

__global__ void k_sumsq(const float* __restrict__ a, float* __restrict__ dst){
  int tid = threadIdx.x;
  float s = 0.f;
  for (int i=tid;i<16384;i+=1024){ float v = a[i]; s += v*v; }
  for (int o=32;o;o>>=1) s += __shfl_down(s, o);
  __shared__ float red[16];
  if ((tid & 63) == 0) red[tid>>6] = s;
  __syncthreads();
  if (tid==0){ float t=0.f; for (int i=0;i<16;++i) t += red[i]; dst[0] = t; }
}

// one-shot transpose of all reused weight matrices
__global__ void k_wtrans(const float* __restrict__ posw, const float* __restrict__ envw,
                         const float* __restrict__ tfuw, const float* __restrict__ ttw,
                         const float* __restrict__ trw,  const float* __restrict__ lpw,
                         const float* __restrict__ lew,  const float* __restrict__ ltw,
                         float* __restrict__ ws){
  int i = blockIdx.x*1024 + threadIdx.x;
  float v;
  if (i < 327680){                       // pos_up (5,128,128,4) -> [l][(c*4+k)*128+o]
    int l = i>>16, r = i & 65535, o = r & 127, ck = r>>7, c = ck>>2, k = ck&3;
    v = posw[(l<<16) + (((o<<7)+c)<<2) + k];
  } else if (i < 622592){                // env_up (6,128,128,3)
    int i2 = i - 327680; int l = i2/49152, r = i2 - l*49152, o = r&127, ck = r>>7;
    int c = ck/3, k = ck - 3*c;
    v = envw[l*49152 + ((o<<7)+c)*3 + k];
  } else if (i < 770048){                // tfu_up (3,128,128,3)
    int i2 = i - 622592; int l = i2/49152, r = i2 - l*49152, o = r&127, ck = r>>7;
    int c = ck/3, k = ck - 3*c;
    v = tfuw[l*49152 + ((o<<7)+c)*3 + k];
  } else if (i < 786432){                // tt_w (128,128) -> [c][o]
    int i2 = i - 770048; int o = i2 & 127, c = i2 >> 7;
    v = ttw[(o<<7) + c];
  } else if (i < 802816){                // tr_w
    int i2 = i - 786432; int o = i2 & 127, c = i2 >> 7;
    v = trw[(o<<7) + c];
  } else if (i < 868352){                // pos_lin (512,128) -> [k][r]
    int i2 = i - 802816; int r = i2 & 511, k = i2 >> 9;
    v = lpw[(r<<7) + k];
  } else if (i < 933888){                // env_lin
    int i2 = i - 868352; int r = i2 & 511, k = i2 >> 9;
    v = lew[(r<<7) + k];
  } else {                               // tfu_lin (1024,128) -> [k][r]
    int i2 = i - 933888; int r = i2 & 1023, k = i2 >> 10;
    v = ltw[(r<<7) + k];
  }
  ws[WT + i] = v;
}

__global__ void k_reduce(const float* __restrict__ rw, const float* __restrict__ rb,
                         float* __restrict__ ws){
  int o = blockIdx.x, t = threadIdx.x;
  float g = sqrtf(ws[NSQ]) + 1e-8f;
  float acc = rb[o];
  const float* hp = ws + HP;
  for (int c=0;c<128;++c) acc += rw[o*161 + c] * __fdiv_rn(hp[c*128 + t], g);
  // positional encoding (exact replication of the f32 op sequence)
  float delta = __fdiv_rn(2.0f, 127.0f);
  float p = __fadd_rn(-1.0f, __fmul_rn((float)t, delta));
  acc += rw[o*161 + 128] * p;
  float sc = 1.0f;
  const float PIF = (float)M_PI;
#pragma unroll
  for (int i=0;i<16;++i){
    float f = __fmul_rn(__fmul_rn(p, sc), PIF);
    acc += rw[o*161 + 129 + 2*i] * sinf(f);
    acc += rw[o*161 + 130 + 2*i] * cosf(f);
    sc = sc * 2.0f;
  }
  ws[HA + o*128 + t] = acc;
}

__global__ void k_combW(const float* __restrict__ dw, const float* __restrict__ db,
                        const float* __restrict__ pw, const float* __restrict__ pb,
                        float* __restrict__ ws){
  int l = blockIdx.x >> 7, o = blockIdx.x & 127, c = threadIdx.x;
  float a0=0.f, a1=0.f, a2=0.f;
  for (int m=0;m<128;++m){
    float p = pw[(l*128 + o)*128 + m];
    const float* dp = dw + ((l*128 + m)*128 + c)*3;
    a0 += p*dp[0]; a1 += p*dp[1]; a2 += p*dp[2];
  }
  float* W = ws + WC + ((l*128 + o)*128 + c)*3;
  W[0]=a0; W[1]=a1; W[2]=a2;
  if (c==0){
    float b = pb[l*128 + o];
    for (int m=0;m<128;++m) b += pw[(l*128 + o)*128 + m] * db[l*128 + m];
    ws[WBC + l*128 + o] = b;
  }
}

__global__ void k_dil(float* __restrict__ ws, int l, int d, int inoff, int outoff){
  int o = blockIdx.x, t = threadIdx.x;
  const float* in = ws + inoff;
  const float* Wo = ws + WC + (l*128 + o)*384;
  float acc = in[o*128 + t] + ws[WBC + l*128 + o];
  for (int c=0;c<128;++c){
    float v0 = (t-d >= 0)  ? in[c*128 + t - d] : 0.f;
    float v1 = in[c*128 + t];
    float v2 = (t+d < 128) ? in[c*128 + t + d] : 0.f;
    acc += Wo[c*3]*v0 + Wo[c*3+1]*v1 + Wo[c*3+2]*v2;
  }
  ws[outoff + o*128 + t] = acc >= 0.f ? acc : 0.2f*acc;
}

__global__ void k_topk(float* __restrict__ ws, float* __restrict__ out){
  const float* h = ws + HB;
  int t = threadIdx.x;
  __shared__ float nt[128], nt0[128];
  __shared__ int idxs[16];
  __shared__ float r2[2];
  __shared__ float wv[2]; __shared__ int wi[2];
  float colsq = 0.f;
  for (int c=0;c<128;++c){ float v = h[c*128 + t]; colsq += v*v; }
  float s = colsq;
  for (int o=32;o;o>>=1) s += __shfl_down(s, o);
  if ((t & 63) == 0) r2[t>>6] = s;
  __syncthreads();
  float g2 = sqrtf(r2[0] + r2[1]) + 1e-8f;
  float sq2 = 0.f;
  for (int c=0;c<128;++c){ float v = __fdiv_rn(h[c*128 + t], g2); sq2 += v*v; }
  float ntv = sqrtf(sq2);
  nt[t] = ntv; nt0[t] = ntv;
  __syncthreads();
  for (int j=0;j<16;++j){
    float v = nt[t]; int bi = t;
    for (int o=32;o;o>>=1){
      float ov = __shfl_down(v, o); int oi = __shfl_down(bi, o);
      if (ov > v || (ov == v && oi < bi)){ v = ov; bi = oi; }
    }
    if ((t & 63) == 0){ wv[t>>6] = v; wi[t>>6] = bi; }
    __syncthreads();
    if (t == 0){
      int win = (wv[1] > wv[0] || (wv[1] == wv[0] && wi[1] < wi[0])) ? wi[1] : wi[0];
      idxs[j] = win; nt[win] = -3.0e38f;
    }
    __syncthreads();
  }
  if (t < 16) out[O_IDX + t] = (float)idxs[t];
  for (int j=0;j<16;++j){
    int ij = idxs[j];
    float hv = __fdiv_rn(h[t*128 + ij], g2);
    float enc = __fdiv_rn(hv, nt0[ij] + 1e-8f);
    out[O_ENC + j*128 + t] = enc;
    ws[EWS + j*128 + t] = enc;
  }
}

__global__ void k_timetrans(float* __restrict__ ws, const float* __restrict__ ttb,
                            const float* __restrict__ trb, float* __restrict__ out){
  int kind = blockIdx.x >> 4, j = blockIdx.x & 15, o = threadIdx.x;
  __shared__ float er[128];
  er[o] = ws[EWS + j*128 + o];
  __syncthreads();
  const float* Wt = ws + (kind ? WT_TR : WT_TT);
  float acc = kind ? trb[o] : ttb[o];
  for (int c=0;c<128;++c) acc += er[c] * Wt[c*128 + o];
  out[(kind ? O_TR : O_TIME) + j*128 + o] = acc;
  ws[(kind ? TRANSO : TIMEO) + j*128 + o] = acc;
}

// ================= decoder stacks =================

__global__ void k_lin(float* __restrict__ ws, const float* __restrict__ lb,
                      int zoff, int ltoff, int R, int start, int dstoff){
  int e = blockIdx.x, tid = threadIdx.x;
  __shared__ float z[128];
  if (tid < 128) z[tid] = ws[zoff + e*128 + tid];
  __syncthreads();
  int s = tid >> 7, c = tid & 127;
  int r = c*start + s;
  float acc = lb[r];
  const float* lt = ws + ltoff;
  for (int k=0;k<128;++k) acc += z[k] * lt[k*R + r];
  ws[dstoff + e*(start<<7) + tid] = acc;   // (e, s, c) layout
}

template<int JT>
__global__ void k_convT(float* __restrict__ ws, const float* __restrict__ bias,
                        int srcoff, int dstoff, int wtoff, int Lin, int nJT){
  int e = blockIdx.x / nJT, jt = blockIdx.x - e*nJT;
  int j0 = jt*JT, o = threadIdx.x;
  const int SC = JT/2 + 2;
  __shared__ float xs[18*128];
  int s_lo = (j0 >> 1) - 1;
  const float* in = ws + srcoff + e*Lin*128;
  for (int idx=o; idx<SC*128; idx+=128){
    int si = idx >> 7, c = idx & 127, s = s_lo + si;
    xs[idx] = (s >= 0 && s < Lin) ? in[s*128 + c] : 0.f;
  }
  __syncthreads();
  float acc[JT];
#pragma unroll
  for (int jj=0;jj<JT;++jj) acc[jj] = bias[o];
  const float* wt = ws + wtoff;
  for (int c=0;c<128;++c){
    float w0 = wt[((c<<2)+0)*128 + o];
    float w1 = wt[((c<<2)+1)*128 + o];
    float w2 = wt[((c<<2)+2)*128 + o];
    float w3 = wt[((c<<2)+3)*128 + o];
#pragma unroll
    for (int jj=0;jj<JT;++jj){
      if ((jj & 1) == 0){
        acc[jj] += xs[((jj>>1)<<7) + c]*w3 + xs[(((jj>>1)+1)<<7) + c]*w1;
      } else {
        acc[jj] += xs[(((jj+1)>>1)<<7) + c]*w2 + xs[((((jj+1)>>1)+1)<<7) + c]*w0;
      }
    }
  }
  float* outp = ws + dstoff + e*(Lin*2)*128;
#pragma unroll
  for (int jj=0;jj<JT;++jj){
    float v = acc[jj];
    outp[(j0+jj)*128 + o] = v >= 0.f ? v : 0.2f*v;
  }
}

template<int JT>
__global__ void k_conv3up(float* __restrict__ ws, const float* __restrict__ bias,
                          int srcoff, int dstoff, int wtoff, int Lin, int nJT){
  int e = blockIdx.x / nJT, jt = blockIdx.x - e*nJT;
  int j0 = jt*JT, o = threadIdx.x;
  const int SC = JT/2 + 2;
  __shared__ float xs[18*128];
  int fs = (j0 >> 1) - 1;
  const float* in = ws + srcoff + e*Lin*128;
  for (int idx=o; idx<SC*128; idx+=128){
    int si = idx >> 7, c = idx & 127, s = fs + si;
    xs[idx] = (s >= 0 && s < Lin) ? in[s*128 + c] : 0.f;
  }
  __syncthreads();
  float acc[JT];
#pragma unroll
  for (int jj=0;jj<JT;++jj) acc[jj] = bias[o];
  const float* wt = ws + wtoff;
  for (int c=0;c<128;++c){
    float w0 = wt[(c*3+0)*128 + o];
    float w1 = wt[(c*3+1)*128 + o];
    float w2 = wt[(c*3+2)*128 + o];
#pragma unroll
    for (int jj=0;jj<JT;++jj){
      acc[jj] += xs[((((jj-1)>>1)+1)<<7) + c]*w0
               + xs[((((jj  )>>1)+1)<<7) + c]*w1
               + xs[((((jj+1)>>1)+1)<<7) + c]*w2;
    }
  }
  float* outp = ws + dstoff + e*(Lin*2)*128;
#pragma unroll
  for (int jj=0;jj<JT;++jj){
    float v = acc[jj];
    outp[(j0+jj)*128 + o] = v >= 0.f ? v : 0.2f*v;
  }
}

__global__ void k_out_pos(float* __restrict__ ws, const float* __restrict__ pw,
                          const float* __restrict__ pb){
  int e = blockIdx.x, tid = threadIdx.x;
  __shared__ float xs[16384];
  const float* in = ws + BUFB + e*16384;
  for (int idx=tid; idx<16384; idx+=128){
    int q = idx >> 7, c = idx & 127;
    xs[(q<<7) + ((c+q)&127)] = in[idx];   // swizzled store
  }
  __syncthreads();
  int j = tid;
  float acc = pb[0];
  for (int c=0;c<128;++c){
#pragma unroll
    for (int k=0;k<3;++k){
      int q = j + k - 1;
      if (q >= 0 && q < 128) acc += xs[(q<<7) + ((c+q)&127)] * pw[c*3 + k];
    }
  }
  // softmax over 128 lanes; reuse xs as scratch after barrier
  float m = acc;
  for (int o=32;o;o>>=1) m = fmaxf(m, __shfl_down(m, o));
  __syncthreads();
  if ((tid & 63) == 0) xs[tid>>6] = m;
  __syncthreads();
  m = fmaxf(xs[0], xs[1]);
  float ex = expf(__fsub_rn(acc, m));
  float s = ex;
  for (int o=32;o;o>>=1) s += __shfl_down(s, o);
  __syncthreads();
  if ((tid & 63) == 0) xs[2 + (tid>>6)] = s;
  __syncthreads();
  s = xs[2] + xs[3];
  ws[PE + e*128 + j] = __fdiv_rn(ex, s);
}

__global__ void k_out_env(float* __restrict__ ws, const float* __restrict__ ew,
                          const float* __restrict__ eb, float* __restrict__ out){
  int e = blockIdx.x >> 2, b0 = (blockIdx.x & 3) << 6, tid = threadIdx.x;
  __shared__ float xs[66*128];
  const float* in = ws + BUFA + e*32768;
  for (int idx=tid; idx<66*128; idx+=64){
    int qs = idx >> 7, c = idx & 127, q = b0 - 1 + qs;
    xs[(qs<<7) + ((c+qs)&127)] = (q >= 0 && q < 256) ? in[q*128 + c] : 0.f;
  }
  __syncthreads();
  int b = b0 + tid;
  float acc = eb[0];
  for (int c=0;c<128;++c){
#pragma unroll
    for (int k=0;k<3;++k){
      int qs = tid + k;
      acc += xs[(qs<<7) + ((c+qs)&127)] * ew[c*3 + k];
    }
  }
  acc = fmaxf(acc, 0.f);
  out[O_ENV + e*256 + b] = acc;
  ws[ENVO + e*256 + b] = acc;
}

__global__ void k_out_tfu(float* __restrict__ ws, const float* __restrict__ tw,
                          const float* __restrict__ tb_){
  int e = blockIdx.x, tid = threadIdx.x;
  __shared__ float xs[66*128];
  __shared__ float tf[2048];
  const float* in = ws + BUFB + e*8192;
  for (int idx=tid; idx<66*128; idx+=1024){
    int qs = idx >> 7, c = idx & 127, q = -1 + qs;
    xs[(qs<<7) + ((c+qs)&127)] = (q >= 0 && q < 64) ? in[q*128 + c] : 0.f;
  }
  __syncthreads();
  int r0 = tid >> 6, b = tid & 63;
  for (int rr=r0; rr<32; rr+=16){
    float acc = tb_[rr];
    for (int c=0;c<128;++c){
#pragma unroll
      for (int k=0;k<3;++k){
        int qs = b + k;
        acc += xs[(qs<<7) + ((c+qs)&127)] * tw[(rr*128 + c)*3 + k];
      }
    }
    tf[rr*64 + b] = acc;
  }
  __syncthreads();
  if (tid < 64){
    float best = tf[tid]; int bi = 0;
    for (int r=1;r<32;++r){ float v = tf[r*64 + tid]; if (v > best){ best = v; bi = r; } }
    ((int*)(ws + RSEL))[e*64 + tid] = bi;
  }
}

// ================= synthesis =================

__global__ void k_zero(float* __restrict__ ws){
  int i = blockIdx.x*1024 + threadIdx.x;          // 32 blocks x 1024
  if (i < 16*2048){
    int e = i >> 11, r = i & 2047;
    ((unsigned short*)(ws + KB))[e*34816 + r] = 0;
  }
  if (i < 16*128){
    int e = i >> 7, r = i & 127;
    if (r < 64) ((unsigned short*)(ws + CRB0))[e*32832 + (r==0 ? 0 : 32768 + r)] = 0;
    else        ((unsigned short*)(ws + CRB1))[e*32832 + 32768 + (r-64)] = 0;
  }
}

__global__ void k_sines(float* __restrict__ ws){
  int b = blockIdx.x >> 5;
  int t = ((blockIdx.x & 31) << 10) + threadIdx.x;
  float l0 = __fdiv_rn((float)log(20.0),   (float)log(10.0));
  float l1 = __fdiv_rn((float)log(9922.5), (float)log(10.0));
  float dl = __fdiv_rn(__fsub_rn(l1, l0), 63.0f);
  float lb = __fadd_rn(l0, __fmul_rn((float)b, dl));
  float freq = (float)pow(10.0, (double)lb);
  float w = __fmul_rn((float)(2.0*M_PI), freq);
  float tn = __fdiv_rn((float)t, 22050.0f);
  ws[SINES + b*NSAMP + t] = sinf(__fmul_rn(w, tn));
}

__global__ void k_envs(float* __restrict__ ws, const float* __restrict__ noise){
  int e = blockIdx.x >> 5;
  int tau = ((blockIdx.x & 31) << 10) + threadIdx.x;
  float cf = __fsub_rn(__fdiv_rn(__fmul_rn(__fadd_rn((float)tau, 0.5f), 256.0f), 32768.0f), 0.5f);
  float c = fminf(fmaxf(cf, 0.0f), 255.0f);
  int i0 = (int)floorf(c);
  int i1 = min(i0 + 1, 255);
  float w = __fsub_rn(c, (float)i0);
  float e0 = ws[ENVO + e*256 + i0], e1 = ws[ENVO + e*256 + i1];
  float val = __fadd_rn(__fmul_rn(e0, __fsub_rn(1.0f, w)), __fmul_rn(e1, w));
  ws[ENVS + e*NSAMP + tau] = val * noise[tau];
}

// impulse-comb conv; writes reversed bf16 copies (CRB0/CRB1) for the MFMA stage
__global__ void k_c(float* __restrict__ ws){
  int e = blockIdx.x >> 5, seg = blockIdx.x & 31;
  int t = (seg << 10) + threadIdx.x;
  __shared__ float pl[128];
  if (threadIdx.x < 128) pl[threadIdx.x] = ws[PE + e*128 + threadIdx.x];
  __syncthreads();
  const float* ev = ws + ENVS + e*NSAMP;
  int kub = min(127, (seg << 2) + 3);
  float acc = 0.f;
  for (int k=0;k<=kub;++k){
    int u = t - (k << 8);
    if (u >= 0) acc += pl[k] * ev[u];
  }
  unsigned short hv = f2bf(acc);
  ((unsigned short*)(ws + CRB0))[e*32832 + 32768 - t] = hv;
  ((unsigned short*)(ws + CRB1))[e*32832 + 32767 - t] = hv;
}

// resonance kernel K; writes bf16 (scaled) for the MFMA stage
__global__ void k_K(float* __restrict__ ws){
  int e = blockIdx.x >> 7, F = blockIdx.x & 127;
  int t = (F << 8) + threadIdx.x;
  __shared__ float ampl[64];
  if (threadIdx.x < 64){
    int r = ((const int*)(ws + RSEL))[e*64 + threadIdx.x];
    float d = __fadd_rn(0.5f, __fmul_rn((float)r, __fdiv_rn(__fsub_rn(0.9999f, 0.5f), 31.0f)));
    ampl[threadIdx.x] = (float)pow((double)d, (double)F);
  }
  __syncthreads();
  float acc = 0.f;
  for (int b=0;b<64;++b) acc += ws[SINES + b*NSAMP + t] * ampl[b];
  ((unsigned short*)(ws + KB))[e*34816 + 2048 + t] = f2bf(acc * (1.0f/(64.0f*65536.0f)));
}

// Toeplitz conv via MFMA 32x32x16 bf16, block-level reduction, no atomics.
// Block = (event e, tile T2, quarter qb); 4 waves take segments qb*4+w.
// out[t0 + 2*i + p + 64*n] += sum_k A_p[i][k] * B[k][n]
//   A_p[i][k] = c[t0 - u0 + 2i + p - k]  (reversed copies CRB0/CRB1, 4B-aligned)
//   B[k][n]   = K[u0 + 64n + k]
// Tile T2 has 2*(T2+1) segments; nblk(T2)=ceil((T2+1)/2) blocks; 72 blocks/event.
__global__ __launch_bounds__(256, 2)
void k_bigmfma(float* __restrict__ ws){
  int b = blockIdx.x;
  int w = threadIdx.x >> 6;
  int lane = threadIdx.x & 63;
  int e = b / 72;
  int r = b - e*72;
  int T2 = 0, cum = 0;
  while (cum + ((T2+2)>>1) <= r){ cum += (T2+2)>>1; T2++; }
  int qb = r - cum;
  int nseg = 2*(T2+1);
  int seg = qb*4 + w;
  int t0 = T2 << 11;
  int il = lane & 31, h = lane >> 5;
  __shared__ float red[4*2048];
  f32x16 acc0 = {}; f32x16 acc1 = {};
  if (seg < nseg){
    int u0 = -1984 + (seg << 10);
    const unsigned short* Kp  = (const unsigned short*)(ws + KB)   + e*34816 + 2048;
    const unsigned short* C0p = (const unsigned short*)(ws + CRB0) + e*32832;
    const unsigned short* C1p = (const unsigned short*)(ws + CRB1) + e*32832;
    int bB  = u0 + (il << 6) + (h << 3);
    int bA0 = 32768 - t0 + u0 - (il << 1) + (h << 3);
    int bA1 = bA0 - 2;
#pragma unroll 2
    for (int q = 0; q < 64; ++q){
      union { f32x4 v; bf16x8 s; } a0u, a1u, bu;
      a0u.v = *(const f32x4*)(C0p + bA0);
      a1u.v = *(const f32x4*)(C1p + bA1);
      bu.v  = *(const f32x4*)(Kp  + bB);
      acc0 = __builtin_amdgcn_mfma_f32_32x32x16_bf16(a0u.s, bu.s, acc0, 0, 0, 0);
      acc1 = __builtin_amdgcn_mfma_f32_32x32x16_bf16(a1u.s, bu.s, acc1, 0, 0, 0);
      bA0 += 16; bA1 += 16; bB += 16;
    }
  }
  // LDS layout: red[w][row*64 + p*32 + il]  (2 lanes/bank on store: free)
  float* rw_ = red + w*2048;
#pragma unroll
  for (int rr = 0; rr < 16; ++rr){
    int row = (rr & 3) + ((rr >> 2) << 3) + (h << 2);
    rw_[(row << 6) + il]      = acc0[rr];
    rw_[(row << 6) + 32 + il] = acc1[rr];
  }
  __syncthreads();
  // cross-wave reduction + coalesced slab store
  float* slab = ws + SLAB + b*2048;
  int tid = threadIdx.x;
#pragma unroll
  for (int jj = 0; jj < 8; ++jj){
    int pos = tid*8 + jj;                // pos = il2*64 + (2*row + p)
    int il2 = pos >> 6, x = pos & 63;
    int idx = ((x >> 1) << 6) + ((x & 1) << 5) + il2;
    slab[pos] = red[idx] + red[2048+idx] + red[4096+idx] + red[6144+idx];
  }
}

__global__ void k_final(const float* __restrict__ ws, float* __restrict__ out){
  int t = blockIdx.x*1024 + threadIdx.x;
  int T2 = t >> 11, pos = t & 2047;     // T2 uniform within a block
  int cum = 0;
  for (int j=0;j<T2;++j) cum += (j+2)>>1;
  int nb = (T2+2)>>1;
  float s = 0.f;
  for (int e=0;e<16;++e){
    const float* sl = ws + SLAB + (e*72 + cum)*2048 + pos;
    for (int q=0;q<nb;++q) s += sl[q*2048];
  }
  out[t] = s;
}

// ================= launcher =================

extern "C" void kernel_launch(void* const* d_in, const int* in_sizes, int n_in,
                              void* d_out, int out_size, void* d_ws, size_t ws_size,
                              hipStream_t stream){
  const float* x         = (const float*)d_in[0];
  const float* noise     = (const float*)d_in[1];
  const float* fb_w      = (const float*)d_in[2];
  const float* reduce_w  = (const float*)d_in[3];
  const float* reduce_b  = (const float*)d_in[4];
  const float* dl_dw     = (const float*)d_in[5];
  const float* dl_db     = (const float*)d_in[6];
  const float* dl_pw     = (const float*)d_in[7];
  const float* dl_pb     = (const float*)d_in[8];
  const float* tt_b      = (const float*)d_in[10];
  const float* tr_b      = (const float*)d_in[12];
  const float* pos_lin_w = (const float*)d_in[13];
  const float* pos_lin_b = (const float*)d_in[14];
  const float* pos_up_w  = (const float*)d_in[15];
  const float* pos_up_b  = (const float*)d_in[16];
  const float* pos_out_w = (const float*)d_in[17];
  const float* pos_out_b = (const float*)d_in[18];
  const float* env_lin_w = (const float*)d_in[19];
  const float* env_lin_b = (const float*)d_in[20];
  const float* env_up_w  = (const float*)d_in[21];
  const float* env_up_b  = (const float*)d_in[22];
  const float* env_out_w = (const float*)d_in[23];
  const float* env_out_b = (const float*)d_in[24];
  const float* tfu_lin_w = (const float*)d_in[25];
  const float* tfu_lin_b = (const float*)d_in[26];
  const float* tfu_up_w  = (const float*)d_in[27];
  const float* tfu_up_b  = (const float*)d_in[28];
  const float* tfu_out_w = (const float*)d_in[29];
  const float* tfu_out_b = (const float*)d_in[30];
  const float* tt_w      = (const float*)d_in[9];
  const float* tr_w      = (const float*)d_in[11];
  float* out = (float*)d_out;
  float* ws  = (float*)d_ws;

  k_zero<<<32, 1024, 0, stream>>>(ws);
  k_prefix<<<1, 1024, 0, stream>>>(x, ws);
  k_fbpool<<<4096, 512, 0, stream>>>(fb_w, ws);
  k_sumsq<<<1, 1024, 0, stream>>>(ws + HP, ws + NSQ);
  k_wtrans<<<1040, 1024, 0, stream>>>(pos_up_w, env_up_w, tfu_up_w, tt_w, tr_w,
                                      pos_lin_w, env_lin_w, tfu_lin_w, ws);
  k_reduce<<<128, 128, 0, stream>>>(reduce_w, reduce_b, ws);
  k_combW<<<640, 128, 0, stream>>>(dl_dw, dl_db, dl_pw, dl_pb, ws);
  const int DIL[5] = {1, 3, 9, 27, 1};
  int src = HA, dst = HB;
  for (int l=0;l<5;++l){
    k_dil<<<128, 128, 0, stream>>>(ws, l, DIL[l], src, dst);
    int tmp = src; src = dst; dst = tmp;
  }
  k_topk<<<1, 128, 0, stream>>>(ws, out);
  k_timetrans<<<32, 128, 0, stream>>>(ws, tt_b, tr_b, out);

  // pos stack (impulse placement)
  k_lin<<<16, 512, 0, stream>>>(ws, pos_lin_b, TIMEO, LT_POS, 512, 4, BUFA);
  k_convT<8> <<<16, 128, 0, stream>>>(ws, pos_up_b + 0,   BUFA, BUFB, WT_POS + 0,       4,  1);
  k_convT<16><<<16, 128, 0, stream>>>(ws, pos_up_b + 128, BUFB, BUFA, WT_POS + 65536,   8,  1);
  k_convT<32><<<16, 128, 0, stream>>>(ws, pos_up_b + 256, BUFA, BUFB, WT_POS + 131072, 16,  1);
  k_convT<32><<<32, 128, 0, stream>>>(ws, pos_up_b + 384, BUFB, BUFA, WT_POS + 196608, 32,  2);
  k_convT<32><<<64, 128, 0, stream>>>(ws, pos_up_b + 512, BUFA, BUFB, WT_POS + 262144, 64,  4);
  k_out_pos<<<16, 128, 0, stream>>>(ws, pos_out_w, pos_out_b);

  // env stack
  k_lin<<<16, 512, 0, stream>>>(ws, env_lin_b, TRANSO, LT_ENV, 512, 4, BUFA);
  k_conv3up<8> <<<16, 128, 0, stream>>>(ws, env_up_b + 0,   BUFA, BUFB, WT_ENV + 0,       4,  1);
  k_conv3up<16><<<16, 128, 0, stream>>>(ws, env_up_b + 128, BUFB, BUFA, WT_ENV + 49152,   8,  1);
  k_conv3up<32><<<16, 128, 0, stream>>>(ws, env_up_b + 256, BUFA, BUFB, WT_ENV + 98304,  16,  1);
  k_conv3up<32><<<32, 128, 0, stream>>>(ws, env_up_b + 384, BUFB, BUFA, WT_ENV + 147456, 32,  2);
  k_conv3up<32><<<64, 128, 0, stream>>>(ws, env_up_b + 512, BUFA, BUFB, WT_ENV + 196608, 64,  4);
  k_conv3up<32><<<128,128, 0, stream>>>(ws, env_up_b + 640, BUFB, BUFA, WT_ENV + 245760, 128, 8);
  k_out_env<<<64, 64, 0, stream>>>(ws, env_out_w, env_out_b, out);

  // tfu stack
  k_lin<<<16, 1024, 0, stream>>>(ws, tfu_lin_b, TRANSO, LT_TFU, 1024, 8, BUFA);
  k_conv3up<16><<<16, 128, 0, stream>>>(ws, tfu_up_b + 0,   BUFA, BUFB, WT_TFU + 0,      8,  1);
  k_conv3up<32><<<16, 128, 0, stream>>>(ws, tfu_up_b + 128, BUFB, BUFA, WT_TFU + 49152, 16,  1);
  k_conv3up<32><<<32, 128, 0, stream>>>(ws, tfu_up_b + 256, BUFA, BUFB, WT_TFU + 98304, 32,  2);
  k_out_tfu<<<16, 1024, 0, stream>>>(ws, tfu_out_w, tfu_out_b);

  // synthesis
  k_sines<<<2048, 1024, 0, stream>>>(ws);
  k_envs<<<512, 1024, 0, stream>>>(ws, noise);
  k_c<<<512, 1024, 0, stream>>>(ws);
  k_K<<<2048, 256, 0, stream>>>(ws);
  k_bigmfma<<<1152, 256, 0, stream>>>(ws);
  k_final<<<32, 1024, 0, stream>>>(ws, out);
}

// Round 4
// 960.748 us; speedup vs baseline: 2.1535x; 1.4177x over previous
//
#include <hip/hip_runtime.h>
#include <math.h>

// ---------------- constants ----------------
#define NSAMP 32768
#define NFRM  128

// ---- ws layout (float offsets) ----
static constexpr int S_OFF  = 0;                   // 32772 (prefix sums, 32769 used)
static constexpr int HP     = 32772;               // 16384
static constexpr int NSQ    = HP + 16384;          // 16 (unused now)
static constexpr int HA     = NSQ + 16;            // 16384
static constexpr int HB     = HA + 16384;          // 16384
static constexpr int WC     = HB + 16384;          // 245760 combined dilated weights
static constexpr int WBC    = WC + 245760;         // 640 combined dilated bias
static constexpr int EWS    = WBC + 640;           // 2048 (unused now)
static constexpr int TIMEO  = EWS + 2048;          // 2048
static constexpr int TRANSO = TIMEO + 2048;        // 2048
static constexpr int PE     = TRANSO + 2048;       // 2048 softmax impulse weights
static constexpr int RSEL   = PE + 2048;           // 1024 (ints)
static constexpr int ENVO   = RSEL + 1024;         // 4096 env (16,256)
static constexpr int BUFA   = ENVO + 4096;         // 524288  (env stack A)
static constexpr int BUFB   = BUFA + 524288;       // 524288  (env stack B)
static constexpr int WT     = BUFB + 524288;       // transposed weights, 1064960 total
static constexpr int WT_POS = WT;                  // 327680  [l][(c*4+k)*128+o]
static constexpr int WT_ENV = WT + 327680;         // 294912  [l][(c*3+k)*128+o]
static constexpr int WT_TFU = WT + 622592;         // 147456
static constexpr int WT_TT  = WT + 770048;         // 16384   [c][o]
static constexpr int WT_TR  = WT + 786432;         // 16384
static constexpr int LT_POS = WT + 802816;         // 65536   [k][r], R=512
static constexpr int LT_ENV = WT + 868352;         // 65536
static constexpr int LT_TFU = WT + 933888;         // 131072  [k][r], R=1024
static constexpr int SINES  = WT + 1064960;        // 2097152 (64 x 32768)
static constexpr int ENVS   = SINES + 2097152;     // 524288 (16 x 32768 f32)
// SLAB overlays SINES+ENVS (both dead once k_bigmfma runs):
// 1152 slabs x 2048 f32 = 2359296 <= 2621440 available.
static constexpr int SLAB   = SINES;
// bf16 conv operands (ushort-indexed off these f32 offsets)
static constexpr int CRB0   = ENVS + 524288;       // 16 x 32832 ushort ; CRB0[x]=c[32768-x]
static constexpr int CRB1   = CRB0 + 262656;       // 16 x 32832 ushort ; CRB1[y]=c[32767-y]
static constexpr int KB     = CRB1 + 262656;       // 16 x 34816 ushort ; KB[2048+u]=K[u]
// pos / tfu stack ping-pong buffers (disjoint from env's BUFA/BUFB)
static constexpr int PA     = KB + 278528;         // 262144
static constexpr int PB     = PA + 262144;         // 262144
static constexpr int TA     = PB + 262144;         // 131072
static constexpr int TB     = TA + 131072;         // 131072

// ---- output offsets ----
static constexpr int O_IDX  = 32768;
static constexpr int O_ENC  = 32784;
static constexpr int O_ENV  = 34832;
static constexpr int O_TIME = 38928;
static constexpr int O_TR   = 40976;

typedef short bf16x8 __attribute__((ext_vector_type(8)));
typedef float f32x4  __attribute__((ext_vector_type(4)));
typedef float f32x16 __attribute__((ext_vector_type(16)));

static __device__ __forceinline__ unsigned short f2bf(float f){
  unsigned int u = __float_as_uint(f);
  unsigned int r = (u + 0x7FFFu + ((u >> 16) & 1u)) >> 16;
  return (unsigned short)r;
}

// ================= fused setup: prefix + wtrans + combW + sines + zero =================
// Block map: [0]=prefix, [1,1041)=wtrans, [1041,1121)=combW, [1121,3169)=sines, [3169,3201)=zero
__global__ void k_setup(const float* __restrict__ x,
                        const float* __restrict__ posw, const float* __restrict__ envw,
                        const float* __restrict__ tfuw, const float* __restrict__ ttw,
                        const float* __restrict__ trw,  const float* __restrict__ lpw,
                        const float* __restrict__ lew,  const float* __restrict__ ltw,
                        const float* __restrict__ dw,   const float* __restrict__ db,
                        const float* __restrict__ pw,   const float* __restrict__ pb2,
                        float* __restrict__ ws){
  __shared__ float ps[1024];
  int b = blockIdx.x, tid = threadIdx.x;
  if (b == 0){
    // exclusive prefix sums of x into S
    float* S = ws + S_OFF;
    float v[32];
    const float4* x4 = (const float4*)(x + tid*32);
    float s = 0.f;
#pragma unroll
    for (int i=0;i<8;++i){
      float4 q = x4[i];
      v[4*i]=q.x; v[4*i+1]=q.y; v[4*i+2]=q.z; v[4*i+3]=q.w;
      s += q.x+q.y+q.z+q.w;
    }
    ps[tid] = s; __syncthreads();
    for (int ofs=1; ofs<1024; ofs<<=1){
      float add = (tid>=ofs)? ps[tid-ofs] : 0.f;
      __syncthreads();
      ps[tid] += add;
      __syncthreads();
    }
    float run = ps[tid] - s;
#pragma unroll
    for (int i=0;i<32;++i){ S[tid*32+i] = run; run += v[i]; }
    if (tid==1023) S[32768] = ps[1023];
  } else if (b < 1041){
    int i = (b-1)*1024 + tid;
    float v;
    if (i < 327680){                       // pos_up (5,128,128,4) -> [l][(c*4+k)*128+o]
      int l = i>>16, r = i & 65535, o = r & 127, ck = r>>7, c = ck>>2, k = ck&3;
      v = posw[(l<<16) + (((o<<7)+c)<<2) + k];
    } else if (i < 622592){                // env_up (6,128,128,3)
      int i2 = i - 327680; int l = i2/49152, r = i2 - l*49152, o = r&127, ck = r>>7;
      int c = ck/3, k = ck - 3*c;
      v = envw[l*49152 + ((o<<7)+c)*3 + k];
    } else if (i < 770048){                // tfu_up (3,128,128,3)
      int i2 = i - 622592; int l = i2/49152, r = i2 - l*49152, o = r&127, ck = r>>7;
      int c = ck/3, k = ck - 3*c;
      v = tfuw[l*49152 + ((o<<7)+c)*3 + k];
    } else if (i < 786432){                // tt_w -> [c][o]
      int i2 = i - 770048; int o = i2 & 127, c = i2 >> 7;
      v = ttw[(o<<7) + c];
    } else if (i < 802816){                // tr_w
      int i2 = i - 786432; int o = i2 & 127, c = i2 >> 7;
      v = trw[(o<<7) + c];
    } else if (i < 868352){                // pos_lin -> [k][r]
      int i2 = i - 802816; int r = i2 & 511, k = i2 >> 9;
      v = lpw[(r<<7) + k];
    } else if (i < 933888){                // env_lin
      int i2 = i - 868352; int r = i2 & 511, k = i2 >> 9;
      v = lew[(r<<7) + k];
    } else {                               // tfu_lin
      int i2 = i - 933888; int r = i2 & 1023, k = i2 >> 10;
      v = ltw[(r<<7) + k];
    }
    ws[WT + i] = v;
  } else if (b < 1121){
    // combW: fold pointwise (pw) into dilated weights
    int idx = (b-1041)*1024 + tid;
    if (idx < 81920){
      int l = idx >> 14, r = idx & 16383, o = r >> 7, c = r & 127;
      float a0=0.f, a1=0.f, a2=0.f;
      for (int m=0;m<128;++m){
        float p = pw[(l*128 + o)*128 + m];
        const float* dp = dw + ((l*128 + m)*128 + c)*3;
        a0 += p*dp[0]; a1 += p*dp[1]; a2 += p*dp[2];
      }
      float* W = ws + WC + ((l*128 + o)*128 + c)*3;
      W[0]=a0; W[1]=a1; W[2]=a2;
      if (c==0){
        float bb = pb2[l*128 + o];
        for (int m=0;m<128;++m) bb += pw[(l*128 + o)*128 + m] * db[l*128 + m];
        ws[WBC + l*128 + o] = bb;
      }
    }
  } else if (b < 3169){
    int b2 = b - 1121;
    int band = b2 >> 5;
    int t = ((b2 & 31) << 10) + tid;
    float l0 = __fdiv_rn((float)log(20.0),   (float)log(10.0));
    float l1 = __fdiv_rn((float)log(9922.5), (float)log(10.0));
    float dl = __fdiv_rn(__fsub_rn(l1, l0), 63.0f);
    float lb = __fadd_rn(l0, __fmul_rn((float)band, dl));
    float freq = (float)pow(10.0, (double)lb);
    float w = __fmul_rn((float)(2.0*M_PI), freq);
    float tn = __fdiv_rn((float)t, 22050.0f);
    ws[SINES + band*NSAMP + t] = sinf(__fmul_rn(w, tn));
  } else {
    int i = (b-3169)*1024 + tid;   // [0,32768)
    {
      int e = i >> 11, r = i & 2047;
      ((unsigned short*)(ws + KB))[e*34816 + r] = 0;
    }
    if (i < 16*128){
      int e = i >> 7, r = i & 127;
      if (r < 64) ((unsigned short*)(ws + CRB0))[e*32832 + (r==0 ? 0 : 32768 + r)] = 0;
      else        ((unsigned short*)(ws + CRB1))[e*32832 + 32768 + (r-64)] = 0;
    }
  }
}

// ================= front-end =================

__global__ void k_fbpool(const float* __restrict__ fbw, float* __restrict__ ws){
  const float* S = ws + S_OFF;
  int c = blockIdx.x >> 5, j0 = (blockIdx.x & 31) << 2;
  int jj = threadIdx.x >> 7, kk = threadIdx.x & 127;
  int j = j0 + jj;
  int i0 = max(0, 256*j - 256), i1 = min(32767, 256*j + 255);
  float acc = 0.f;
#pragma unroll
  for (int m=0;m<4;++m){
    int k = kk + (m<<7);
    int hi = min(max(i1 + k - 255, 0), 32768);
    int lo = min(max(i0 + k - 256, 0), 32768);
    acc += fbw[c*512 + k] * (S[hi] - S[lo]);
  }
  for (int o=32;o;o>>=1) acc += __shfl_down(acc, o);
  __shared__ float red[8];
  if ((threadIdx.x & 63) == 0) red[threadIdx.x>>6] = acc;
  __syncthreads();
  if (threadIdx.x < 4)
    ws[HP + c*128 + j0 + threadIdx.x] = (red[2*threadIdx.x] + red[2*threadIdx.x+1]) * (1.0f/512.0f);
}

__global__ void k_reduce(const float* __restrict__ rw, const float* __restrict__ rb,
                         float* __restrict__ ws){
  int o = blockIdx.x, t = threadIdx.x;
  const float* hp = ws + HP;
  // inline global sumsq (each block recomputes; 64 KB L2-resident)
  float sq = 0.f;
  for (int i=t;i<16384;i+=128){ float v = hp[i]; sq += v*v; }
  for (int ofs=32;ofs;ofs>>=1) sq += __shfl_down(sq, ofs);
  __shared__ float rr2[2];
  if ((t & 63) == 0) rr2[t>>6] = sq;
  __syncthreads();
  float g = sqrtf(rr2[0] + rr2[1]) + 1e-8f;
  float acc = rb[o];
  for (int c=0;c<128;++c) acc += rw[o*161 + c] * __fdiv_rn(hp[c*128 + t], g);
  // positional encoding (exact replication of the f32 op sequence)
  float delta = __fdiv_rn(2.0f, 127.0f);
  float p = __fadd_rn(-1.0f, __fmul_rn((float)t, delta));
  acc += rw[o*161 + 128] * p;
  float sc = 1.0f;
  const float PIF = (float)M_PI;
#pragma unroll
  for (int i=0;i<16;++i){
    float f = __fmul_rn(__fmul_rn(p, sc), PIF);
    acc += rw[o*161 + 129 + 2*i] * sinf(f);
    acc += rw[o*161 + 130 + 2*i] * cosf(f);
    sc = sc * 2.0f;
  }
  ws[HA + o*128 + t] = acc;
}

__global__ void k_dil(float* __restrict__ ws, int l, int d, int inoff, int outoff){
  int o = blockIdx.x, t = threadIdx.x;
  const float* in = ws + inoff;
  const float* Wo = ws + WC + (l*128 + o)*384;
  float acc = in[o*128 + t] + ws[WBC + l*128 + o];
  for (int c=0;c<128;++c){
    float v0 = (t-d >= 0)  ? in[c*128 + t - d] : 0.f;
    float v1 = in[c*128 + t];
    float v2 = (t+d < 128) ? in[c*128 + t + d] : 0.f;
    acc += Wo[c*3]*v0 + Wo[c*3+1]*v1 + Wo[c*3+2]*v2;
  }
  ws[outoff + o*128 + t] = acc >= 0.f ? acc : 0.2f*acc;
}

// topk + encoded + (fused) time/transfer linears
__global__ void k_topk(float* __restrict__ ws, const float* __restrict__ ttb,
                       const float* __restrict__ trb, float* __restrict__ out){
  const float* h = ws + HB;
  int t = threadIdx.x;
  __shared__ float nt[128], nt0[128];
  __shared__ int idxs[16];
  __shared__ float r2[2];
  __shared__ float wv[2]; __shared__ int wi[2];
  __shared__ float es[2048];
  float colsq = 0.f;
  for (int c=0;c<128;++c){ float v = h[c*128 + t]; colsq += v*v; }
  float s = colsq;
  for (int o=32;o;o>>=1) s += __shfl_down(s, o);
  if ((t & 63) == 0) r2[t>>6] = s;
  __syncthreads();
  float g2 = sqrtf(r2[0] + r2[1]) + 1e-8f;
  float sq2 = 0.f;
  for (int c=0;c<128;++c){ float v = __fdiv_rn(h[c*128 + t], g2); sq2 += v*v; }
  float ntv = sqrtf(sq2);
  nt[t] = ntv; nt0[t] = ntv;
  __syncthreads();
  for (int j=0;j<16;++j){
    float v = nt[t]; int bi = t;
    for (int o=32;o;o>>=1){
      float ov = __shfl_down(v, o); int oi = __shfl_down(bi, o);
      if (ov > v || (ov == v && oi < bi)){ v = ov; bi = oi; }
    }
    if ((t & 63) == 0){ wv[t>>6] = v; wi[t>>6] = bi; }
    __syncthreads();
    if (t == 0){
      int win = (wv[1] > wv[0] || (wv[1] == wv[0] && wi[1] < wi[0])) ? wi[1] : wi[0];
      idxs[j] = win; nt[win] = -3.0e38f;
    }
    __syncthreads();
  }
  if (t < 16) out[O_IDX + t] = (float)idxs[t];
  for (int j=0;j<16;++j){
    int ij = idxs[j];
    float hv = __fdiv_rn(h[t*128 + ij], g2);
    float enc = __fdiv_rn(hv, nt0[ij] + 1e-8f);
    out[O_ENC + j*128 + t] = enc;
    es[j*128 + t] = enc;
  }
  __syncthreads();
  // fused time/transfer: 4096 dots over 128 threads
  for (int m=0;m<32;++m){
    int idx = m*128 + t;
    int kind = idx >> 11, j = (idx >> 7) & 15, o = idx & 127;
    const float* Wt = ws + (kind ? WT_TR : WT_TT);
    float acc = kind ? trb[o] : ttb[o];
    for (int c=0;c<128;++c) acc += es[j*128 + c] * Wt[c*128 + o];
    out[(kind ? O_TR : O_TIME) + j*128 + o] = acc;
    ws[(kind ? TRANSO : TIMEO) + j*128 + o] = acc;
  }
}

// ================= decoder stacks (fused across pos/env/tfu) =================

// fused linears: blocks 0..15 pos, 16..31 env, 32..47 tfu ; 1024 threads
__global__ void k_lin3(float* __restrict__ ws, const float* __restrict__ plb,
                       const float* __restrict__ elb, const float* __restrict__ tlb){
  int b = blockIdx.x, tid = threadIdx.x;
  int stack = b >> 4, e = b & 15;
  int zoff  = (stack == 0) ? TIMEO : TRANSO;
  int ltoff = (stack == 0) ? LT_POS : (stack == 1) ? LT_ENV : LT_TFU;
  int R     = (stack == 2) ? 1024 : 512;
  int start = (stack == 2) ? 8 : 4;
  int dst   = (stack == 0) ? PA : (stack == 1) ? BUFA : TA;
  const float* lb = (stack == 0) ? plb : (stack == 1) ? elb : tlb;
  __shared__ float z[128];
  if (tid < 128) z[tid] = ws[zoff + e*128 + tid];
  __syncthreads();
  if (tid < (start<<7)){
    int s = tid >> 7, c = tid & 127;
    int r = c*start + s;
    float acc = lb[r];
    const float* lt = ws + ltoff;
    for (int k=0;k<128;++k) acc += z[k] * lt[k*R + r];
    ws[dst + e*(start<<7) + tid] = acc;   // (e, s, c) layout
  }
}

static __device__ __forceinline__ void convT32_dev(float* __restrict__ ws, const float* __restrict__ bias,
                                                   int srcoff, int dstoff, int wtoff, int Lin,
                                                   int e, int jt, float* xs){
  int j0 = jt*32, o = threadIdx.x;
  int s_lo = (j0 >> 1) - 1;
  const float* in = ws + srcoff + e*Lin*128;
  for (int idx=o; idx<18*128; idx+=128){
    int si = idx >> 7, c = idx & 127, s = s_lo + si;
    xs[idx] = (s >= 0 && s < Lin) ? in[s*128 + c] : 0.f;
  }
  __syncthreads();
  float acc[32];
#pragma unroll
  for (int jj=0;jj<32;++jj) acc[jj] = bias[o];
  const float* wt = ws + wtoff;
  for (int c=0;c<128;++c){
    float w0 = wt[((c<<2)+0)*128 + o];
    float w1 = wt[((c<<2)+1)*128 + o];
    float w2 = wt[((c<<2)+2)*128 + o];
    float w3 = wt[((c<<2)+3)*128 + o];
#pragma unroll
    for (int jj=0;jj<32;++jj){
      if ((jj & 1) == 0){
        acc[jj] += xs[((jj>>1)<<7) + c]*w3 + xs[(((jj>>1)+1)<<7) + c]*w1;
      } else {
        acc[jj] += xs[(((jj+1)>>1)<<7) + c]*w2 + xs[((((jj+1)>>1)+1)<<7) + c]*w0;
      }
    }
  }
  int Lout = Lin*2;
  float* outp = ws + dstoff + e*Lout*128;
#pragma unroll
  for (int jj=0;jj<32;++jj){
    if (j0+jj < Lout){
      float v = acc[jj];
      outp[(j0+jj)*128 + o] = v >= 0.f ? v : 0.2f*v;
    }
  }
}

static __device__ __forceinline__ void conv3up32_dev(float* __restrict__ ws, const float* __restrict__ bias,
                                                     int srcoff, int dstoff, int wtoff, int Lin,
                                                     int e, int jt, float* xs){
  int j0 = jt*32, o = threadIdx.x;
  int fs = (j0 >> 1) - 1;
  const float* in = ws + srcoff + e*Lin*128;
  for (int idx=o; idx<18*128; idx+=128){
    int si = idx >> 7, c = idx & 127, s = fs + si;
    xs[idx] = (s >= 0 && s < Lin) ? in[s*128 + c] : 0.f;
  }
  __syncthreads();
  float acc[32];
#pragma unroll
  for (int jj=0;jj<32;++jj) acc[jj] = bias[o];
  const float* wt = ws + wtoff;
  for (int c=0;c<128;++c){
    float w0 = wt[(c*3+0)*128 + o];
    float w1 = wt[(c*3+1)*128 + o];
    float w2 = wt[(c*3+2)*128 + o];
#pragma unroll
    for (int jj=0;jj<32;++jj){
      acc[jj] += xs[((((jj-1)>>1)+1)<<7) + c]*w0
               + xs[((((jj  )>>1)+1)<<7) + c]*w1
               + xs[((((jj+1)>>1)+1)<<7) + c]*w2;
    }
  }
  int Lout = Lin*2;
  float* outp = ws + dstoff + e*Lout*128;
#pragma unroll
  for (int jj=0;jj<32;++jj){
    if (j0+jj < Lout){
      float v = acc[jj];
      outp[(j0+jj)*128 + o] = v >= 0.f ? v : 0.2f*v;
    }
  }
}

__global__ __launch_bounds__(128)
void k_layer(float* __restrict__ ws, const float* __restrict__ pbias,
             const float* __restrict__ ebias, const float* __restrict__ tbias,
             int c1, int c2,
             int pLin, int pWt, int pBo, int pNJ, int pSrc, int pDst,
             int eLin, int eWt, int eBo, int eNJ, int eSrc, int eDst,
             int tLin, int tWt, int tBo, int tNJ, int tSrc, int tDst){
  __shared__ float xs[18*128];
  int b = blockIdx.x;
  if (b < c1){
    int e = b / pNJ, jt = b - e*pNJ;
    convT32_dev(ws, pbias + pBo, pSrc, pDst, pWt, pLin, e, jt, xs);
  } else if (b < c2){
    int bl = b - c1; int e = bl / eNJ, jt = bl - e*eNJ;
    conv3up32_dev(ws, ebias + eBo, eSrc, eDst, eWt, eLin, e, jt, xs);
  } else {
    int bl = b - c2; int e = bl / tNJ, jt = bl - e*tNJ;
    conv3up32_dev(ws, tbias + tBo, tSrc, tDst, tWt, tLin, e, jt, xs);
  }
}

// fused epilogues: blocks 0..15 out_pos, 16..79 out_env, 80..95 out_tfu ; 256 threads
__global__ void k_outs(float* __restrict__ ws,
                       const float* __restrict__ pw, const float* __restrict__ pb,
                       const float* __restrict__ ew, const float* __restrict__ eb,
                       const float* __restrict__ tw, const float* __restrict__ tb_,
                       float* __restrict__ out){
  __shared__ float xs[16384];
  int b = blockIdx.x, tid = threadIdx.x;
  if (b < 16){
    int e = b;
    const float* in = ws + PB + e*16384;
    for (int idx=tid; idx<16384; idx+=256){
      int q = idx >> 7, c = idx & 127;
      xs[(q<<7) + ((c+q)&127)] = in[idx];
    }
    __syncthreads();
    float acc = pb[0];
    if (tid < 128){
      int j = tid;
      for (int c=0;c<128;++c){
#pragma unroll
        for (int k=0;k<3;++k){
          int q = j + k - 1;
          if (q >= 0 && q < 128) acc += xs[(q<<7) + ((c+q)&127)] * pw[c*3 + k];
        }
      }
    }
    __syncthreads();
    xs[tid] = (tid < 128) ? acc : -3.0e38f;
    __syncthreads();
    for (int s=128; s>=1; s>>=1){ if (tid < s) xs[tid] = fmaxf(xs[tid], xs[tid+s]); __syncthreads(); }
    float m = xs[0];
    __syncthreads();
    float ex = (tid < 128) ? expf(__fsub_rn(acc, m)) : 0.f;
    xs[tid] = ex;
    __syncthreads();
    for (int s=128; s>=1; s>>=1){ if (tid < s) xs[tid] += xs[tid+s]; __syncthreads(); }
    if (tid < 128) ws[PE + e*128 + tid] = __fdiv_rn(ex, xs[0]);
  } else if (b < 80){
    int idx2 = b - 16; int e = idx2 >> 2, b0 = (idx2 & 3) << 6;
    const float* in = ws + BUFA + e*32768;
    for (int idx=tid; idx<8448; idx+=256){
      int qs = idx >> 7, c = idx & 127, q = b0 - 1 + qs;
      xs[(qs<<7) + ((c+qs)&127)] = (q >= 0 && q < 256) ? in[q*128 + c] : 0.f;
    }
    __syncthreads();
    int part = tid >> 6, bb = tid & 63;
    float acc = (part == 0) ? eb[0] : 0.f;
    for (int c2=0;c2<32;++c2){
      int c = part*32 + c2;
#pragma unroll
      for (int k=0;k<3;++k){
        int qs = bb + k;
        acc += xs[(qs<<7) + ((c+qs)&127)] * ew[c*3 + k];
      }
    }
    xs[8448 + tid] = acc;
    __syncthreads();
    if (tid < 64){
      float a = xs[8448+tid] + xs[8448+64+tid] + xs[8448+128+tid] + xs[8448+192+tid];
      a = fmaxf(a, 0.f);
      out[O_ENV + e*256 + b0 + tid] = a;
      ws[ENVO + e*256 + b0 + tid] = a;
    }
  } else {
    int e = b - 80;
    const float* in = ws + TB + e*8192;
    for (int idx=tid; idx<8448; idx+=256){
      int qs = idx >> 7, c = idx & 127, q = -1 + qs;
      xs[(qs<<7) + ((c+qs)&127)] = (q >= 0 && q < 64) ? in[q*128 + c] : 0.f;
    }
    __syncthreads();
    int r0 = tid >> 6, bb = tid & 63;
    for (int rr=r0; rr<32; rr+=4){
      float acc = tb_[rr];
      for (int c=0;c<128;++c){
#pragma unroll
        for (int k=0;k<3;++k){
          int qs = bb + k;
          acc += xs[(qs<<7) + ((c+qs)&127)] * tw[(rr*128 + c)*3 + k];
        }
      }
      xs[8448 + rr*64 + bb] = acc;
    }
    __syncthreads();
    if (tid < 64){
      float best = xs[8448 + tid]; int bi = 0;
      for (int r=1;r<32;++r){ float v = xs[8448 + r*64 + tid]; if (v > best){ best = v; bi = r; } }
      ((int*)(ws + RSEL))[e*64 + tid] = bi;
    }
  }
}

// ================= synthesis =================

// fused: blocks 0..2047 resonance-K (bf16), blocks 2048..4095 envs
__global__ void k_envK(float* __restrict__ ws, const float* __restrict__ noise){
  int b = blockIdx.x, tid = threadIdx.x;
  if (b < 2048){
    int e = b >> 7, F = b & 127;
    int t = (F << 8) + tid;
    __shared__ float ampl[64];
    if (tid < 64){
      int r = ((const int*)(ws + RSEL))[e*64 + tid];
      float d = __fadd_rn(0.5f, __fmul_rn((float)r, __fdiv_rn(__fsub_rn(0.9999f, 0.5f), 31.0f)));
      ampl[tid] = (float)pow((double)d, (double)F);
    }
    __syncthreads();
    float acc = 0.f;
    for (int band=0;band<64;++band) acc += ws[SINES + band*NSAMP + t] * ampl[band];
    ((unsigned short*)(ws + KB))[e*34816 + 2048 + t] = f2bf(acc * (1.0f/(64.0f*65536.0f)));
  } else {
    int idx = (b - 2048)*256 + tid;
    int e = idx >> 15, tau = idx & 32767;
    float cf = __fsub_rn(__fdiv_rn(__fmul_rn(__fadd_rn((float)tau, 0.5f), 256.0f), 32768.0f), 0.5f);
    float c = fminf(fmaxf(cf, 0.0f), 255.0f);
    int i0 = (int)floorf(c);
    int i1 = min(i0 + 1, 255);
    float w = __fsub_rn(c, (float)i0);
    float e0 = ws[ENVO + e*256 + i0], e1 = ws[ENVO + e*256 + i1];
    float val = __fadd_rn(__fmul_rn(e0, __fsub_rn(1.0f, w)), __fmul_rn(e1, w));
    ws[ENVS + e*NSAMP + tau] = val * noise[tau];
  }
}

// impulse-comb conv; writes reversed bf16 copies (CRB0/CRB1) for the MFMA stage
__global__ void k_c(float* __restrict__ ws){
  int e = blockIdx.x >> 5, seg = blockIdx.x & 31;
  int t = (seg << 10) + threadIdx.x;
  __shared__ float pl[128];
  if (threadIdx.x < 128) pl[threadIdx.x] = ws[PE + e*128 + threadIdx.x];
  __syncthreads();
  const float* ev = ws + ENVS + e*NSAMP;
  int kub = min(127, (seg << 2) + 3);
  float acc = 0.f;
  for (int k=0;k<=kub;++k){
    int u = t - (k << 8);
    if (u >= 0) acc += pl[k] * ev[u];
  }
  unsigned short hv = f2bf(acc);
  ((unsigned short*)(ws + CRB0))[e*32832 + 32768 - t] = hv;
  ((unsigned short*)(ws + CRB1))[e*32832 + 32767 - t] = hv;
}

// Toeplitz conv via MFMA 32x32x16 bf16; 16 KB LDS two-phase reduction, no atomics.
__global__ __launch_bounds__(256, 4)
void k_bigmfma(float* __restrict__ ws){
  int b = blockIdx.x;
  int w = threadIdx.x >> 6;
  int lane = threadIdx.x & 63;
  int e = b / 72;
  int r = b - e*72;
  int T2 = 0, cum = 0;
  while (cum + ((T2+2)>>1) <= r){ cum += (T2+2)>>1; T2++; }
  int qb = r - cum;
  int nseg = 2*(T2+1);
  int seg = qb*4 + w;
  int t0 = T2 << 11;
  int il = lane & 31, h = lane >> 5;
  __shared__ float red[2][2048];
  f32x16 acc0 = {}; f32x16 acc1 = {};
  if (seg < nseg){
    int u0 = -1984 + (seg << 10);
    const unsigned short* Kp  = (const unsigned short*)(ws + KB)   + e*34816 + 2048;
    const unsigned short* C0p = (const unsigned short*)(ws + CRB0) + e*32832;
    const unsigned short* C1p = (const unsigned short*)(ws + CRB1) + e*32832;
    int bB  = u0 + (il << 6) + (h << 3);
    int bA0 = 32768 - t0 + u0 - (il << 1) + (h << 3);
    int bA1 = bA0 - 2;
#pragma unroll 2
    for (int q = 0; q < 64; ++q){
      union { f32x4 v; bf16x8 s; } a0u, a1u, bu;
      a0u.v = *(const f32x4*)(C0p + bA0);
      a1u.v = *(const f32x4*)(C1p + bA1);
      bu.v  = *(const f32x4*)(Kp  + bB);
      acc0 = __builtin_amdgcn_mfma_f32_32x32x16_bf16(a0u.s, bu.s, acc0, 0, 0, 0);
      acc1 = __builtin_amdgcn_mfma_f32_32x32x16_bf16(a1u.s, bu.s, acc1, 0, 0, 0);
      bA0 += 16; bA1 += 16; bB += 16;
    }
  }
  int wl = w & 1;
  if (w < 2){
#pragma unroll
    for (int rr = 0; rr < 16; ++rr){
      int row = (rr & 3) + ((rr >> 2) << 3) + (h << 2);
      red[wl][(row << 6) + il]      = acc0[rr];
      red[wl][(row << 6) + 32 + il] = acc1[rr];
    }
  }
  __syncthreads();
  if (w >= 2){
#pragma unroll
    for (int rr = 0; rr < 16; ++rr){
      int row = (rr & 3) + ((rr >> 2) << 3) + (h << 2);
      red[wl][(row << 6) + il]      += acc0[rr];
      red[wl][(row << 6) + 32 + il] += acc1[rr];
    }
  }
  __syncthreads();
  float* slab = ws + SLAB + b*2048;
  int tid = threadIdx.x;
#pragma unroll
  for (int jj = 0; jj < 8; ++jj){
    int pos = tid*8 + jj;                // pos = il2*64 + (2*row + p)
    int il2 = pos >> 6, x = pos & 63;
    int idx = ((x >> 1) << 6) + ((x & 1) << 5) + il2;
    slab[pos] = red[0][idx] + red[1][idx];
  }
}

__global__ void k_final(const float* __restrict__ ws, float* __restrict__ out){
  int t = blockIdx.x*1024 + threadIdx.x;
  int T2 = t >> 11, pos = t & 2047;
  int cum = 0;
  for (int j=0;j<T2;++j) cum += (j+2)>>1;
  int nb = (T2+2)>>1;
  float s = 0.f;
  for (int e=0;e<16;++e){
    const float* sl = ws + SLAB + (e*72 + cum)*2048 + pos;
    for (int q=0;q<nb;++q) s += sl[q*2048];
  }
  out[t] = s;
}

// ================= launcher =================

extern "C" void kernel_launch(void* const* d_in, const int* in_sizes, int n_in,
                              void* d_out, int out_size, void* d_ws, size_t ws_size,
                              hipStream_t stream){
  const float* x         = (const float*)d_in[0];
  const float* noise     = (const float*)d_in[1];
  const float* fb_w      = (const float*)d_in[2];
  const float* reduce_w  = (const float*)d_in[3];
  const float* reduce_b  = (const float*)d_in[4];
  const float* dl_dw     = (const float*)d_in[5];
  const float* dl_db     = (const float*)d_in[6];
  const float* dl_pw     = (const float*)d_in[7];
  const float* dl_pb     = (const float*)d_in[8];
  const float* tt_w      = (const float*)d_in[9];
  const float* tt_b      = (const float*)d_in[10];
  const float* tr_w      = (const float*)d_in[11];
  const float* tr_b      = (const float*)d_in[12];
  const float* pos_lin_w = (const float*)d_in[13];
  const float* pos_lin_b = (const float*)d_in[14];
  const float* pos_up_w  = (const float*)d_in[15];
  const float* pos_up_b  = (const float*)d_in[16];
  const float* pos_out_w = (const float*)d_in[17];
  const float* pos_out_b = (const float*)d_in[18];
  const float* env_lin_w = (const float*)d_in[19];
  const float* env_lin_b = (const float*)d_in[20];
  const float* env_up_w  = (const float*)d_in[21];
  const float* env_up_b  = (const float*)d_in[22];
  const float* env_out_w = (const float*)d_in[23];
  const float* env_out_b = (const float*)d_in[24];
  const float* tfu_lin_w = (const float*)d_in[25];
  const float* tfu_lin_b = (const float*)d_in[26];
  const float* tfu_up_w  = (const float*)d_in[27];
  const float* tfu_up_b  = (const float*)d_in[28];
  const float* tfu_out_w = (const float*)d_in[29];
  const float* tfu_out_b = (const float*)d_in[30];
  float* out = (float*)d_out;
  float* ws  = (float*)d_ws;

  k_setup<<<3201, 1024, 0, stream>>>(x, pos_up_w, env_up_w, tfu_up_w, tt_w, tr_w,
                                     pos_lin_w, env_lin_w, tfu_lin_w,
                                     dl_dw, dl_db, dl_pw, dl_pb, ws);
  k_fbpool<<<4096, 512, 0, stream>>>(fb_w, ws);
  k_reduce<<<128, 128, 0, stream>>>(reduce_w, reduce_b, ws);
  const int DIL[5] = {1, 3, 9, 27, 1};
  int src = HA, dst = HB;
  for (int l=0;l<5;++l){
    k_dil<<<128, 128, 0, stream>>>(ws, l, DIL[l], src, dst);
    int tmp = src; src = dst; dst = tmp;
  }
  k_topk<<<1, 128, 0, stream>>>(ws, tt_b, tr_b, out);
  k_lin3<<<48, 1024, 0, stream>>>(ws, pos_lin_b, env_lin_b, tfu_lin_b);

  // fused decoder layers (pos convT | env conv3 | tfu conv3)
  k_layer<<<48, 128, 0, stream>>>(ws, pos_up_b, env_up_b, tfu_up_b, 16, 32,
      4,  WT_POS + 0,      0,   1, PA,   PB,
      4,  WT_ENV + 0,      0,   1, BUFA, BUFB,
      8,  WT_TFU + 0,      0,   1, TA,   TB);
  k_layer<<<48, 128, 0, stream>>>(ws, pos_up_b, env_up_b, tfu_up_b, 16, 32,
      8,  WT_POS + 65536,  128, 1, PB,   PA,
      8,  WT_ENV + 49152,  128, 1, BUFB, BUFA,
      16, WT_TFU + 49152,  128, 1, TB,   TA);
  k_layer<<<64, 128, 0, stream>>>(ws, pos_up_b, env_up_b, tfu_up_b, 16, 32,
      16, WT_POS + 131072, 256, 1, PA,   PB,
      16, WT_ENV + 98304,  256, 1, BUFA, BUFB,
      32, WT_TFU + 98304,  256, 2, TA,   TB);
  k_layer<<<64, 128, 0, stream>>>(ws, pos_up_b, env_up_b, tfu_up_b, 32, 64,
      32, WT_POS + 196608, 384, 2, PB,   PA,
      32, WT_ENV + 147456, 384, 2, BUFB, BUFA,
      1,  0,               0,   1, 0,    0);
  k_layer<<<128, 128, 0, stream>>>(ws, pos_up_b, env_up_b, tfu_up_b, 64, 128,
      64, WT_POS + 262144, 512, 4, PA,   PB,
      64, WT_ENV + 196608, 512, 4, BUFA, BUFB,
      1,  0,               0,   1, 0,    0);
  k_layer<<<128, 128, 0, stream>>>(ws, pos_up_b, env_up_b, tfu_up_b, 0, 128,
      1,  0,               0,   1, 0,    0,
      128, WT_ENV + 245760, 640, 8, BUFB, BUFA,
      1,  0,               0,   1, 0,    0);

  k_outs<<<96, 256, 0, stream>>>(ws, pos_out_w, pos_out_b, env_out_w, env_out_b,
                                 tfu_out_w, tfu_out_b, out);

  k_envK<<<4096, 256, 0, stream>>>(ws, noise);
  k_c<<<512, 1024, 0, stream>>>(ws);
  k_bigmfma<<<1152, 256, 0, stream>>>(ws);
  k_final<<<32, 1024, 0, stream>>>(ws, out);
}

// Round 5
// 905.189 us; speedup vs baseline: 2.2857x; 1.0614x over previous
//
#include <hip/hip_runtime.h>
#include <math.h>

// ---------------- constants ----------------
#define NSAMP 32768
#define NFRM  128

// ---- ws layout (float offsets) ----
static constexpr int S_OFF  = 0;                   // 32772 (prefix sums, 32769 used)
static constexpr int HP     = 32772;               // 16384
static constexpr int NSQ    = HP + 16384;          // 16 (unused now)
static constexpr int HA     = NSQ + 16;            // 16384
static constexpr int HB     = HA + 16384;          // 16384
static constexpr int TFQ    = HA;                  // 32768 tf scores (overlays HA+HB, dead after topk)
static constexpr int WC     = HB + 16384;          // 245760 combined dilated weights
static constexpr int WBC    = WC + 245760;         // 640 combined dilated bias
static constexpr int EWS    = WBC + 640;           // 2048 encoded
static constexpr int TIMEO  = EWS + 2048;          // 2048
static constexpr int TRANSO = TIMEO + 2048;        // 2048
static constexpr int PE     = TRANSO + 2048;       // 2048 softmax impulse weights
static constexpr int RSEL   = PE + 2048;           // 1024 (unused now)
static constexpr int ENVO   = RSEL + 1024;         // 4096 env (16,256)
static constexpr int BUFA   = ENVO + 4096;         // 524288  (env stack A)
static constexpr int BUFB   = BUFA + 524288;       // 524288  (env stack B)
static constexpr int WT     = BUFB + 524288;       // transposed weights, 1064960 total
static constexpr int WT_POS = WT;                  // 327680  [l][(c*4+k)*128+o]
static constexpr int WT_ENV = WT + 327680;         // 294912  [l][(c*3+k)*128+o]
static constexpr int WT_TFU = WT + 622592;         // 147456
static constexpr int WT_TT  = WT + 770048;         // 16384   [c][o]
static constexpr int WT_TR  = WT + 786432;         // 16384
static constexpr int LT_POS = WT + 802816;         // 65536   [k][r], R=512
static constexpr int LT_ENV = WT + 868352;         // 65536
static constexpr int LT_TFU = WT + 933888;         // 131072  [k][r], R=1024
static constexpr int SINES  = WT + 1064960;        // 2097152 (64 x 32768)
static constexpr int ENVS   = SINES + 2097152;     // 524288 (16 x 32768 f32)
// SLAB overlays SINES+ENVS (both dead once k_bigmfma runs)
static constexpr int SLAB   = SINES;
// bf16 conv operands (ushort-indexed off these f32 offsets)
static constexpr int CRB0   = ENVS + 524288;       // 16 x 32832 ushort ; CRB0[x]=c[32768-x]
static constexpr int CRB1   = CRB0 + 262656;       // 16 x 32832 ushort ; CRB1[y]=c[32767-y]
static constexpr int KB     = CRB1 + 262656;       // 16 x 34816 ushort ; KB[2048+u]=K[u]
// pos / tfu stack ping-pong buffers (disjoint from env's BUFA/BUFB)
static constexpr int PA     = KB + 278528;         // 262144
static constexpr int PB     = PA + 262144;         // 262144
static constexpr int TA     = PB + 262144;         // 131072
static constexpr int TB     = TA + 131072;         // 131072

// ---- output offsets ----
static constexpr int O_IDX  = 32768;
static constexpr int O_ENC  = 32784;
static constexpr int O_ENV  = 34832;
static constexpr int O_TIME = 38928;
static constexpr int O_TR   = 40976;

typedef short bf16x8 __attribute__((ext_vector_type(8)));
typedef float f32x4  __attribute__((ext_vector_type(4)));
typedef float f32x16 __attribute__((ext_vector_type(16)));

static __device__ __forceinline__ unsigned short f2bf(float f){
  unsigned int u = __float_as_uint(f);
  unsigned int r = (u + 0x7FFFu + ((u >> 16) & 1u)) >> 16;
  return (unsigned short)r;
}

// ================= fused setup: prefix + wtrans + combW + sines + zero =================
// Block map: [0]=prefix, [1,1041)=wtrans, [1041,1121)=combW, [1121,3169)=sines, [3169,3201)=zero
__global__ void k_setup(const float* __restrict__ x,
                        const float* __restrict__ posw, const float* __restrict__ envw,
                        const float* __restrict__ tfuw, const float* __restrict__ ttw,
                        const float* __restrict__ trw,  const float* __restrict__ lpw,
                        const float* __restrict__ lew,  const float* __restrict__ ltw,
                        const float* __restrict__ dw,   const float* __restrict__ db,
                        const float* __restrict__ pw,   const float* __restrict__ pb2,
                        float* __restrict__ ws){
  __shared__ float ps[1024];
  int b = blockIdx.x, tid = threadIdx.x;
  if (b == 0){
    // exclusive prefix sums of x into S
    float* S = ws + S_OFF;
    float v[32];
    const float4* x4 = (const float4*)(x + tid*32);
    float s = 0.f;
#pragma unroll
    for (int i=0;i<8;++i){
      float4 q = x4[i];
      v[4*i]=q.x; v[4*i+1]=q.y; v[4*i+2]=q.z; v[4*i+3]=q.w;
      s += q.x+q.y+q.z+q.w;
    }
    ps[tid] = s; __syncthreads();
    for (int ofs=1; ofs<1024; ofs<<=1){
      float add = (tid>=ofs)? ps[tid-ofs] : 0.f;
      __syncthreads();
      ps[tid] += add;
      __syncthreads();
    }
    float run = ps[tid] - s;
#pragma unroll
    for (int i=0;i<32;++i){ S[tid*32+i] = run; run += v[i]; }
    if (tid==1023) S[32768] = ps[1023];
  } else if (b < 1041){
    int i = (b-1)*1024 + tid;
    float v;
    if (i < 327680){                       // pos_up (5,128,128,4) -> [l][(c*4+k)*128+o]
      int l = i>>16, r = i & 65535, o = r & 127, ck = r>>7, c = ck>>2, k = ck&3;
      v = posw[(l<<16) + (((o<<7)+c)<<2) + k];
    } else if (i < 622592){                // env_up (6,128,128,3)
      int i2 = i - 327680; int l = i2/49152, r = i2 - l*49152, o = r&127, ck = r>>7;
      int c = ck/3, k = ck - 3*c;
      v = envw[l*49152 + ((o<<7)+c)*3 + k];
    } else if (i < 770048){                // tfu_up (3,128,128,3)
      int i2 = i - 622592; int l = i2/49152, r = i2 - l*49152, o = r&127, ck = r>>7;
      int c = ck/3, k = ck - 3*c;
      v = tfuw[l*49152 + ((o<<7)+c)*3 + k];
    } else if (i < 786432){                // tt_w -> [c][o]
      int i2 = i - 770048; int o = i2 & 127, c = i2 >> 7;
      v = ttw[(o<<7) + c];
    } else if (i < 802816){                // tr_w
      int i2 = i - 786432; int o = i2 & 127, c = i2 >> 7;
      v = trw[(o<<7) + c];
    } else if (i < 868352){                // pos_lin -> [k][r]
      int i2 = i - 802816; int r = i2 & 511, k = i2 >> 9;
      v = lpw[(r<<7) + k];
    } else if (i < 933888){                // env_lin
      int i2 = i - 868352; int r = i2 & 511, k = i2 >> 9;
      v = lew[(r<<7) + k];
    } else {                               // tfu_lin
      int i2 = i - 933888; int r = i2 & 1023, k = i2 >> 10;
      v = ltw[(r<<7) + k];
    }
    ws[WT + i] = v;
  } else if (b < 1121){
    // combW: fold pointwise (pw) into dilated weights
    int idx = (b-1041)*1024 + tid;
    if (idx < 81920){
      int l = idx >> 14, r = idx & 16383, o = r >> 7, c = r & 127;
      float a0=0.f, a1=0.f, a2=0.f;
      for (int m=0;m<128;++m){
        float p = pw[(l*128 + o)*128 + m];
        const float* dp = dw + ((l*128 + m)*128 + c)*3;
        a0 += p*dp[0]; a1 += p*dp[1]; a2 += p*dp[2];
      }
      float* W = ws + WC + ((l*128 + o)*128 + c)*3;
      W[0]=a0; W[1]=a1; W[2]=a2;
      if (c==0){
        float bb = pb2[l*128 + o];
        for (int m=0;m<128;++m) bb += pw[(l*128 + o)*128 + m] * db[l*128 + m];
        ws[WBC + l*128 + o] = bb;
      }
    }
  } else if (b < 3169){
    int b2 = b - 1121;
    int band = b2 >> 5;
    int t = ((b2 & 31) << 10) + tid;
    if (tid == 0){
      // freq is block-uniform: compute once, broadcast (was per-thread double pow)
      float l0 = __fdiv_rn((float)log(20.0),   (float)log(10.0));
      float l1 = __fdiv_rn((float)log(9922.5), (float)log(10.0));
      float dl = __fdiv_rn(__fsub_rn(l1, l0), 63.0f);
      float lb = __fadd_rn(l0, __fmul_rn((float)band, dl));
      float freq = (float)pow(10.0, (double)lb);
      ps[0] = __fmul_rn((float)(2.0*M_PI), freq);
    }
    __syncthreads();
    float w = ps[0];
    float tn = __fdiv_rn((float)t, 22050.0f);
    ws[SINES + band*NSAMP + t] = sinf(__fmul_rn(w, tn));
  } else {
    int i = (b-3169)*1024 + tid;   // [0,32768)
    {
      int e = i >> 11, r = i & 2047;
      ((unsigned short*)(ws + KB))[e*34816 + r] = 0;
    }
    if (i < 16*128){
      int e = i >> 7, r = i & 127;
      if (r < 64) ((unsigned short*)(ws + CRB0))[e*32832 + (r==0 ? 0 : 32768 + r)] = 0;
      else        ((unsigned short*)(ws + CRB1))[e*32832 + 32768 + (r-64)] = 0;
    }
  }
}

// ================= front-end =================

__global__ void k_fbpool(const float* __restrict__ fbw, float* __restrict__ ws){
  const float* S = ws + S_OFF;
  int c = blockIdx.x >> 5, j0 = (blockIdx.x & 31) << 2;
  int jj = threadIdx.x >> 7, kk = threadIdx.x & 127;
  int j = j0 + jj;
  int i0 = max(0, 256*j - 256), i1 = min(32767, 256*j + 255);
  float acc = 0.f;
#pragma unroll
  for (int m=0;m<4;++m){
    int k = kk + (m<<7);
    int hi = min(max(i1 + k - 255, 0), 32768);
    int lo = min(max(i0 + k - 256, 0), 32768);
    acc += fbw[c*512 + k] * (S[hi] - S[lo]);
  }
  for (int o=32;o;o>>=1) acc += __shfl_down(acc, o);
  __shared__ float red[8];
  if ((threadIdx.x & 63) == 0) red[threadIdx.x>>6] = acc;
  __syncthreads();
  if (threadIdx.x < 4)
    ws[HP + c*128 + j0 + threadIdx.x] = (red[2*threadIdx.x] + red[2*threadIdx.x+1]) * (1.0f/512.0f);
}

__global__ void k_reduce(const float* __restrict__ rw, const float* __restrict__ rb,
                         float* __restrict__ ws){
  int o = blockIdx.x, t = threadIdx.x;
  const float* hp = ws + HP;
  float sq = 0.f;
  for (int i=t;i<16384;i+=128){ float v = hp[i]; sq += v*v; }
  for (int ofs=32;ofs;ofs>>=1) sq += __shfl_down(sq, ofs);
  __shared__ float rr2[2];
  if ((t & 63) == 0) rr2[t>>6] = sq;
  __syncthreads();
  float g = sqrtf(rr2[0] + rr2[1]) + 1e-8f;
  float acc = rb[o];
  for (int c=0;c<128;++c) acc += rw[o*161 + c] * __fdiv_rn(hp[c*128 + t], g);
  float delta = __fdiv_rn(2.0f, 127.0f);
  float p = __fadd_rn(-1.0f, __fmul_rn((float)t, delta));
  acc += rw[o*161 + 128] * p;
  float sc = 1.0f;
  const float PIF = (float)M_PI;
#pragma unroll
  for (int i=0;i<16;++i){
    float f = __fmul_rn(__fmul_rn(p, sc), PIF);
    acc += rw[o*161 + 129 + 2*i] * sinf(f);
    acc += rw[o*161 + 130 + 2*i] * cosf(f);
    sc = sc * 2.0f;
  }
  ws[HA + o*128 + t] = acc;
}

__global__ void k_dil(float* __restrict__ ws, int l, int d, int inoff, int outoff){
  int o = blockIdx.x, t = threadIdx.x;
  const float* in = ws + inoff;
  const float* Wo = ws + WC + (l*128 + o)*384;
  float acc = in[o*128 + t] + ws[WBC + l*128 + o];
  for (int c=0;c<128;++c){
    float v0 = (t-d >= 0)  ? in[c*128 + t - d] : 0.f;
    float v1 = in[c*128 + t];
    float v2 = (t+d < 128) ? in[c*128 + t + d] : 0.f;
    acc += Wo[c*3]*v0 + Wo[c*3+1]*v1 + Wo[c*3+2]*v2;
  }
  ws[outoff + o*128 + t] = acc >= 0.f ? acc : 0.2f*acc;
}

// topk + encoded (selection only; time/transfer moved to k_tt)
__global__ void k_topk(float* __restrict__ ws, float* __restrict__ out){
  const float* h = ws + HB;
  int t = threadIdx.x;
  __shared__ float nt[128], nt0[128];
  __shared__ int idxs[16];
  __shared__ float r2[2];
  __shared__ float wv[2]; __shared__ int wi[2];
  float colsq = 0.f;
  for (int c=0;c<128;++c){ float v = h[c*128 + t]; colsq += v*v; }
  float s = colsq;
  for (int o=32;o;o>>=1) s += __shfl_down(s, o);
  if ((t & 63) == 0) r2[t>>6] = s;
  __syncthreads();
  float g2 = sqrtf(r2[0] + r2[1]) + 1e-8f;
  float sq2 = 0.f;
  for (int c=0;c<128;++c){ float v = __fdiv_rn(h[c*128 + t], g2); sq2 += v*v; }
  float ntv = sqrtf(sq2);
  nt[t] = ntv; nt0[t] = ntv;
  __syncthreads();
  for (int j=0;j<16;++j){
    float v = nt[t]; int bi = t;
    for (int o=32;o;o>>=1){
      float ov = __shfl_down(v, o); int oi = __shfl_down(bi, o);
      if (ov > v || (ov == v && oi < bi)){ v = ov; bi = oi; }
    }
    if ((t & 63) == 0){ wv[t>>6] = v; wi[t>>6] = bi; }
    __syncthreads();
    if (t == 0){
      int win = (wv[1] > wv[0] || (wv[1] == wv[0] && wi[1] < wi[0])) ? wi[1] : wi[0];
      idxs[j] = win; nt[win] = -3.0e38f;
    }
    __syncthreads();
  }
  if (t < 16) out[O_IDX + t] = (float)idxs[t];
  for (int j=0;j<16;++j){
    int ij = idxs[j];
    float hv = __fdiv_rn(h[t*128 + ij], g2);
    float enc = __fdiv_rn(hv, nt0[ij] + 1e-8f);
    out[O_ENC + j*128 + t] = enc;
    ws[EWS + j*128 + t] = enc;
  }
}

// time/transfer linears: 32 blocks x 128 (coalesced Wt column loads)
__global__ void k_tt(float* __restrict__ ws, const float* __restrict__ ttb,
                     const float* __restrict__ trb, float* __restrict__ out){
  int kind = blockIdx.x >> 4, j = blockIdx.x & 15, o = threadIdx.x;
  __shared__ float er[128];
  er[o] = ws[EWS + j*128 + o];
  __syncthreads();
  const float* Wt = ws + (kind ? WT_TR : WT_TT);
  float acc = kind ? trb[o] : ttb[o];
  for (int c=0;c<128;++c) acc += er[c] * Wt[c*128 + o];
  out[(kind ? O_TR : O_TIME) + j*128 + o] = acc;
  ws[(kind ? TRANSO : TIMEO) + j*128 + o] = acc;
}

// ================= decoder stacks (fused across pos/env/tfu) =================

__global__ void k_lin3(float* __restrict__ ws, const float* __restrict__ plb,
                       const float* __restrict__ elb, const float* __restrict__ tlb){
  int b = blockIdx.x, tid = threadIdx.x;
  int stack = b >> 4, e = b & 15;
  int zoff  = (stack == 0) ? TIMEO : TRANSO;
  int ltoff = (stack == 0) ? LT_POS : (stack == 1) ? LT_ENV : LT_TFU;
  int R     = (stack == 2) ? 1024 : 512;
  int start = (stack == 2) ? 8 : 4;
  int dst   = (stack == 0) ? PA : (stack == 1) ? BUFA : TA;
  const float* lb = (stack == 0) ? plb : (stack == 1) ? elb : tlb;
  __shared__ float z[128];
  if (tid < 128) z[tid] = ws[zoff + e*128 + tid];
  __syncthreads();
  if (tid < (start<<7)){
    int s = tid >> 7, c = tid & 127;
    int r = c*start + s;
    float acc = lb[r];
    const float* lt = ws + ltoff;
    for (int k=0;k<128;++k) acc += z[k] * lt[k*R + r];
    ws[dst + e*(start<<7) + tid] = acc;   // (e, s, c) layout
  }
}

static __device__ __forceinline__ void convT32_dev(float* __restrict__ ws, const float* __restrict__ bias,
                                                   int srcoff, int dstoff, int wtoff, int Lin,
                                                   int e, int jt, float* xs){
  int j0 = jt*32, o = threadIdx.x;
  int s_lo = (j0 >> 1) - 1;
  const float* in = ws + srcoff + e*Lin*128;
  for (int idx=o; idx<18*128; idx+=128){
    int si = idx >> 7, c = idx & 127, s = s_lo + si;
    xs[idx] = (s >= 0 && s < Lin) ? in[s*128 + c] : 0.f;
  }
  __syncthreads();
  float acc[32];
#pragma unroll
  for (int jj=0;jj<32;++jj) acc[jj] = bias[o];
  const float* wt = ws + wtoff;
  for (int c=0;c<128;++c){
    float w0 = wt[((c<<2)+0)*128 + o];
    float w1 = wt[((c<<2)+1)*128 + o];
    float w2 = wt[((c<<2)+2)*128 + o];
    float w3 = wt[((c<<2)+3)*128 + o];
#pragma unroll
    for (int jj=0;jj<32;++jj){
      if ((jj & 1) == 0){
        acc[jj] += xs[((jj>>1)<<7) + c]*w3 + xs[(((jj>>1)+1)<<7) + c]*w1;
      } else {
        acc[jj] += xs[(((jj+1)>>1)<<7) + c]*w2 + xs[((((jj+1)>>1)+1)<<7) + c]*w0;
      }
    }
  }
  int Lout = Lin*2;
  float* outp = ws + dstoff + e*Lout*128;
#pragma unroll
  for (int jj=0;jj<32;++jj){
    if (j0+jj < Lout){
      float v = acc[jj];
      outp[(j0+jj)*128 + o] = v >= 0.f ? v : 0.2f*v;
    }
  }
}

static __device__ __forceinline__ void conv3up32_dev(float* __restrict__ ws, const float* __restrict__ bias,
                                                     int srcoff, int dstoff, int wtoff, int Lin,
                                                     int e, int jt, float* xs){
  int j0 = jt*32, o = threadIdx.x;
  int fs = (j0 >> 1) - 1;
  const float* in = ws + srcoff + e*Lin*128;
  for (int idx=o; idx<18*128; idx+=128){
    int si = idx >> 7, c = idx & 127, s = fs + si;
    xs[idx] = (s >= 0 && s < Lin) ? in[s*128 + c] : 0.f;
  }
  __syncthreads();
  float acc[32];
#pragma unroll
  for (int jj=0;jj<32;++jj) acc[jj] = bias[o];
  const float* wt = ws + wtoff;
  for (int c=0;c<128;++c){
    float w0 = wt[(c*3+0)*128 + o];
    float w1 = wt[(c*3+1)*128 + o];
    float w2 = wt[(c*3+2)*128 + o];
#pragma unroll
    for (int jj=0;jj<32;++jj){
      acc[jj] += xs[((((jj-1)>>1)+1)<<7) + c]*w0
               + xs[((((jj  )>>1)+1)<<7) + c]*w1
               + xs[((((jj+1)>>1)+1)<<7) + c]*w2;
    }
  }
  int Lout = Lin*2;
  float* outp = ws + dstoff + e*Lout*128;
#pragma unroll
  for (int jj=0;jj<32;++jj){
    if (j0+jj < Lout){
      float v = acc[jj];
      outp[(j0+jj)*128 + o] = v >= 0.f ? v : 0.2f*v;
    }
  }
}

__global__ __launch_bounds__(128)
void k_layer(float* __restrict__ ws, const float* __restrict__ pbias,
             const float* __restrict__ ebias, const float* __restrict__ tbias,
             int c1, int c2,
             int pLin, int pWt, int pBo, int pNJ, int pSrc, int pDst,
             int eLin, int eWt, int eBo, int eNJ, int eSrc, int eDst,
             int tLin, int tWt, int tBo, int tNJ, int tSrc, int tDst){
  __shared__ float xs[18*128];
  int b = blockIdx.x;
  if (b < c1){
    int e = b / pNJ, jt = b - e*pNJ;
    convT32_dev(ws, pbias + pBo, pSrc, pDst, pWt, pLin, e, jt, xs);
  } else if (b < c2){
    int bl = b - c1; int e = bl / eNJ, jt = bl - e*eNJ;
    conv3up32_dev(ws, ebias + eBo, eSrc, eDst, eWt, eLin, e, jt, xs);
  } else {
    int bl = b - c2; int e = bl / tNJ, jt = bl - e*tNJ;
    conv3up32_dev(ws, tbias + tBo, tSrc, tDst, tWt, tLin, e, jt, xs);
  }
}

// fused epilogues: blocks 0..15 out_pos, 16..79 out_env, 80..143 out_tfu ; 256 threads
__global__ void k_outs(float* __restrict__ ws,
                       const float* __restrict__ pw, const float* __restrict__ pb,
                       const float* __restrict__ ew, const float* __restrict__ eb,
                       const float* __restrict__ tw, const float* __restrict__ tb_,
                       float* __restrict__ out){
  __shared__ float xs[16384];
  int b = blockIdx.x, tid = threadIdx.x;
  if (b < 16){
    int e = b;
    const float* in = ws + PB + e*16384;
    for (int idx=tid; idx<16384; idx+=256){
      int q = idx >> 7, c = idx & 127;
      xs[(q<<7) + ((c+q)&127)] = in[idx];
    }
    __syncthreads();
    float acc = pb[0];
    if (tid < 128){
      int j = tid;
      for (int c=0;c<128;++c){
#pragma unroll
        for (int k=0;k<3;++k){
          int q = j + k - 1;
          if (q >= 0 && q < 128) acc += xs[(q<<7) + ((c+q)&127)] * pw[c*3 + k];
        }
      }
    }
    __syncthreads();
    xs[tid] = (tid < 128) ? acc : -3.0e38f;
    __syncthreads();
    for (int s=128; s>=1; s>>=1){ if (tid < s) xs[tid] = fmaxf(xs[tid], xs[tid+s]); __syncthreads(); }
    float m = xs[0];
    __syncthreads();
    float ex = (tid < 128) ? expf(__fsub_rn(acc, m)) : 0.f;
    xs[tid] = ex;
    __syncthreads();
    for (int s=128; s>=1; s>>=1){ if (tid < s) xs[tid] += xs[tid+s]; __syncthreads(); }
    if (tid < 128) ws[PE + e*128 + tid] = __fdiv_rn(ex, xs[0]);
  } else if (b < 80){
    int idx2 = b - 16; int e = idx2 >> 2, b0 = (idx2 & 3) << 6;
    const float* in = ws + BUFA + e*32768;
    for (int idx=tid; idx<8448; idx+=256){
      int qs = idx >> 7, c = idx & 127, q = b0 - 1 + qs;
      xs[(qs<<7) + ((c+qs)&127)] = (q >= 0 && q < 256) ? in[q*128 + c] : 0.f;
    }
    __syncthreads();
    int part = tid >> 6, bb = tid & 63;
    float acc = (part == 0) ? eb[0] : 0.f;
    for (int c2=0;c2<32;++c2){
      int c = part*32 + c2;
#pragma unroll
      for (int k=0;k<3;++k){
        int qs = bb + k;
        acc += xs[(qs<<7) + ((c+qs)&127)] * ew[c*3 + k];
      }
    }
    xs[8448 + tid] = acc;
    __syncthreads();
    if (tid < 64){
      float a = xs[8448+tid] + xs[8448+64+tid] + xs[8448+128+tid] + xs[8448+192+tid];
      a = fmaxf(a, 0.f);
      out[O_ENV + e*256 + b0 + tid] = a;
      ws[ENVO + e*256 + b0 + tid] = a;
    }
  } else {
    // out_tfu: 64 blocks = (event e, rr-group rg of 8 rows); all-LDS inner loop
    int b2 = b - 80; int e = b2 >> 2, rg = b2 & 3;
    float* tws = xs + 8448;              // 3072 floats
    const float* in = ws + TB + e*8192;
    for (int idx=tid; idx<8448; idx+=256){
      int qs = idx >> 7, c = idx & 127, q = -1 + qs;
      xs[(qs<<7) + ((c+qs)&127)] = (q >= 0 && q < 64) ? in[q*128 + c] : 0.f;
    }
    for (int idx=tid; idx<3072; idx+=256) tws[idx] = tw[rg*3072 + idx];
    __syncthreads();
    int rl0 = tid >> 6, bb = tid & 63;
    for (int rl=rl0; rl<8; rl+=4){
      int rr = rg*8 + rl;
      float acc = tb_[rr];
      for (int c=0;c<128;++c){
#pragma unroll
        for (int k=0;k<3;++k){
          int qs = bb + k;
          acc += xs[(qs<<7) + ((c+qs)&127)] * tws[rl*384 + c*3 + k];
        }
      }
      ws[TFQ + e*2048 + rr*64 + bb] = acc;
    }
  }
}

// ================= synthesis =================

// fused: blocks 0..2047 resonance-K (bf16, with inline argmax), blocks 2048..4095 envs
__global__ void k_envK(float* __restrict__ ws, const float* __restrict__ noise){
  int b = blockIdx.x, tid = threadIdx.x;
  if (b < 2048){
    int e = b >> 7, F = b & 127;
    int t = (F << 8) + tid;
    __shared__ float ampl[64];
    if (tid < 64){
      const float* tf = ws + TFQ + e*2048;
      float best = tf[tid]; int bi = 0;
      for (int r=1;r<32;++r){ float v = tf[r*64 + tid]; if (v > best){ best = v; bi = r; } }
      float d = __fadd_rn(0.5f, __fmul_rn((float)bi, __fdiv_rn(__fsub_rn(0.9999f, 0.5f), 31.0f)));
      ampl[tid] = (float)pow((double)d, (double)F);
    }
    __syncthreads();
    float acc = 0.f;
    for (int band=0;band<64;++band) acc += ws[SINES + band*NSAMP + t] * ampl[band];
    ((unsigned short*)(ws + KB))[e*34816 + 2048 + t] = f2bf(acc * (1.0f/(64.0f*65536.0f)));
  } else {
    int idx = (b - 2048)*256 + tid;
    int e = idx >> 15, tau = idx & 32767;
    float cf = __fsub_rn(__fdiv_rn(__fmul_rn(__fadd_rn((float)tau, 0.5f), 256.0f), 32768.0f), 0.5f);
    float c = fminf(fmaxf(cf, 0.0f), 255.0f);
    int i0 = (int)floorf(c);
    int i1 = min(i0 + 1, 255);
    float w = __fsub_rn(c, (float)i0);
    float e0 = ws[ENVO + e*256 + i0], e1 = ws[ENVO + e*256 + i1];
    float val = __fadd_rn(__fmul_rn(e0, __fsub_rn(1.0f, w)), __fmul_rn(e1, w));
    ws[ENVS + e*NSAMP + tau] = val * noise[tau];
  }
}

// impulse-comb conv; writes reversed bf16 copies (CRB0/CRB1) for the MFMA stage
__global__ void k_c(float* __restrict__ ws){
  int e = blockIdx.x >> 5, seg = blockIdx.x & 31;
  int t = (seg << 10) + threadIdx.x;
  __shared__ float pl[128];
  if (threadIdx.x < 128) pl[threadIdx.x] = ws[PE + e*128 + threadIdx.x];
  __syncthreads();
  const float* ev = ws + ENVS + e*NSAMP;
  int kub = min(127, (seg << 2) + 3);
  float acc = 0.f;
  for (int k=0;k<=kub;++k){
    int u = t - (k << 8);
    if (u >= 0) acc += pl[k] * ev[u];
  }
  unsigned short hv = f2bf(acc);
  ((unsigned short*)(ws + CRB0))[e*32832 + 32768 - t] = hv;
  ((unsigned short*)(ws + CRB1))[e*32832 + 32767 - t] = hv;
}

// Toeplitz conv via MFMA 32x32x16 bf16; 16 KB LDS two-phase reduction, no atomics.
__global__ __launch_bounds__(256, 4)
void k_bigmfma(float* __restrict__ ws){
  int b = blockIdx.x;
  int w = threadIdx.x >> 6;
  int lane = threadIdx.x & 63;
  int e = b / 72;
  int r = b - e*72;
  int T2 = 0, cum = 0;
  while (cum + ((T2+2)>>1) <= r){ cum += (T2+2)>>1; T2++; }
  int qb = r - cum;
  int nseg = 2*(T2+1);
  int seg = qb*4 + w;
  int t0 = T2 << 11;
  int il = lane & 31, h = lane >> 5;
  __shared__ float red[2][2048];
  f32x16 acc0 = {}; f32x16 acc1 = {};
  if (seg < nseg){
    int u0 = -1984 + (seg << 10);
    const unsigned short* Kp  = (const unsigned short*)(ws + KB)   + e*34816 + 2048;
    const unsigned short* C0p = (const unsigned short*)(ws + CRB0) + e*32832;
    const unsigned short* C1p = (const unsigned short*)(ws + CRB1) + e*32832;
    int bB  = u0 + (il << 6) + (h << 3);
    int bA0 = 32768 - t0 + u0 - (il << 1) + (h << 3);
    int bA1 = bA0 - 2;
#pragma unroll 2
    for (int q = 0; q < 64; ++q){
      union { f32x4 v; bf16x8 s; } a0u, a1u, bu;
      a0u.v = *(const f32x4*)(C0p + bA0);
      a1u.v = *(const f32x4*)(C1p + bA1);
      bu.v  = *(const f32x4*)(Kp  + bB);
      acc0 = __builtin_amdgcn_mfma_f32_32x32x16_bf16(a0u.s, bu.s, acc0, 0, 0, 0);
      acc1 = __builtin_amdgcn_mfma_f32_32x32x16_bf16(a1u.s, bu.s, acc1, 0, 0, 0);
      bA0 += 16; bA1 += 16; bB += 16;
    }
  }
  int wl = w & 1;
  if (w < 2){
#pragma unroll
    for (int rr = 0; rr < 16; ++rr){
      int row = (rr & 3) + ((rr >> 2) << 3) + (h << 2);
      red[wl][(row << 6) + il]      = acc0[rr];
      red[wl][(row << 6) + 32 + il] = acc1[rr];
    }
  }
  __syncthreads();
  if (w >= 2){
#pragma unroll
    for (int rr = 0; rr < 16; ++rr){
      int row = (rr & 3) + ((rr >> 2) << 3) + (h << 2);
      red[wl][(row << 6) + il]      += acc0[rr];
      red[wl][(row << 6) + 32 + il] += acc1[rr];
    }
  }
  __syncthreads();
  float* slab = ws + SLAB + b*2048;
  int tid = threadIdx.x;
#pragma unroll
  for (int jj = 0; jj < 8; ++jj){
    int pos = tid*8 + jj;                // pos = il2*64 + (2*row + p)
    int il2 = pos >> 6, x = pos & 63;
    int idx = ((x >> 1) << 6) + ((x & 1) << 5) + il2;
    slab[pos] = red[0][idx] + red[1][idx];
  }
}

__global__ void k_final(const float* __restrict__ ws, float* __restrict__ out){
  int t = blockIdx.x*1024 + threadIdx.x;
  int T2 = t >> 11, pos = t & 2047;
  int cum = 0;
  for (int j=0;j<T2;++j) cum += (j+2)>>1;
  int nb = (T2+2)>>1;
  float s = 0.f;
  for (int e=0;e<16;++e){
    const float* sl = ws + SLAB + (e*72 + cum)*2048 + pos;
    for (int q=0;q<nb;++q) s += sl[q*2048];
  }
  out[t] = s;
}

// ================= launcher =================

extern "C" void kernel_launch(void* const* d_in, const int* in_sizes, int n_in,
                              void* d_out, int out_size, void* d_ws, size_t ws_size,
                              hipStream_t stream){
  const float* x         = (const float*)d_in[0];
  const float* noise     = (const float*)d_in[1];
  const float* fb_w      = (const float*)d_in[2];
  const float* reduce_w  = (const float*)d_in[3];
  const float* reduce_b  = (const float*)d_in[4];
  const float* dl_dw     = (const float*)d_in[5];
  const float* dl_db     = (const float*)d_in[6];
  const float* dl_pw     = (const float*)d_in[7];
  const float* dl_pb     = (const float*)d_in[8];
  const float* tt_w      = (const float*)d_in[9];
  const float* tt_b      = (const float*)d_in[10];
  const float* tr_w      = (const float*)d_in[11];
  const float* tr_b      = (const float*)d_in[12];
  const float* pos_lin_w = (const float*)d_in[13];
  const float* pos_lin_b = (const float*)d_in[14];
  const float* pos_up_w  = (const float*)d_in[15];
  const float* pos_up_b  = (const float*)d_in[16];
  const float* pos_out_w = (const float*)d_in[17];
  const float* pos_out_b = (const float*)d_in[18];
  const float* env_lin_w = (const float*)d_in[19];
  const float* env_lin_b = (const float*)d_in[20];
  const float* env_up_w  = (const float*)d_in[21];
  const float* env_up_b  = (const float*)d_in[22];
  const float* env_out_w = (const float*)d_in[23];
  const float* env_out_b = (const float*)d_in[24];
  const float* tfu_lin_w = (const float*)d_in[25];
  const float* tfu_lin_b = (const float*)d_in[26];
  const float* tfu_up_w  = (const float*)d_in[27];
  const float* tfu_up_b  = (const float*)d_in[28];
  const float* tfu_out_w = (const float*)d_in[29];
  const float* tfu_out_b = (const float*)d_in[30];
  float* out = (float*)d_out;
  float* ws  = (float*)d_ws;

  k_setup<<<3201, 1024, 0, stream>>>(x, pos_up_w, env_up_w, tfu_up_w, tt_w, tr_w,
                                     pos_lin_w, env_lin_w, tfu_lin_w,
                                     dl_dw, dl_db, dl_pw, dl_pb, ws);
  k_fbpool<<<4096, 512, 0, stream>>>(fb_w, ws);
  k_reduce<<<128, 128, 0, stream>>>(reduce_w, reduce_b, ws);
  const int DIL[5] = {1, 3, 9, 27, 1};
  int src = HA, dst = HB;
  for (int l=0;l<5;++l){
    k_dil<<<128, 128, 0, stream>>>(ws, l, DIL[l], src, dst);
    int tmp = src; src = dst; dst = tmp;
  }
  k_topk<<<1, 128, 0, stream>>>(ws, out);
  k_tt<<<32, 128, 0, stream>>>(ws, tt_b, tr_b, out);
  k_lin3<<<48, 1024, 0, stream>>>(ws, pos_lin_b, env_lin_b, tfu_lin_b);

  // fused decoder layers (pos convT | env conv3 | tfu conv3)
  k_layer<<<48, 128, 0, stream>>>(ws, pos_up_b, env_up_b, tfu_up_b, 16, 32,
      4,  WT_POS + 0,      0,   1, PA,   PB,
      4,  WT_ENV + 0,      0,   1, BUFA, BUFB,
      8,  WT_TFU + 0,      0,   1, TA,   TB);
  k_layer<<<48, 128, 0, stream>>>(ws, pos_up_b, env_up_b, tfu_up_b, 16, 32,
      8,  WT_POS + 65536,  128, 1, PB,   PA,
      8,  WT_ENV + 49152,  128, 1, BUFB, BUFA,
      16, WT_TFU + 49152,  128, 1, TB,   TA);
  k_layer<<<64, 128, 0, stream>>>(ws, pos_up_b, env_up_b, tfu_up_b, 16, 32,
      16, WT_POS + 131072, 256, 1, PA,   PB,
      16, WT_ENV + 98304,  256, 1, BUFA, BUFB,
      32, WT_TFU + 98304,  256, 2, TA,   TB);
  k_layer<<<64, 128, 0, stream>>>(ws, pos_up_b, env_up_b, tfu_up_b, 32, 64,
      32, WT_POS + 196608, 384, 2, PB,   PA,
      32, WT_ENV + 147456, 384, 2, BUFB, BUFA,
      1,  0,               0,   1, 0,    0);
  k_layer<<<128, 128, 0, stream>>>(ws, pos_up_b, env_up_b, tfu_up_b, 64, 128,
      64, WT_POS + 262144, 512, 4, PA,   PB,
      64, WT_ENV + 196608, 512, 4, BUFA, BUFB,
      1,  0,               0,   1, 0,    0);
  k_layer<<<128, 128, 0, stream>>>(ws, pos_up_b, env_up_b, tfu_up_b, 0, 128,
      1,  0,               0,   1, 0,    0,
      128, WT_ENV + 245760, 640, 8, BUFB, BUFA,
      1,  0,               0,   1, 0,    0);

  k_outs<<<144, 256, 0, stream>>>(ws, pos_out_w, pos_out_b, env_out_w, env_out_b,
                                  tfu_out_w, tfu_out_b, out);

  k_envK<<<4096, 256, 0, stream>>>(ws, noise);
  k_c<<<512, 1024, 0, stream>>>(ws);
  k_bigmfma<<<1152, 256, 0, stream>>>(ws);
  k_final<<<32, 1024, 0, stream>>>(ws, out);
}

// Round 6
// 891.694 us; speedup vs baseline: 2.3203x; 1.0151x over previous
//
#include <hip/hip_runtime.h>
#include <math.h>

// ---------------- constants ----------------
#define NSAMP 32768
#define NFRM  128

// ---- ws layout (float offsets) ----
static constexpr int S_OFF  = 0;                   // 32772 (prefix sums, 32769 used)
static constexpr int HP     = 32772;               // 16384
static constexpr int NSQ    = HP + 16384;          // 16 (unused now)
static constexpr int HA     = NSQ + 16;            // 16384
static constexpr int HB     = HA + 16384;          // 16384
static constexpr int TFQ    = HA;                  // 32768 tf scores (overlays HA+HB, dead after topk)
static constexpr int WC     = HB + 16384;          // 245760 combined dilated weights
static constexpr int WBC    = WC + 245760;         // 640 combined dilated bias
static constexpr int EWS    = WBC + 640;           // 2048 encoded
static constexpr int TIMEO  = EWS + 2048;          // 2048
static constexpr int TRANSO = TIMEO + 2048;        // 2048
static constexpr int PE     = TRANSO + 2048;       // 2048 softmax impulse weights
static constexpr int RSEL   = PE + 2048;           // 1024 (unused now)
static constexpr int ENVO   = RSEL + 1024;         // 4096 env (16,256)
static constexpr int BUFA   = ENVO + 4096;         // 524288  (env stack A)
static constexpr int BUFB   = BUFA + 524288;       // 524288  (env stack B)
static constexpr int WT     = BUFB + 524288;       // transposed weights, 1064960 total
static constexpr int WT_POS = WT;                  // 327680  [l][(c*4+k)*128+o]
static constexpr int WT_ENV = WT + 327680;         // 294912  [l][(c*3+k)*128+o]
static constexpr int WT_TFU = WT + 622592;         // 147456
static constexpr int WT_TT  = WT + 770048;         // 16384   [c][o]
static constexpr int WT_TR  = WT + 786432;         // 16384
static constexpr int LT_POS = WT + 802816;         // 65536   [k][r], R=512
static constexpr int LT_ENV = WT + 868352;         // 65536
static constexpr int LT_TFU = WT + 933888;         // 131072  [k][r], R=1024
static constexpr int SINES  = WT + 1064960;        // 2097152 (64 x 32768)
static constexpr int ENVS   = SINES + 2097152;     // 524288 (16 x 32768 f32)
// SLAB overlays SINES+ENVS (both dead once k_bigmfma runs)
static constexpr int SLAB   = SINES;
// bf16 conv operands (ushort-indexed off these f32 offsets)
static constexpr int CRB0   = ENVS + 524288;       // 16 x 32832 ushort ; CRB0[x]=c[32768-x]
static constexpr int CRB1   = CRB0 + 262656;       // 16 x 32832 ushort ; CRB1[y]=c[32767-y]
static constexpr int KB     = CRB1 + 262656;       // 16 x 34816 ushort ; KB[2048+u]=K[u]
// pos / tfu stack ping-pong buffers (disjoint from env's BUFA/BUFB)
static constexpr int PA     = KB + 278528;         // 262144
static constexpr int PB     = PA + 262144;         // 262144
static constexpr int TA     = PB + 262144;         // 131072
static constexpr int TB     = TA + 131072;         // 131072

// ---- output offsets ----
static constexpr int O_IDX  = 32768;
static constexpr int O_ENC  = 32784;
static constexpr int O_ENV  = 34832;
static constexpr int O_TIME = 38928;
static constexpr int O_TR   = 40976;

typedef short bf16x8 __attribute__((ext_vector_type(8)));
typedef float f32x4  __attribute__((ext_vector_type(4)));
typedef float f32x16 __attribute__((ext_vector_type(16)));

static __device__ __forceinline__ unsigned short f2bf(float f){
  unsigned int u = __float_as_uint(f);
  unsigned int r = (u + 0x7FFFu + ((u >> 16) & 1u)) >> 16;
  return (unsigned short)r;
}

// ================= fused setup: prefix + wtrans + combW + sines + zero =================
// Block map: [0]=prefix, [1,1041)=wtrans, [1041,1121)=combW, [1121,3169)=sines, [3169,3201)=zero
__global__ void k_setup(const float* __restrict__ x,
                        const float* __restrict__ posw, const float* __restrict__ envw,
                        const float* __restrict__ tfuw, const float* __restrict__ ttw,
                        const float* __restrict__ trw,  const float* __restrict__ lpw,
                        const float* __restrict__ lew,  const float* __restrict__ ltw,
                        const float* __restrict__ dw,   const float* __restrict__ db,
                        const float* __restrict__ pw,   const float* __restrict__ pb2,
                        float* __restrict__ ws){
  __shared__ float ps[1024];
  int b = blockIdx.x, tid = threadIdx.x;
  if (b == 0){
    // exclusive prefix sums of x into S
    float* S = ws + S_OFF;
    float v[32];
    const float4* x4 = (const float4*)(x + tid*32);
    float s = 0.f;
#pragma unroll
    for (int i=0;i<8;++i){
      float4 q = x4[i];
      v[4*i]=q.x; v[4*i+1]=q.y; v[4*i+2]=q.z; v[4*i+3]=q.w;
      s += q.x+q.y+q.z+q.w;
    }
    ps[tid] = s; __syncthreads();
    for (int ofs=1; ofs<1024; ofs<<=1){
      float add = (tid>=ofs)? ps[tid-ofs] : 0.f;
      __syncthreads();
      ps[tid] += add;
      __syncthreads();
    }
    float run = ps[tid] - s;
#pragma unroll
    for (int i=0;i<32;++i){ S[tid*32+i] = run; run += v[i]; }
    if (tid==1023) S[32768] = ps[1023];
  } else if (b < 1041){
    int i = (b-1)*1024 + tid;
    float v;
    if (i < 327680){                       // pos_up (5,128,128,4) -> [l][(c*4+k)*128+o]
      int l = i>>16, r = i & 65535, o = r & 127, ck = r>>7, c = ck>>2, k = ck&3;
      v = posw[(l<<16) + (((o<<7)+c)<<2) + k];
    } else if (i < 622592){                // env_up (6,128,128,3)
      int i2 = i - 327680; int l = i2/49152, r = i2 - l*49152, o = r&127, ck = r>>7;
      int c = ck/3, k = ck - 3*c;
      v = envw[l*49152 + ((o<<7)+c)*3 + k];
    } else if (i < 770048){                // tfu_up (3,128,128,3)
      int i2 = i - 622592; int l = i2/49152, r = i2 - l*49152, o = r&127, ck = r>>7;
      int c = ck/3, k = ck - 3*c;
      v = tfuw[l*49152 + ((o<<7)+c)*3 + k];
    } else if (i < 786432){                // tt_w -> [c][o]
      int i2 = i - 770048; int o = i2 & 127, c = i2 >> 7;
      v = ttw[(o<<7) + c];
    } else if (i < 802816){                // tr_w
      int i2 = i - 786432; int o = i2 & 127, c = i2 >> 7;
      v = trw[(o<<7) + c];
    } else if (i < 868352){                // pos_lin -> [k][r]
      int i2 = i - 802816; int r = i2 & 511, k = i2 >> 9;
      v = lpw[(r<<7) + k];
    } else if (i < 933888){                // env_lin
      int i2 = i - 868352; int r = i2 & 511, k = i2 >> 9;
      v = lew[(r<<7) + k];
    } else {                               // tfu_lin
      int i2 = i - 933888; int r = i2 & 1023, k = i2 >> 10;
      v = ltw[(r<<7) + k];
    }
    ws[WT + i] = v;
  } else if (b < 1121){
    // combW: fold pointwise (pw) into dilated weights
    int idx = (b-1041)*1024 + tid;
    if (idx < 81920){
      int l = idx >> 14, r = idx & 16383, o = r >> 7, c = r & 127;
      float a0=0.f, a1=0.f, a2=0.f;
      for (int m=0;m<128;++m){
        float p = pw[(l*128 + o)*128 + m];
        const float* dp = dw + ((l*128 + m)*128 + c)*3;
        a0 += p*dp[0]; a1 += p*dp[1]; a2 += p*dp[2];
      }
      float* W = ws + WC + ((l*128 + o)*128 + c)*3;
      W[0]=a0; W[1]=a1; W[2]=a2;
      if (c==0){
        float bb = pb2[l*128 + o];
        for (int m=0;m<128;++m) bb += pw[(l*128 + o)*128 + m] * db[l*128 + m];
        ws[WBC + l*128 + o] = bb;
      }
    }
  } else if (b < 3169){
    int b2 = b - 1121;
    int band = b2 >> 5;
    int t = ((b2 & 31) << 10) + tid;
    if (tid == 0){
      float l0 = __fdiv_rn((float)log(20.0),   (float)log(10.0));
      float l1 = __fdiv_rn((float)log(9922.5), (float)log(10.0));
      float dl = __fdiv_rn(__fsub_rn(l1, l0), 63.0f);
      float lb = __fadd_rn(l0, __fmul_rn((float)band, dl));
      float freq = (float)pow(10.0, (double)lb);
      ps[0] = __fmul_rn((float)(2.0*M_PI), freq);
    }
    __syncthreads();
    float w = ps[0];
    float tn = __fdiv_rn((float)t, 22050.0f);
    ws[SINES + band*NSAMP + t] = sinf(__fmul_rn(w, tn));
  } else {
    int i = (b-3169)*1024 + tid;   // [0,32768)
    {
      int e = i >> 11, r = i & 2047;
      ((unsigned short*)(ws + KB))[e*34816 + r] = 0;
    }
    if (i < 16*128){
      int e = i >> 7, r = i & 127;
      if (r < 64) ((unsigned short*)(ws + CRB0))[e*32832 + (r==0 ? 0 : 32768 + r)] = 0;
      else        ((unsigned short*)(ws + CRB1))[e*32832 + 32768 + (r-64)] = 0;
    }
  }
}

// ================= front-end =================

__global__ void k_fbpool(const float* __restrict__ fbw, float* __restrict__ ws){
  const float* S = ws + S_OFF;
  int c = blockIdx.x >> 5, j0 = (blockIdx.x & 31) << 2;
  int jj = threadIdx.x >> 7, kk = threadIdx.x & 127;
  int j = j0 + jj;
  int i0 = max(0, 256*j - 256), i1 = min(32767, 256*j + 255);
  float acc = 0.f;
#pragma unroll
  for (int m=0;m<4;++m){
    int k = kk + (m<<7);
    int hi = min(max(i1 + k - 255, 0), 32768);
    int lo = min(max(i0 + k - 256, 0), 32768);
    acc += fbw[c*512 + k] * (S[hi] - S[lo]);
  }
  for (int o=32;o;o>>=1) acc += __shfl_down(acc, o);
  __shared__ float red[8];
  if ((threadIdx.x & 63) == 0) red[threadIdx.x>>6] = acc;
  __syncthreads();
  if (threadIdx.x < 4)
    ws[HP + c*128 + j0 + threadIdx.x] = (red[2*threadIdx.x] + red[2*threadIdx.x+1]) * (1.0f/512.0f);
}

__global__ void k_reduce(const float* __restrict__ rw, const float* __restrict__ rb,
                         float* __restrict__ ws){
  int o = blockIdx.x, t = threadIdx.x;
  const float* hp = ws + HP;
  float sq = 0.f;
  for (int i=t;i<16384;i+=128){ float v = hp[i]; sq += v*v; }
  for (int ofs=32;ofs;ofs>>=1) sq += __shfl_down(sq, ofs);
  __shared__ float rr2[2];
  if ((t & 63) == 0) rr2[t>>6] = sq;
  __syncthreads();
  float g = sqrtf(rr2[0] + rr2[1]) + 1e-8f;
  float acc = rb[o];
  for (int c=0;c<128;++c) acc += rw[o*161 + c] * __fdiv_rn(hp[c*128 + t], g);
  float delta = __fdiv_rn(2.0f, 127.0f);
  float p = __fadd_rn(-1.0f, __fmul_rn((float)t, delta));
  acc += rw[o*161 + 128] * p;
  float sc = 1.0f;
  const float PIF = (float)M_PI;
#pragma unroll
  for (int i=0;i<16;++i){
    float f = __fmul_rn(__fmul_rn(p, sc), PIF);
    acc += rw[o*161 + 129 + 2*i] * sinf(f);
    acc += rw[o*161 + 130 + 2*i] * cosf(f);
    sc = sc * 2.0f;
  }
  ws[HA + o*128 + t] = acc;
}

// dilated conv layer: full input tile LDS-staged (one load window, no per-c global chain)
__global__ void k_dil(float* __restrict__ ws, int l, int d, int inoff, int outoff){
  __shared__ float xin[16384];
  int o = blockIdx.x, t = threadIdx.x;
  const float* in = ws + inoff;
  for (int idx=t; idx<16384; idx+=128) xin[idx] = in[idx];
  __syncthreads();
  const float* Wo = ws + WC + (l*128 + o)*384;
  float acc = xin[o*128 + t] + ws[WBC + l*128 + o];
  for (int c=0;c<128;++c){
    float v0 = (t-d >= 0)  ? xin[c*128 + t - d] : 0.f;
    float v1 = xin[c*128 + t];
    float v2 = (t+d < 128) ? xin[c*128 + t + d] : 0.f;
    acc += Wo[c*3]*v0 + Wo[c*3+1]*v1 + Wo[c*3+2]*v2;
  }
  ws[outoff + o*128 + t] = acc >= 0.f ? acc : 0.2f*acc;
}

// topk + encoded (selection only)
__global__ void k_topk(float* __restrict__ ws, float* __restrict__ out){
  const float* h = ws + HB;
  int t = threadIdx.x;
  __shared__ float nt[128], nt0[128];
  __shared__ int idxs[16];
  __shared__ float r2[2];
  __shared__ float wv[2]; __shared__ int wi[2];
  float colsq = 0.f;
  for (int c=0;c<128;++c){ float v = h[c*128 + t]; colsq += v*v; }
  float s = colsq;
  for (int o=32;o;o>>=1) s += __shfl_down(s, o);
  if ((t & 63) == 0) r2[t>>6] = s;
  __syncthreads();
  float g2 = sqrtf(r2[0] + r2[1]) + 1e-8f;
  float sq2 = 0.f;
  for (int c=0;c<128;++c){ float v = __fdiv_rn(h[c*128 + t], g2); sq2 += v*v; }
  float ntv = sqrtf(sq2);
  nt[t] = ntv; nt0[t] = ntv;
  __syncthreads();
  for (int j=0;j<16;++j){
    float v = nt[t]; int bi = t;
    for (int o=32;o;o>>=1){
      float ov = __shfl_down(v, o); int oi = __shfl_down(bi, o);
      if (ov > v || (ov == v && oi < bi)){ v = ov; bi = oi; }
    }
    if ((t & 63) == 0){ wv[t>>6] = v; wi[t>>6] = bi; }
    __syncthreads();
    if (t == 0){
      int win = (wv[1] > wv[0] || (wv[1] == wv[0] && wi[1] < wi[0])) ? wi[1] : wi[0];
      idxs[j] = win; nt[win] = -3.0e38f;
    }
    __syncthreads();
  }
  if (t < 16) out[O_IDX + t] = (float)idxs[t];
  for (int j=0;j<16;++j){
    int ij = idxs[j];
    float hv = __fdiv_rn(h[t*128 + ij], g2);
    float enc = __fdiv_rn(hv, nt0[ij] + 1e-8f);
    out[O_ENC + j*128 + t] = enc;
    ws[EWS + j*128 + t] = enc;
  }
}

// time/transfer linears: 32 blocks x 1024 (8-way c-split + LDS reduce)
__global__ void k_tt(float* __restrict__ ws, const float* __restrict__ ttb,
                     const float* __restrict__ trb, float* __restrict__ out){
  int kind = blockIdx.x >> 4, j = blockIdx.x & 15;
  int tid = threadIdx.x;
  int o = tid & 127, cg = tid >> 7;     // 8 c-groups
  __shared__ float er[128];
  __shared__ float part[8][128];
  if (tid < 128) er[tid] = ws[EWS + j*128 + tid];
  __syncthreads();
  const float* Wt = ws + (kind ? WT_TR : WT_TT);
  float acc = 0.f;
  for (int c=cg; c<128; c+=8) acc += er[c] * Wt[c*128 + o];
  part[cg][o] = acc;
  __syncthreads();
  if (tid < 128){
    float a = kind ? trb[tid] : ttb[tid];
#pragma unroll
    for (int g=0; g<8; ++g) a += part[g][tid];
    out[(kind ? O_TR : O_TIME) + j*128 + tid] = a;
    ws[(kind ? TRANSO : TIMEO) + j*128 + tid] = a;
  }
}

// ================= decoder stacks (fused across pos/env/tfu) =================

__global__ void k_lin3(float* __restrict__ ws, const float* __restrict__ plb,
                       const float* __restrict__ elb, const float* __restrict__ tlb){
  int b = blockIdx.x, tid = threadIdx.x;
  int stack = b >> 4, e = b & 15;
  int zoff  = (stack == 0) ? TIMEO : TRANSO;
  int ltoff = (stack == 0) ? LT_POS : (stack == 1) ? LT_ENV : LT_TFU;
  int R     = (stack == 2) ? 1024 : 512;
  int start = (stack == 2) ? 8 : 4;
  int dst   = (stack == 0) ? PA : (stack == 1) ? BUFA : TA;
  const float* lb = (stack == 0) ? plb : (stack == 1) ? elb : tlb;
  __shared__ float z[128];
  if (tid < 128) z[tid] = ws[zoff + e*128 + tid];
  __syncthreads();
  if (tid < (start<<7)){
    int s = tid >> 7, c = tid & 127;
    int r = c*start + s;
    float acc = lb[r];
    const float* lt = ws + ltoff;
    for (int k=0;k<128;++k) acc += z[k] * lt[k*R + r];
    ws[dst + e*(start<<7) + tid] = acc;   // (e, s, c) layout
  }
}

// convT (k=4, stride2): weights LDS-staged in 16-c chunks (32 KB)
static __device__ __forceinline__ void convT32_dev(float* __restrict__ ws, const float* __restrict__ bias,
                                                   int srcoff, int dstoff, int wtoff, int Lin,
                                                   int e, int jt, float* xs, float* wl){
  int j0 = jt*32, o = threadIdx.x;
  int s_lo = (j0 >> 1) - 1;
  const float* in = ws + srcoff + e*Lin*128;
  for (int idx=o; idx<18*128; idx+=128){
    int si = idx >> 7, c = idx & 127, s = s_lo + si;
    xs[idx] = (s >= 0 && s < Lin) ? in[s*128 + c] : 0.f;
  }
  float acc[32];
#pragma unroll
  for (int jj=0;jj<32;++jj) acc[jj] = bias[o];
  const float* wt = ws + wtoff;
  for (int cb=0; cb<128; cb+=16){
    __syncthreads();
    for (int idx=o; idx<8192; idx+=128) wl[idx] = wt[(cb<<9) + idx];
    __syncthreads();
#pragma unroll
    for (int cc=0; cc<16; ++cc){
      int c = cb + cc;
      float w0 = wl[((cc<<2)+0)*128 + o];
      float w1 = wl[((cc<<2)+1)*128 + o];
      float w2 = wl[((cc<<2)+2)*128 + o];
      float w3 = wl[((cc<<2)+3)*128 + o];
#pragma unroll
      for (int jj=0;jj<32;++jj){
        if ((jj & 1) == 0){
          acc[jj] += xs[((jj>>1)<<7) + c]*w3 + xs[(((jj>>1)+1)<<7) + c]*w1;
        } else {
          acc[jj] += xs[(((jj+1)>>1)<<7) + c]*w2 + xs[((((jj+1)>>1)+1)<<7) + c]*w0;
        }
      }
    }
  }
  int Lout = Lin*2;
  float* outp = ws + dstoff + e*Lout*128;
#pragma unroll
  for (int jj=0;jj<32;++jj){
    if (j0+jj < Lout){
      float v = acc[jj];
      outp[(j0+jj)*128 + o] = v >= 0.f ? v : 0.2f*v;
    }
  }
}

// conv3 on nearest-2x-upsampled input: weights LDS-staged in 16-c chunks (24 KB)
static __device__ __forceinline__ void conv3up32_dev(float* __restrict__ ws, const float* __restrict__ bias,
                                                     int srcoff, int dstoff, int wtoff, int Lin,
                                                     int e, int jt, float* xs, float* wl){
  int j0 = jt*32, o = threadIdx.x;
  int fs = (j0 >> 1) - 1;
  const float* in = ws + srcoff + e*Lin*128;
  for (int idx=o; idx<18*128; idx+=128){
    int si = idx >> 7, c = idx & 127, s = fs + si;
    xs[idx] = (s >= 0 && s < Lin) ? in[s*128 + c] : 0.f;
  }
  float acc[32];
#pragma unroll
  for (int jj=0;jj<32;++jj) acc[jj] = bias[o];
  const float* wt = ws + wtoff;
  for (int cb=0; cb<128; cb+=16){
    __syncthreads();
    for (int idx=o; idx<6144; idx+=128) wl[idx] = wt[cb*384 + idx];
    __syncthreads();
#pragma unroll
    for (int cc=0; cc<16; ++cc){
      int c = cb + cc;
      float w0 = wl[(cc*3+0)*128 + o];
      float w1 = wl[(cc*3+1)*128 + o];
      float w2 = wl[(cc*3+2)*128 + o];
#pragma unroll
      for (int jj=0;jj<32;++jj){
        acc[jj] += xs[((((jj-1)>>1)+1)<<7) + c]*w0
                 + xs[((((jj  )>>1)+1)<<7) + c]*w1
                 + xs[((((jj+1)>>1)+1)<<7) + c]*w2;
      }
    }
  }
  int Lout = Lin*2;
  float* outp = ws + dstoff + e*Lout*128;
#pragma unroll
  for (int jj=0;jj<32;++jj){
    if (j0+jj < Lout){
      float v = acc[jj];
      outp[(j0+jj)*128 + o] = v >= 0.f ? v : 0.2f*v;
    }
  }
}

__global__ __launch_bounds__(128)
void k_layer(float* __restrict__ ws, const float* __restrict__ pbias,
             const float* __restrict__ ebias, const float* __restrict__ tbias,
             int c1, int c2,
             int pLin, int pWt, int pBo, int pNJ, int pSrc, int pDst,
             int eLin, int eWt, int eBo, int eNJ, int eSrc, int eDst,
             int tLin, int tWt, int tBo, int tNJ, int tSrc, int tDst){
  __shared__ float xs[18*128];
  __shared__ float wl[8192];
  int b = blockIdx.x;
  if (b < c1){
    int e = b / pNJ, jt = b - e*pNJ;
    convT32_dev(ws, pbias + pBo, pSrc, pDst, pWt, pLin, e, jt, xs, wl);
  } else if (b < c2){
    int bl = b - c1; int e = bl / eNJ, jt = bl - e*eNJ;
    conv3up32_dev(ws, ebias + eBo, eSrc, eDst, eWt, eLin, e, jt, xs, wl);
  } else {
    int bl = b - c2; int e = bl / tNJ, jt = bl - e*tNJ;
    conv3up32_dev(ws, tbias + tBo, tSrc, tDst, tWt, tLin, e, jt, xs, wl);
  }
}

// fused epilogues: blocks 0..15 out_pos, 16..79 out_env, 80..143 out_tfu ; 256 threads
__global__ void k_outs(float* __restrict__ ws,
                       const float* __restrict__ pw, const float* __restrict__ pb,
                       const float* __restrict__ ew, const float* __restrict__ eb,
                       const float* __restrict__ tw, const float* __restrict__ tb_,
                       float* __restrict__ out){
  __shared__ float xs[16384];
  int b = blockIdx.x, tid = threadIdx.x;
  if (b < 16){
    int e = b;
    const float* in = ws + PB + e*16384;
    for (int idx=tid; idx<16384; idx+=256){
      int q = idx >> 7, c = idx & 127;
      xs[(q<<7) + ((c+q)&127)] = in[idx];
    }
    __syncthreads();
    float acc = pb[0];
    if (tid < 128){
      int j = tid;
      for (int c=0;c<128;++c){
#pragma unroll
        for (int k=0;k<3;++k){
          int q = j + k - 1;
          if (q >= 0 && q < 128) acc += xs[(q<<7) + ((c+q)&127)] * pw[c*3 + k];
        }
      }
    }
    __syncthreads();
    xs[tid] = (tid < 128) ? acc : -3.0e38f;
    __syncthreads();
    for (int s=128; s>=1; s>>=1){ if (tid < s) xs[tid] = fmaxf(xs[tid], xs[tid+s]); __syncthreads(); }
    float m = xs[0];
    __syncthreads();
    float ex = (tid < 128) ? expf(__fsub_rn(acc, m)) : 0.f;
    xs[tid] = ex;
    __syncthreads();
    for (int s=128; s>=1; s>>=1){ if (tid < s) xs[tid] += xs[tid+s]; __syncthreads(); }
    if (tid < 128) ws[PE + e*128 + tid] = __fdiv_rn(ex, xs[0]);
  } else if (b < 80){
    int idx2 = b - 16; int e = idx2 >> 2, b0 = (idx2 & 3) << 6;
    const float* in = ws + BUFA + e*32768;
    for (int idx=tid; idx<8448; idx+=256){
      int qs = idx >> 7, c = idx & 127, q = b0 - 1 + qs;
      xs[(qs<<7) + ((c+qs)&127)] = (q >= 0 && q < 256) ? in[q*128 + c] : 0.f;
    }
    __syncthreads();
    int part = tid >> 6, bb = tid & 63;
    float acc = (part == 0) ? eb[0] : 0.f;
    for (int c2=0;c2<32;++c2){
      int c = part*32 + c2;
#pragma unroll
      for (int k=0;k<3;++k){
        int qs = bb + k;
        acc += xs[(qs<<7) + ((c+qs)&127)] * ew[c*3 + k];
      }
    }
    xs[8448 + tid] = acc;
    __syncthreads();
    if (tid < 64){
      float a = xs[8448+tid] + xs[8448+64+tid] + xs[8448+128+tid] + xs[8448+192+tid];
      a = fmaxf(a, 0.f);
      out[O_ENV + e*256 + b0 + tid] = a;
      ws[ENVO + e*256 + b0 + tid] = a;
    }
  } else {
    // out_tfu: 64 blocks = (event e, rr-group rg of 8 rows); all-LDS inner loop
    int b2 = b - 80; int e = b2 >> 2, rg = b2 & 3;
    float* tws = xs + 8448;              // 3072 floats
    const float* in = ws + TB + e*8192;
    for (int idx=tid; idx<8448; idx+=256){
      int qs = idx >> 7, c = idx & 127, q = -1 + qs;
      xs[(qs<<7) + ((c+qs)&127)] = (q >= 0 && q < 64) ? in[q*128 + c] : 0.f;
    }
    for (int idx=tid; idx<3072; idx+=256) tws[idx] = tw[rg*3072 + idx];
    __syncthreads();
    int rl0 = tid >> 6, bb = tid & 63;
    for (int rl=rl0; rl<8; rl+=4){
      int rr = rg*8 + rl;
      float acc = tb_[rr];
      for (int c=0;c<128;++c){
#pragma unroll
        for (int k=0;k<3;++k){
          int qs = bb + k;
          acc += xs[(qs<<7) + ((c+qs)&127)] * tws[rl*384 + c*3 + k];
        }
      }
      ws[TFQ + e*2048 + rr*64 + bb] = acc;
    }
  }
}

// ================= synthesis =================

// fused: blocks 0..2047 resonance-K (bf16, with inline argmax), blocks 2048..4095 envs
__global__ void k_envK(float* __restrict__ ws, const float* __restrict__ noise){
  int b = blockIdx.x, tid = threadIdx.x;
  if (b < 2048){
    int e = b >> 7, F = b & 127;
    int t = (F << 8) + tid;
    __shared__ float ampl[64];
    if (tid < 64){
      const float* tf = ws + TFQ + e*2048;
      float best = tf[tid]; int bi = 0;
      for (int r=1;r<32;++r){ float v = tf[r*64 + tid]; if (v > best){ best = v; bi = r; } }
      float d = __fadd_rn(0.5f, __fmul_rn((float)bi, __fdiv_rn(__fsub_rn(0.9999f, 0.5f), 31.0f)));
      ampl[tid] = (float)pow((double)d, (double)F);
    }
    __syncthreads();
    float acc = 0.f;
    for (int band=0;band<64;++band) acc += ws[SINES + band*NSAMP + t] * ampl[band];
    ((unsigned short*)(ws + KB))[e*34816 + 2048 + t] = f2bf(acc * (1.0f/(64.0f*65536.0f)));
  } else {
    int idx = (b - 2048)*256 + tid;
    int e = idx >> 15, tau = idx & 32767;
    float cf = __fsub_rn(__fdiv_rn(__fmul_rn(__fadd_rn((float)tau, 0.5f), 256.0f), 32768.0f), 0.5f);
    float c = fminf(fmaxf(cf, 0.0f), 255.0f);
    int i0 = (int)floorf(c);
    int i1 = min(i0 + 1, 255);
    float w = __fsub_rn(c, (float)i0);
    float e0 = ws[ENVO + e*256 + i0], e1 = ws[ENVO + e*256 + i1];
    float val = __fadd_rn(__fmul_rn(e0, __fsub_rn(1.0f, w)), __fmul_rn(e1, w));
    ws[ENVS + e*NSAMP + tau] = val * noise[tau];
  }
}

// impulse-comb conv; writes reversed bf16 copies (CRB0/CRB1) for the MFMA stage
__global__ void k_c(float* __restrict__ ws){
  int e = blockIdx.x >> 5, seg = blockIdx.x & 31;
  int t = (seg << 10) + threadIdx.x;
  __shared__ float pl[128];
  if (threadIdx.x < 128) pl[threadIdx.x] = ws[PE + e*128 + threadIdx.x];
  __syncthreads();
  const float* ev = ws + ENVS + e*NSAMP;
  int kub = min(127, (seg << 2) + 3);
  float acc = 0.f;
  for (int k=0;k<=kub;++k){
    int u = t - (k << 8);
    if (u >= 0) acc += pl[k] * ev[u];
  }
  unsigned short hv = f2bf(acc);
  ((unsigned short*)(ws + CRB0))[e*32832 + 32768 - t] = hv;
  ((unsigned short*)(ws + CRB1))[e*32832 + 32767 - t] = hv;
}

// Toeplitz conv via MFMA 32x32x16 bf16; 16 KB LDS two-phase reduction, no atomics.
__global__ __launch_bounds__(256, 4)
void k_bigmfma(float* __restrict__ ws){
  int b = blockIdx.x;
  int w = threadIdx.x >> 6;
  int lane = threadIdx.x & 63;
  int e = b / 72;
  int r = b - e*72;
  int T2 = 0, cum = 0;
  while (cum + ((T2+2)>>1) <= r){ cum += (T2+2)>>1; T2++; }
  int qb = r - cum;
  int nseg = 2*(T2+1);
  int seg = qb*4 + w;
  int t0 = T2 << 11;
  int il = lane & 31, h = lane >> 5;
  __shared__ float red[2][2048];
  f32x16 acc0 = {}; f32x16 acc1 = {};
  if (seg < nseg){
    int u0 = -1984 + (seg << 10);
    const unsigned short* Kp  = (const unsigned short*)(ws + KB)   + e*34816 + 2048;
    const unsigned short* C0p = (const unsigned short*)(ws + CRB0) + e*32832;
    const unsigned short* C1p = (const unsigned short*)(ws + CRB1) + e*32832;
    int bB  = u0 + (il << 6) + (h << 3);
    int bA0 = 32768 - t0 + u0 - (il << 1) + (h << 3);
    int bA1 = bA0 - 2;
#pragma unroll 2
    for (int q = 0; q < 64; ++q){
      union { f32x4 v; bf16x8 s; } a0u, a1u, bu;
      a0u.v = *(const f32x4*)(C0p + bA0);
      a1u.v = *(const f32x4*)(C1p + bA1);
      bu.v  = *(const f32x4*)(Kp  + bB);
      acc0 = __builtin_amdgcn_mfma_f32_32x32x16_bf16(a0u.s, bu.s, acc0, 0, 0, 0);
      acc1 = __builtin_amdgcn_mfma_f32_32x32x16_bf16(a1u.s, bu.s, acc1, 0, 0, 0);
      bA0 += 16; bA1 += 16; bB += 16;
    }
  }
  int wl = w & 1;
  if (w < 2){
#pragma unroll
    for (int rr = 0; rr < 16; ++rr){
      int row = (rr & 3) + ((rr >> 2) << 3) + (h << 2);
      red[wl][(row << 6) + il]      = acc0[rr];
      red[wl][(row << 6) + 32 + il] = acc1[rr];
    }
  }
  __syncthreads();
  if (w >= 2){
#pragma unroll
    for (int rr = 0; rr < 16; ++rr){
      int row = (rr & 3) + ((rr >> 2) << 3) + (h << 2);
      red[wl][(row << 6) + il]      += acc0[rr];
      red[wl][(row << 6) + 32 + il] += acc1[rr];
    }
  }
  __syncthreads();
  float* slab = ws + SLAB + b*2048;
  int tid = threadIdx.x;
#pragma unroll
  for (int jj = 0; jj < 8; ++jj){
    int pos = tid*8 + jj;                // pos = il2*64 + (2*row + p)
    int il2 = pos >> 6, x = pos & 63;
    int idx = ((x >> 1) << 6) + ((x & 1) << 5) + il2;
    slab[pos] = red[0][idx] + red[1][idx];
  }
}

__global__ void k_final(const float* __restrict__ ws, float* __restrict__ out){
  int t = blockIdx.x*1024 + threadIdx.x;
  int T2 = t >> 11, pos = t & 2047;
  int cum = 0;
  for (int j=0;j<T2;++j) cum += (j+2)>>1;
  int nb = (T2+2)>>1;
  float s = 0.f;
  for (int e=0;e<16;++e){
    const float* sl = ws + SLAB + (e*72 + cum)*2048 + pos;
    for (int q=0;q<nb;++q) s += sl[q*2048];
  }
  out[t] = s;
}

// ================= launcher =================

extern "C" void kernel_launch(void* const* d_in, const int* in_sizes, int n_in,
                              void* d_out, int out_size, void* d_ws, size_t ws_size,
                              hipStream_t stream){
  const float* x         = (const float*)d_in[0];
  const float* noise     = (const float*)d_in[1];
  const float* fb_w      = (const float*)d_in[2];
  const float* reduce_w  = (const float*)d_in[3];
  const float* reduce_b  = (const float*)d_in[4];
  const float* dl_dw     = (const float*)d_in[5];
  const float* dl_db     = (const float*)d_in[6];
  const float* dl_pw     = (const float*)d_in[7];
  const float* dl_pb     = (const float*)d_in[8];
  const float* tt_w      = (const float*)d_in[9];
  const float* tt_b      = (const float*)d_in[10];
  const float* tr_w      = (const float*)d_in[11];
  const float* tr_b      = (const float*)d_in[12];
  const float* pos_lin_w = (const float*)d_in[13];
  const float* pos_lin_b = (const float*)d_in[14];
  const float* pos_up_w  = (const float*)d_in[15];
  const float* pos_up_b  = (const float*)d_in[16];
  const float* pos_out_w = (const float*)d_in[17];
  const float* pos_out_b = (const float*)d_in[18];
  const float* env_lin_w = (const float*)d_in[19];
  const float* env_lin_b = (const float*)d_in[20];
  const float* env_up_w  = (const float*)d_in[21];
  const float* env_up_b  = (const float*)d_in[22];
  const float* env_out_w = (const float*)d_in[23];
  const float* env_out_b = (const float*)d_in[24];
  const float* tfu_lin_w = (const float*)d_in[25];
  const float* tfu_lin_b = (const float*)d_in[26];
  const float* tfu_up_w  = (const float*)d_in[27];
  const float* tfu_up_b  = (const float*)d_in[28];
  const float* tfu_out_w = (const float*)d_in[29];
  const float* tfu_out_b = (const float*)d_in[30];
  float* out = (float*)d_out;
  float* ws  = (float*)d_ws;

  k_setup<<<3201, 1024, 0, stream>>>(x, pos_up_w, env_up_w, tfu_up_w, tt_w, tr_w,
                                     pos_lin_w, env_lin_w, tfu_lin_w,
                                     dl_dw, dl_db, dl_pw, dl_pb, ws);
  k_fbpool<<<4096, 512, 0, stream>>>(fb_w, ws);
  k_reduce<<<128, 128, 0, stream>>>(reduce_w, reduce_b, ws);
  const int DIL[5] = {1, 3, 9, 27, 1};
  int src = HA, dst = HB;
  for (int l=0;l<5;++l){
    k_dil<<<128, 128, 0, stream>>>(ws, l, DIL[l], src, dst);
    int tmp = src; src = dst; dst = tmp;
  }
  k_topk<<<1, 128, 0, stream>>>(ws, out);
  k_tt<<<32, 1024, 0, stream>>>(ws, tt_b, tr_b, out);
  k_lin3<<<48, 1024, 0, stream>>>(ws, pos_lin_b, env_lin_b, tfu_lin_b);

  // fused decoder layers (pos convT | env conv3 | tfu conv3)
  k_layer<<<48, 128, 0, stream>>>(ws, pos_up_b, env_up_b, tfu_up_b, 16, 32,
      4,  WT_POS + 0,      0,   1, PA,   PB,
      4,  WT_ENV + 0,      0,   1, BUFA, BUFB,
      8,  WT_TFU + 0,      0,   1, TA,   TB);
  k_layer<<<48, 128, 0, stream>>>(ws, pos_up_b, env_up_b, tfu_up_b, 16, 32,
      8,  WT_POS + 65536,  128, 1, PB,   PA,
      8,  WT_ENV + 49152,  128, 1, BUFB, BUFA,
      16, WT_TFU + 49152,  128, 1, TB,   TA);
  k_layer<<<64, 128, 0, stream>>>(ws, pos_up_b, env_up_b, tfu_up_b, 16, 32,
      16, WT_POS + 131072, 256, 1, PA,   PB,
      16, WT_ENV + 98304,  256, 1, BUFA, BUFB,
      32, WT_TFU + 98304,  256, 2, TA,   TB);
  k_layer<<<64, 128, 0, stream>>>(ws, pos_up_b, env_up_b, tfu_up_b, 32, 64,
      32, WT_POS + 196608, 384, 2, PB,   PA,
      32, WT_ENV + 147456, 384, 2, BUFB, BUFA,
      1,  0,               0,   1, 0,    0);
  k_layer<<<128, 128, 0, stream>>>(ws, pos_up_b, env_up_b, tfu_up_b, 64, 128,
      64, WT_POS + 262144, 512, 4, PA,   PB,
      64, WT_ENV + 196608, 512, 4, BUFA, BUFB,
      1,  0,               0,   1, 0,    0);
  k_layer<<<128, 128, 0, stream>>>(ws, pos_up_b, env_up_b, tfu_up_b, 0, 128,
      1,  0,               0,   1, 0,    0,
      128, WT_ENV + 245760, 640, 8, BUFB, BUFA,
      1,  0,               0,   1, 0,    0);

  k_outs<<<144, 256, 0, stream>>>(ws, pos_out_w, pos_out_b, env_out_w, env_out_b,
                                  tfu_out_w, tfu_out_b, out);

  k_envK<<<4096, 256, 0, stream>>>(ws, noise);
  k_c<<<512, 1024, 0, stream>>>(ws);
  k_bigmfma<<<1152, 256, 0, stream>>>(ws);
  k_final<<<32, 1024, 0, stream>>>(ws, out);
}